// Round 6
// baseline (334.408 us; speedup 1.0000x reference)
//
#include <hip/hip_runtime.h>
#include <math.h>

#define D_MODEL 1024
#define D_STATE 16
#define D_CONV  4
#define DT_RANK 64
#define D_INNER 2048
#define BATCH   2
#define SEQ     1024
#define BT      (BATCH*SEQ)   // 2048 rows
#define NCHUNK  32
#define CLEN    (SEQ/NCHUNK)  // 32
#define KSPLIT  16            // split-K factor for dbc GEMM

typedef int   v4i __attribute__((ext_vector_type(4)));
typedef float v4f __attribute__((ext_vector_type(4)));
typedef unsigned short u16;

// ===========================================================================
// fp32 GEMM (dt projection + fallback path)
// ===========================================================================
template<int BM, int BN, int BK, int TM, int TN, int EPI>
__launch_bounds__(256)
__global__ void gemm_nt(const float* __restrict__ A, int lda,
                        const float* __restrict__ B, int ldb,
                        float* __restrict__ C, int ldc,
                        int K, const float* __restrict__ bias) {
    constexpr int BX = BN / TN;
    constexpr int BY = BM / TM;
    constexpr int THREADS = BX * BY;

    __shared__ float As[BK][BM + 1];
    __shared__ float Bs[BK][BN + 1];

    const int tid = threadIdx.x;
    const int tx  = tid % BX;
    const int ty  = tid / BX;
    const int m0  = blockIdx.y * BM;
    const int n0  = blockIdx.x * BN;

    float acc[TM][TN] = {};

    for (int k0 = 0; k0 < K; k0 += BK) {
        #pragma unroll
        for (int l = 0; l < (BM * BK) / (THREADS * 4); ++l) {
            int idx = (tid + l * THREADS) * 4;
            int row = idx / BK, col = idx % BK;
            const float4 v = *reinterpret_cast<const float4*>(
                &A[(size_t)(m0 + row) * lda + k0 + col]);
            As[col + 0][row] = v.x; As[col + 1][row] = v.y;
            As[col + 2][row] = v.z; As[col + 3][row] = v.w;
        }
        #pragma unroll
        for (int l = 0; l < (BN * BK) / (THREADS * 4); ++l) {
            int idx = (tid + l * THREADS) * 4;
            int row = idx / BK, col = idx % BK;
            const float4 v = *reinterpret_cast<const float4*>(
                &B[(size_t)(n0 + row) * ldb + k0 + col]);
            Bs[col + 0][row] = v.x; Bs[col + 1][row] = v.y;
            Bs[col + 2][row] = v.z; Bs[col + 3][row] = v.w;
        }
        __syncthreads();

        #pragma unroll
        for (int kk = 0; kk < BK; ++kk) {
            float a[TM], b[TN];
            #pragma unroll
            for (int i = 0; i < TM; ++i) a[i] = As[kk][ty * TM + i];
            #pragma unroll
            for (int j = 0; j < TN; ++j) b[j] = Bs[kk][tx * TN + j];
            #pragma unroll
            for (int i = 0; i < TM; ++i)
                #pragma unroll
                for (int j = 0; j < TN; ++j)
                    acc[i][j] = fmaf(a[i], b[j], acc[i][j]);
        }
        __syncthreads();
    }

    #pragma unroll
    for (int i = 0; i < TM; ++i) {
        float* outp = &C[(size_t)(m0 + ty * TM + i) * ldc + n0 + tx * TN];
        float vals[4];
        #pragma unroll
        for (int j = 0; j < TN; ++j) {
            float val = acc[i][j];
            if (EPI == 1) {
                val += bias[n0 + tx * TN + j];
                val = (val > 20.f) ? val : log1pf(expf(val));
            }
            vals[j] = val;
        }
        float4 v;
        v.x = vals[0]; v.y = vals[1]; v.z = vals[2]; v.w = vals[3];
        *reinterpret_cast<float4*>(outp) = v;
    }
}

// ===========================================================================
// Split-K fp32 GEMM for the skinny dbc projection (N=96, K=2048).
// ===========================================================================
template<int BM, int BN, int BK, int TM, int TN>
__launch_bounds__(128)
__global__ void gemm_nt_splitk(const float* __restrict__ A, int lda,
                               const float* __restrict__ B, int ldb,
                               float* __restrict__ part, int N, int kchunk) {
    constexpr int BX = BN / TN;
    constexpr int BY = BM / TM;
    constexpr int THREADS = BX * BY;

    __shared__ float As[BK][BM + 1];
    __shared__ float Bs[BK][BN + 1];

    const int tid = threadIdx.x;
    const int tx  = tid % BX;
    const int ty  = tid / BX;
    const int m0  = blockIdx.y * BM;
    const int n0  = blockIdx.x * BN;
    const int kb  = blockIdx.z * kchunk;

    float acc[TM][TN] = {};

    for (int k0 = kb; k0 < kb + kchunk; k0 += BK) {
        #pragma unroll
        for (int l = 0; l < (BM * BK) / (THREADS * 4); ++l) {
            int idx = (tid + l * THREADS) * 4;
            int row = idx / BK, col = idx % BK;
            const float4 v = *reinterpret_cast<const float4*>(
                &A[(size_t)(m0 + row) * lda + k0 + col]);
            As[col + 0][row] = v.x; As[col + 1][row] = v.y;
            As[col + 2][row] = v.z; As[col + 3][row] = v.w;
        }
        #pragma unroll
        for (int l = 0; l < (BN * BK) / (THREADS * 4); ++l) {
            int idx = (tid + l * THREADS) * 4;
            int row = idx / BK, col = idx % BK;
            const float4 v = *reinterpret_cast<const float4*>(
                &B[(size_t)(n0 + row) * ldb + k0 + col]);
            Bs[col + 0][row] = v.x; Bs[col + 1][row] = v.y;
            Bs[col + 2][row] = v.z; Bs[col + 3][row] = v.w;
        }
        __syncthreads();

        #pragma unroll
        for (int kk = 0; kk < BK; ++kk) {
            float a[TM], b[TN];
            #pragma unroll
            for (int i = 0; i < TM; ++i) a[i] = As[kk][ty * TM + i];
            #pragma unroll
            for (int j = 0; j < TN; ++j) b[j] = Bs[kk][tx * TN + j];
            #pragma unroll
            for (int i = 0; i < TM; ++i)
                #pragma unroll
                for (int j = 0; j < TN; ++j)
                    acc[i][j] = fmaf(a[i], b[j], acc[i][j]);
        }
        __syncthreads();
    }

    float* base = part + (size_t)blockIdx.z * BT * N;
    #pragma unroll
    for (int i = 0; i < TM; ++i) {
        float* outp = &base[(size_t)(m0 + ty * TM + i) * N + n0 + tx * TN];
        float4 v;
        v.x = acc[i][0]; v.y = acc[i][1]; v.z = acc[i][2]; v.w = acc[i][3];
        *reinterpret_cast<float4*>(outp) = v;
    }
}

__global__ void reduce_splitk(const float* __restrict__ part,
                              float* __restrict__ outp, int n) {
    const int idx = blockIdx.x * 256 + threadIdx.x;
    if (idx >= n) return;
    float s = 0.f;
    #pragma unroll
    for (int kc = 0; kc < KSPLIT; ++kc)
        s += part[(size_t)kc * n + idx];
    outp[idx] = s;
}

// ===========================================================================
// bf16 helpers
// ===========================================================================
__device__ __forceinline__ u16 rne_bf16(float x) {
    unsigned int u = __float_as_uint(x);
    unsigned int r = u + 0x7FFFu + ((u >> 16) & 1u);
    return (u16)(r >> 16);
}

// One pass converting: x -> (hi,lo); W_in -> hi; W_out -> hi.
__global__ void prep_kernel(const float* __restrict__ x,
                            const float* __restrict__ Win,
                            const float* __restrict__ Wout,
                            u16* __restrict__ xhi, u16* __restrict__ xlo,
                            u16* __restrict__ winh, u16* __restrict__ wouth) {
    const size_t M2 = 2u * 1024u * 1024u;
    size_t i = ((size_t)blockIdx.x * 256 + threadIdx.x) * 8;
    if (i < M2) {
        float4 a = *reinterpret_cast<const float4*>(&x[i]);
        float4 b = *reinterpret_cast<const float4*>(&x[i + 4]);
        float xs[8] = {a.x, a.y, a.z, a.w, b.x, b.y, b.z, b.w};
        unsigned int hw[4], lw[4];
        #pragma unroll
        for (int q = 0; q < 4; ++q) {
            u16 h0 = rne_bf16(xs[2*q]);
            u16 h1 = rne_bf16(xs[2*q+1]);
            float d0 = xs[2*q]   - __uint_as_float((unsigned int)h0 << 16);
            float d1 = xs[2*q+1] - __uint_as_float((unsigned int)h1 << 16);
            hw[q] = (unsigned int)h0 | ((unsigned int)h1 << 16);
            lw[q] = (unsigned int)rne_bf16(d0) | ((unsigned int)rne_bf16(d1) << 16);
        }
        *reinterpret_cast<v4i*>(&xhi[i]) = *reinterpret_cast<v4i*>(hw);
        *reinterpret_cast<v4i*>(&xlo[i]) = *reinterpret_cast<v4i*>(lw);
    } else if (i < 3 * M2) {
        size_t j = i - M2;
        float4 a = *reinterpret_cast<const float4*>(&Win[j]);
        float4 b = *reinterpret_cast<const float4*>(&Win[j + 4]);
        float xs[8] = {a.x, a.y, a.z, a.w, b.x, b.y, b.z, b.w};
        unsigned int hw[4];
        #pragma unroll
        for (int q = 0; q < 4; ++q)
            hw[q] = (unsigned int)rne_bf16(xs[2*q]) | ((unsigned int)rne_bf16(xs[2*q+1]) << 16);
        *reinterpret_cast<v4i*>(&winh[j]) = *reinterpret_cast<v4i*>(hw);
    } else {
        size_t j = i - 3 * M2;
        float4 a = *reinterpret_cast<const float4*>(&Wout[j]);
        float4 b = *reinterpret_cast<const float4*>(&Wout[j + 4]);
        float xs[8] = {a.x, a.y, a.z, a.w, b.x, b.y, b.z, b.w};
        unsigned int hw[4];
        #pragma unroll
        for (int q = 0; q < 4; ++q)
            hw[q] = (unsigned int)rne_bf16(xs[2*q]) | ((unsigned int)rne_bf16(xs[2*q+1]) << 16);
        *reinterpret_cast<v4i*>(&wouth[j]) = *reinterpret_cast<v4i*>(hw);
    }
}

// ===========================================================================
// 2-term split-bf16 MFMA GEMM: C = (Ahi+Alo) @ Bhi^T, fp32 accumulate.
// ===========================================================================
#define MFMA_B16(ACC, Af, Bf) \
    asm("v_mfma_f32_16x16x32_bf16 %0, %1, %2, %0" : "+v"(ACC) : "v"(Af), "v"(Bf))

template<int BM, int BN, int WM, int WN>
__launch_bounds__(256)
__global__ void gemm_mfma2(const u16* __restrict__ Ahi, const u16* __restrict__ Alo, int lda,
                           const u16* __restrict__ Bhi, int ldb,
                           float* __restrict__ C, int ldc, int K) {
    constexpr int ACH = BM / 64;
    constexpr int BCH = BN / 64;
    constexpr int WMF = WM / 16;
    constexpr int WNF = WN / 16;
    constexpr int SA  = BM * 40;
    constexpr int SB  = BN * 40;
    constexpr int BUFSZ = 2 * SA + SB;
    constexpr int WCOLS = BN / WN;

    __shared__ u16 smem[2 * BUFSZ];

    const int tid  = threadIdx.x;
    const int lane = tid & 63;
    const int wave = tid >> 6;
    const int wr   = wave / WCOLS, wc = wave % WCOLS;
    const int m0   = blockIdx.y * BM, n0 = blockIdx.x * BN;

    size_t aBase[ACH]; int aW[ACH];
    #pragma unroll
    for (int q = 0; q < ACH; ++q) {
        int c = tid + q * 256, row = c >> 2, slot = c & 3;
        aBase[q] = (size_t)(m0 + row) * lda + slot * 8;
        aW[q] = row * 40 + slot * 8;
    }
    size_t bBase[BCH]; int bW[BCH];
    #pragma unroll
    for (int q = 0; q < BCH; ++q) {
        int c = tid + q * 256, row = c >> 2, slot = c & 3;
        bBase[q] = (size_t)(n0 + row) * ldb + slot * 8;
        bW[q] = row * 40 + slot * 8;
    }

    const int fr = lane & 15;
    const int fk = (lane >> 4) * 8;
    const int fq = lane >> 4;
    int aOff[WMF], bOff[WNF];
    #pragma unroll
    for (int i = 0; i < WMF; ++i) aOff[i] = (wr * WM + i * 16 + fr) * 40 + fk;
    #pragma unroll
    for (int j = 0; j < WNF; ++j) bOff[j] = (wc * WN + j * 16 + fr) * 40 + fk;

    v4f acc[WMF][WNF];
    #pragma unroll
    for (int i = 0; i < WMF; ++i)
        #pragma unroll
        for (int j = 0; j < WNF; ++j)
            acc[i][j] = (v4f)0.f;

    v4i rAh[ACH], rAl[ACH], rBh[BCH];
    #pragma unroll
    for (int q = 0; q < ACH; ++q) {
        rAh[q] = *reinterpret_cast<const v4i*>(Ahi + aBase[q]);
        rAl[q] = *reinterpret_cast<const v4i*>(Alo + aBase[q]);
    }
    #pragma unroll
    for (int q = 0; q < BCH; ++q)
        rBh[q] = *reinterpret_cast<const v4i*>(Bhi + bBase[q]);
    #pragma unroll
    for (int q = 0; q < ACH; ++q) {
        *reinterpret_cast<v4i*>(&smem[aW[q]]) = rAh[q];
        *reinterpret_cast<v4i*>(&smem[SA + aW[q]]) = rAl[q];
    }
    #pragma unroll
    for (int q = 0; q < BCH; ++q)
        *reinterpret_cast<v4i*>(&smem[2 * SA + bW[q]]) = rBh[q];
    __syncthreads();

    const int NK = K / 32;
    for (int k = 0; k < NK; ++k) {
        u16* sc = smem + (k & 1) * BUFSZ;
        if (k + 1 < NK) {
            const int k0 = (k + 1) * 32;
            #pragma unroll
            for (int q = 0; q < ACH; ++q) {
                rAh[q] = *reinterpret_cast<const v4i*>(Ahi + aBase[q] + k0);
                rAl[q] = *reinterpret_cast<const v4i*>(Alo + aBase[q] + k0);
            }
            #pragma unroll
            for (int q = 0; q < BCH; ++q)
                rBh[q] = *reinterpret_cast<const v4i*>(Bhi + bBase[q] + k0);
        }

        v4i ah[WMF], al[WMF];
        #pragma unroll
        for (int i = 0; i < WMF; ++i) {
            ah[i] = *reinterpret_cast<const v4i*>(&sc[aOff[i]]);
            al[i] = *reinterpret_cast<const v4i*>(&sc[SA + aOff[i]]);
        }
        #pragma unroll
        for (int j = 0; j < WNF; ++j) {
            v4i bh = *reinterpret_cast<const v4i*>(&sc[2 * SA + bOff[j]]);
            #pragma unroll
            for (int i = 0; i < WMF; ++i) {
                MFMA_B16(acc[i][j], ah[i], bh);
                MFMA_B16(acc[i][j], al[i], bh);
            }
        }

        if (k + 1 < NK) {
            u16* sn = smem + ((k + 1) & 1) * BUFSZ;
            #pragma unroll
            for (int q = 0; q < ACH; ++q) {
                *reinterpret_cast<v4i*>(&sn[aW[q]]) = rAh[q];
                *reinterpret_cast<v4i*>(&sn[SA + aW[q]]) = rAl[q];
            }
            #pragma unroll
            for (int q = 0; q < BCH; ++q)
                *reinterpret_cast<v4i*>(&sn[2 * SA + bW[q]]) = rBh[q];
            __syncthreads();
        }
    }

    asm volatile("s_nop 7\n\ts_nop 7\n\ts_nop 7" ::: "memory");

    #pragma unroll
    for (int i = 0; i < WMF; ++i) {
        const int row = m0 + wr * WM + i * 16 + fq * 4;
        #pragma unroll
        for (int j = 0; j < WNF; ++j) {
            const int col = n0 + wc * WN + j * 16 + fr;
            #pragma unroll
            for (int r = 0; r < 4; ++r)
                C[(size_t)(row + r) * ldc + col] = acc[i][j][r];
        }
    }
}

// ===========================================================================
// Depthwise causal conv (width 4) + bias + SiLU.
// ===========================================================================
__global__ void conv_silu_kernel(const float* __restrict__ x_in, int xld,
                                 const float* __restrict__ w,
                                 const float* __restrict__ b,
                                 float* __restrict__ x_act) {
    const int idx = blockIdx.x * blockDim.x + threadIdx.x;
    const int ch = idx % D_INNER;
    const int m  = idx / D_INNER;
    const int t  = m % SEQ;

    float acc = b[ch];
    #pragma unroll
    for (int j = 0; j < D_CONV; ++j) {
        int tt = t - (D_CONV - 1) + j;
        if (tt >= 0)
            acc = fmaf(w[ch * D_CONV + j], x_in[(size_t)(m - (D_CONV - 1) + j) * xld + ch], acc);
    }
    x_act[idx] = acc / (1.f + __expf(-acc));
}

// ===========================================================================
// Chunked selective scan. NCHUNK=32, CLEN=32. 8-deep load batching for
// latency hiding (issue 16-24 independent vmem ops, then compute 8 steps).
// ===========================================================================
__global__ void scan_part1(const float* __restrict__ dt,
                           const float* __restrict__ x_act,
                           const float* __restrict__ dbc,
                           const float* __restrict__ A_log,
                           float* __restrict__ P, float* __restrict__ F) {
    __shared__ float Bsh[CLEN][D_STATE];
    const int tid = threadIdx.x;
    const int d = blockIdx.x * 256 + tid;
    const int c = blockIdx.y;
    const int b = blockIdx.z;
    const int mbase = b * SEQ + c * CLEN;

    {   // stage B rows: CLEN*16 = 512 floats, 2 per thread
        const int s = tid & 15, t0 = tid >> 4;
        #pragma unroll
        for (int q = 0; q < 2; ++q)
            Bsh[t0 + 16 * q][s] = dbc[(size_t)(mbase + t0 + 16 * q) * 96 + DT_RANK + s];
    }
    float A[16];
    #pragma unroll
    for (int q = 0; q < 4; ++q) {
        float4 v = *reinterpret_cast<const float4*>(&A_log[d * 16 + q * 4]);
        A[q*4+0] = -__expf(v.x); A[q*4+1] = -__expf(v.y);
        A[q*4+2] = -__expf(v.z); A[q*4+3] = -__expf(v.w);
    }
    __syncthreads();

    float h[16] = {};
    float Pp[16];
    #pragma unroll
    for (int s = 0; s < 16; ++s) Pp[s] = 1.f;

    for (int t0 = 0; t0 < CLEN; t0 += 8) {
        float dtb[8], ub[8];
        #pragma unroll
        for (int q = 0; q < 8; ++q) {
            const int m = mbase + t0 + q;
            dtb[q] = dt[(size_t)m * D_INNER + d];
            ub[q]  = x_act[(size_t)m * D_INNER + d];
        }
        #pragma unroll
        for (int q = 0; q < 8; ++q) {
            const float dtv = dtb[q];
            const float du  = dtv * ub[q];
            float Bv[16];
            #pragma unroll
            for (int r = 0; r < 4; ++r) {
                float4 v = *reinterpret_cast<const float4*>(&Bsh[t0 + q][r * 4]);
                Bv[r*4+0] = v.x; Bv[r*4+1] = v.y; Bv[r*4+2] = v.z; Bv[r*4+3] = v.w;
            }
            #pragma unroll
            for (int s = 0; s < 16; ++s) {
                const float dA = __expf(dtv * A[s]);
                Pp[s] *= dA;
                h[s] = fmaf(dA, h[s], du * Bv[s]);
            }
        }
    }
    const size_t base = ((size_t)(b * NCHUNK + c) * 16) * D_INNER + d;
    #pragma unroll
    for (int s = 0; s < 16; ++s) {
        P[base + (size_t)s * D_INNER] = Pp[s];
        F[base + (size_t)s * D_INNER] = h[s];
    }
}

// Batch-load all chunk summaries to registers, serial combine, store back.
__global__ void scan_combine(const float* __restrict__ P, float* F) {
    const int idx = blockIdx.x * 256 + threadIdx.x;    // over B*16*D_INNER
    const int d  = idx % D_INNER;
    const int bs = idx / D_INNER;
    const int b  = bs >> 4, s = bs & 15;
    const size_t base0 = ((size_t)b * NCHUNK * 16 + s) * D_INNER + d;
    const size_t cstep = (size_t)16 * D_INNER;

    float Pv[NCHUNK], Fv[NCHUNK];
    #pragma unroll
    for (int c = 0; c < NCHUNK; ++c) {
        Pv[c] = P[base0 + c * cstep];
        Fv[c] = F[base0 + c * cstep];
    }
    float G = 0.f;
    #pragma unroll
    for (int c = 0; c < NCHUNK; ++c) {
        const float f = Fv[c];
        Fv[c] = G;                       // initial state for chunk c
        G = fmaf(Pv[c], G, f);
    }
    #pragma unroll
    for (int c = 0; c < NCHUNK; ++c)
        F[base0 + c * cstep] = Fv[c];
}

// BF16OUT=1: emit yf as bf16 (hi,lo) for the MFMA out_proj.
// BF16OUT=0: fp32 yf (fallback; zp may alias yf -> z loaded before stores).
template<int BF16OUT>
__global__ void scan_part2(const float* __restrict__ dt,
                           const float* __restrict__ x_act,
                           const float* __restrict__ dbc,
                           const float* __restrict__ A_log,
                           const float* __restrict__ Dp,
                           const float* __restrict__ Ginit,
                           const float* zp, int zld,
                           float* yf, u16* yh, u16* yl) {
    __shared__ float BCs[CLEN][32];   // [t][0:16]=B, [16:32]=C ; 4 KB
    const int tid = threadIdx.x;
    const int d = blockIdx.x * 256 + tid;
    const int c = blockIdx.y;
    const int b = blockIdx.z;
    const int mbase = b * SEQ + c * CLEN;

    {   // stage B+C: CLEN*32 = 1024 floats, one float4 per thread
        const int t0 = tid >> 3;            // 0..31
        const int j  = (tid & 7) * 4;       // 0..28
        float4 v = *reinterpret_cast<const float4*>(
            &dbc[(size_t)(mbase + t0) * 96 + DT_RANK + j]);
        *reinterpret_cast<float4*>(&BCs[t0][j]) = v;
    }
    float A[16];
    #pragma unroll
    for (int q = 0; q < 4; ++q) {
        float4 v = *reinterpret_cast<const float4*>(&A_log[d * 16 + q * 4]);
        A[q*4+0] = -__expf(v.x); A[q*4+1] = -__expf(v.y);
        A[q*4+2] = -__expf(v.z); A[q*4+3] = -__expf(v.w);
    }
    float h[16];
    const size_t gbase = ((size_t)(b * NCHUNK + c) * 16) * D_INNER + d;
    #pragma unroll
    for (int s = 0; s < 16; ++s) h[s] = Ginit[gbase + (size_t)s * D_INNER];
    const float Dv = Dp[d];
    __syncthreads();

    for (int t0 = 0; t0 < CLEN; t0 += 8) {
        float dtb[8], ub[8], zb[8];
        #pragma unroll
        for (int q = 0; q < 8; ++q) {
            const int m = mbase + t0 + q;
            dtb[q] = dt[(size_t)m * D_INNER + d];
            ub[q]  = x_act[(size_t)m * D_INNER + d];
            zb[q]  = zp[(size_t)m * zld + d];
        }
        #pragma unroll
        for (int q = 0; q < 8; ++q) {
            const int m = mbase + t0 + q;
            const float dtv = dtb[q];
            const float u   = ub[q];
            const float du  = dtv * u;
            float Bv[16], Cv[16];
            #pragma unroll
            for (int r = 0; r < 4; ++r) {
                float4 vb = *reinterpret_cast<const float4*>(&BCs[t0 + q][r * 4]);
                float4 vc = *reinterpret_cast<const float4*>(&BCs[t0 + q][16 + r * 4]);
                Bv[r*4+0] = vb.x; Bv[r*4+1] = vb.y; Bv[r*4+2] = vb.z; Bv[r*4+3] = vb.w;
                Cv[r*4+0] = vc.x; Cv[r*4+1] = vc.y; Cv[r*4+2] = vc.z; Cv[r*4+3] = vc.w;
            }
            float y0 = 0.f, y1 = 0.f;
            #pragma unroll
            for (int s = 0; s < 16; s += 2) {
                const float dA0 = __expf(dtv * A[s]);
                const float dA1 = __expf(dtv * A[s + 1]);
                h[s]     = fmaf(dA0, h[s],     du * Bv[s]);
                h[s + 1] = fmaf(dA1, h[s + 1], du * Bv[s + 1]);
                y0 = fmaf(h[s],     Cv[s],     y0);
                y1 = fmaf(h[s + 1], Cv[s + 1], y1);
            }
            float y = y0 + y1;
            y = fmaf(u, Dv, y);
            const float zv = zb[q];
            const float g  = zv / (1.f + __expf(-zv));
            const float val = y * g;
            if (BF16OUT) {
                const u16 hh = rne_bf16(val);
                yh[(size_t)m * D_INNER + d] = hh;
                yl[(size_t)m * D_INNER + d] =
                    rne_bf16(val - __uint_as_float((unsigned int)hh << 16));
            } else {
                yf[(size_t)m * D_INNER + d] = val;
            }
        }
    }
}

// ===========================================================================
extern "C" void kernel_launch(void* const* d_in, const int* in_sizes, int n_in,
                              void* d_out, int out_size, void* d_ws, size_t ws_size,
                              hipStream_t stream) {
    const float* x      = (const float*)d_in[0];
    const float* W_in   = (const float*)d_in[1];
    const float* conv_w = (const float*)d_in[2];
    const float* conv_b = (const float*)d_in[3];
    const float* W_x    = (const float*)d_in[4];
    const float* W_dt   = (const float*)d_in[5];
    const float* b_dt   = (const float*)d_in[6];
    const float* A_log  = (const float*)d_in[7];
    const float* Dp     = (const float*)d_in[8];
    const float* W_out  = (const float*)d_in[9];
    float* out = (float*)d_out;

    const size_t M1 = 1024u * 1024u;
    // floats: xz 8M | x_act 4M | dbc .1875M | dt 4M
    // shorts: xhi 2M | xlo 2M | winh 4M | wouth 2M | yh 4M | yl 4M
    // P (2M floats) aliases xhi+xlo; F (2M floats) aliases winh (dead after
    // in_proj). dbc split-K partials alias yh/yl (dead until scan_part2).
    const size_t fXZ = 8 * M1, fXACT = 4 * M1, fDBC = (size_t)BT * 96,
                 fDT = 4 * M1;
    const size_t need = (fXZ + fXACT + fDBC + fDT) * 4 + 18 * M1 * 2;

    if (ws_size >= need) {
        float* ws    = (float*)d_ws;
        float* xz    = ws;
        float* x_act = xz    + fXZ;
        float* dbc   = x_act + fXACT;
        float* dtbuf = dbc   + fDBC;
        u16* xhi   = (u16*)(dtbuf + fDT);
        u16* xlo   = xhi   + 2 * M1;
        u16* winh  = xlo   + 2 * M1;
        u16* wouth = winh  + 4 * M1;
        u16* yh    = wouth + 2 * M1;   // 4M shorts
        u16* yl    = yh    + 4 * M1;   // 4M shorts
        float* Pbuf = (float*)xhi;     // 2M floats (xhi+xlo region)
        float* Fbuf = (float*)winh;    // 2M floats (winh region)
        float* dbc_part = (float*)yh;  // 12.6 MB < 16 MB

        // 1) convert: x -> hi/lo, W_in -> hi, W_out -> hi
        prep_kernel<<<dim3((8 * M1) / 2048), 256, 0, stream>>>(
            x, W_in, W_out, xhi, xlo, winh, wouth);

        // 2) in_proj: xz[2048][4096] = x @ W_in^T
        gemm_mfma2<128, 256, 64, 128><<<dim3(4096 / 256, BT / 128), 256, 0, stream>>>(
            xhi, xlo, D_MODEL, winh, D_MODEL, xz, 4096, D_MODEL);

        // 3) conv + SiLU (x_in = xz[:, :2048])
        conv_silu_kernel<<<dim3((BT * D_INNER) / 256), 256, 0, stream>>>(
            xz, 4096, conv_w, conv_b, x_act);

        // 4) dbc = x_act @ W_x^T (fp32 split-K)
        gemm_nt_splitk<64,32,16,4,4><<<dim3(96 / 32, BT / 64, KSPLIT), 128, 0, stream>>>(
            x_act, D_INNER, W_x, D_INNER, dbc_part, 96, D_INNER / KSPLIT);
        reduce_splitk<<<dim3((BT * 96 + 255) / 256), 256, 0, stream>>>(
            dbc_part, dbc, BT * 96);

        // 5) dt = softplus(dbc[:, :64] @ W_dt^T + b_dt) (fp32)
        gemm_nt<64,64,16,4,4,1><<<dim3(D_INNER / 64, BT / 64), 256, 0, stream>>>(
            dbc, 96, W_dt, DT_RANK, dtbuf, D_INNER, DT_RANK, b_dt);

        // 6) chunked scan + skip + gate; emit yf as bf16 hi/lo
        scan_part1<<<dim3(D_INNER / 256, NCHUNK, BATCH), 256, 0, stream>>>(
            dtbuf, x_act, dbc, A_log, Pbuf, Fbuf);
        scan_combine<<<dim3((BATCH * 16 * D_INNER) / 256), 256, 0, stream>>>(
            Pbuf, Fbuf);
        scan_part2<1><<<dim3(D_INNER / 256, NCHUNK, BATCH), 256, 0, stream>>>(
            dtbuf, x_act, dbc, A_log, Dp, Fbuf, xz + D_INNER, 4096,
            nullptr, yh, yl);

        // 7) out_proj: out = yf @ W_out^T
        gemm_mfma2<64, 128, 32, 64><<<dim3(D_MODEL / 128, BT / 64), 256, 0, stream>>>(
            yh, yl, D_INNER, wouth, D_INNER, out, D_MODEL, D_INNER);
    } else {
        // ------------------- fallback: all-fp32 path -----------------------
        float* ws    = (float*)d_ws;
        float* x_in  = ws;
        float* z     = x_in  + (size_t)BT * D_INNER;
        float* x_act = z     + (size_t)BT * D_INNER;
        float* dbc   = x_act + (size_t)BT * D_INNER;
        float* Pbuf  = dbc   + (size_t)BT * 96;
        float* Fbuf  = Pbuf  + (size_t)BATCH * NCHUNK * 16 * D_INNER;
        float* dtbuf = x_in;
        float* yf    = z;

        gemm_nt<64,64,16,4,4,0><<<dim3(D_INNER/64, BT/64), 256, 0, stream>>>(
            x, D_MODEL, W_in, D_MODEL, x_in, D_INNER, D_MODEL, nullptr);
        gemm_nt<64,64,16,4,4,0><<<dim3(D_INNER/64, BT/64), 256, 0, stream>>>(
            x, D_MODEL, W_in + (size_t)D_INNER * D_MODEL, D_MODEL, z, D_INNER, D_MODEL, nullptr);
        conv_silu_kernel<<<dim3((BT * D_INNER) / 256), 256, 0, stream>>>(
            x_in, D_INNER, conv_w, conv_b, x_act);
        gemm_nt<64,32,16,4,4,0><<<dim3(96/32, BT/64), 128, 0, stream>>>(
            x_act, D_INNER, W_x, D_INNER, dbc, 96, D_INNER, nullptr);
        gemm_nt<64,64,16,4,4,1><<<dim3(D_INNER/64, BT/64), 256, 0, stream>>>(
            dbc, 96, W_dt, DT_RANK, dtbuf, D_INNER, DT_RANK, b_dt);
        scan_part1<<<dim3(D_INNER/256, NCHUNK, BATCH), 256, 0, stream>>>(
            dtbuf, x_act, dbc, A_log, Pbuf, Fbuf);
        scan_combine<<<dim3((BATCH * 16 * D_INNER) / 256), 256, 0, stream>>>(
            Pbuf, Fbuf);
        scan_part2<0><<<dim3(D_INNER/256, NCHUNK, BATCH), 256, 0, stream>>>(
            dtbuf, x_act, dbc, A_log, Dp, Fbuf, z, D_INNER, yf, nullptr, nullptr);
        gemm_nt<64,64,16,4,4,0><<<dim3(D_MODEL/64, BT/64), 256, 0, stream>>>(
            yf, D_INNER, W_out, D_INNER, out, D_MODEL, D_INNER, nullptr);
    }
}

// Round 7
// 301.403 us; speedup vs baseline: 1.1095x; 1.1095x over previous
//
#include <hip/hip_runtime.h>
#include <math.h>

#define D_MODEL 1024
#define D_STATE 16
#define D_CONV  4
#define DT_RANK 64
#define D_INNER 2048
#define BATCH   2
#define SEQ     1024
#define BT      (BATCH*SEQ)   // 2048 rows
#define NCHUNK  32
#define CLEN    (SEQ/NCHUNK)  // 32
#define KSPLIT  16            // split-K factor for dbc GEMM

typedef int   v4i __attribute__((ext_vector_type(4)));
typedef float v4f __attribute__((ext_vector_type(4)));
typedef unsigned short u16;

// ===========================================================================
// fp32 GEMM (dt projection + fallback path)
// ===========================================================================
template<int BM, int BN, int BK, int TM, int TN, int EPI>
__launch_bounds__(256)
__global__ void gemm_nt(const float* __restrict__ A, int lda,
                        const float* __restrict__ B, int ldb,
                        float* __restrict__ C, int ldc,
                        int K, const float* __restrict__ bias) {
    constexpr int BX = BN / TN;
    constexpr int BY = BM / TM;
    constexpr int THREADS = BX * BY;

    __shared__ float As[BK][BM + 1];
    __shared__ float Bs[BK][BN + 1];

    const int tid = threadIdx.x;
    const int tx  = tid % BX;
    const int ty  = tid / BX;
    const int m0  = blockIdx.y * BM;
    const int n0  = blockIdx.x * BN;

    float acc[TM][TN] = {};

    for (int k0 = 0; k0 < K; k0 += BK) {
        #pragma unroll
        for (int l = 0; l < (BM * BK) / (THREADS * 4); ++l) {
            int idx = (tid + l * THREADS) * 4;
            int row = idx / BK, col = idx % BK;
            const float4 v = *reinterpret_cast<const float4*>(
                &A[(size_t)(m0 + row) * lda + k0 + col]);
            As[col + 0][row] = v.x; As[col + 1][row] = v.y;
            As[col + 2][row] = v.z; As[col + 3][row] = v.w;
        }
        #pragma unroll
        for (int l = 0; l < (BN * BK) / (THREADS * 4); ++l) {
            int idx = (tid + l * THREADS) * 4;
            int row = idx / BK, col = idx % BK;
            const float4 v = *reinterpret_cast<const float4*>(
                &B[(size_t)(n0 + row) * ldb + k0 + col]);
            Bs[col + 0][row] = v.x; Bs[col + 1][row] = v.y;
            Bs[col + 2][row] = v.z; Bs[col + 3][row] = v.w;
        }
        __syncthreads();

        #pragma unroll
        for (int kk = 0; kk < BK; ++kk) {
            float a[TM], b[TN];
            #pragma unroll
            for (int i = 0; i < TM; ++i) a[i] = As[kk][ty * TM + i];
            #pragma unroll
            for (int j = 0; j < TN; ++j) b[j] = Bs[kk][tx * TN + j];
            #pragma unroll
            for (int i = 0; i < TM; ++i)
                #pragma unroll
                for (int j = 0; j < TN; ++j)
                    acc[i][j] = fmaf(a[i], b[j], acc[i][j]);
        }
        __syncthreads();
    }

    #pragma unroll
    for (int i = 0; i < TM; ++i) {
        float* outp = &C[(size_t)(m0 + ty * TM + i) * ldc + n0 + tx * TN];
        float vals[4];
        #pragma unroll
        for (int j = 0; j < TN; ++j) {
            float val = acc[i][j];
            if (EPI == 1) {
                val += bias[n0 + tx * TN + j];
                val = (val > 20.f) ? val : log1pf(expf(val));
            }
            vals[j] = val;
        }
        float4 v;
        v.x = vals[0]; v.y = vals[1]; v.z = vals[2]; v.w = vals[3];
        *reinterpret_cast<float4*>(outp) = v;
    }
}

// ===========================================================================
// Split-K fp32 GEMM for the skinny dbc projection (N=96, K=2048).
// ===========================================================================
template<int BM, int BN, int BK, int TM, int TN>
__launch_bounds__(128)
__global__ void gemm_nt_splitk(const float* __restrict__ A, int lda,
                               const float* __restrict__ B, int ldb,
                               float* __restrict__ part, int N, int kchunk) {
    constexpr int BX = BN / TN;
    constexpr int BY = BM / TM;
    constexpr int THREADS = BX * BY;

    __shared__ float As[BK][BM + 1];
    __shared__ float Bs[BK][BN + 1];

    const int tid = threadIdx.x;
    const int tx  = tid % BX;
    const int ty  = tid / BX;
    const int m0  = blockIdx.y * BM;
    const int n0  = blockIdx.x * BN;
    const int kb  = blockIdx.z * kchunk;

    float acc[TM][TN] = {};

    for (int k0 = kb; k0 < kb + kchunk; k0 += BK) {
        #pragma unroll
        for (int l = 0; l < (BM * BK) / (THREADS * 4); ++l) {
            int idx = (tid + l * THREADS) * 4;
            int row = idx / BK, col = idx % BK;
            const float4 v = *reinterpret_cast<const float4*>(
                &A[(size_t)(m0 + row) * lda + k0 + col]);
            As[col + 0][row] = v.x; As[col + 1][row] = v.y;
            As[col + 2][row] = v.z; As[col + 3][row] = v.w;
        }
        #pragma unroll
        for (int l = 0; l < (BN * BK) / (THREADS * 4); ++l) {
            int idx = (tid + l * THREADS) * 4;
            int row = idx / BK, col = idx % BK;
            const float4 v = *reinterpret_cast<const float4*>(
                &B[(size_t)(n0 + row) * ldb + k0 + col]);
            Bs[col + 0][row] = v.x; Bs[col + 1][row] = v.y;
            Bs[col + 2][row] = v.z; Bs[col + 3][row] = v.w;
        }
        __syncthreads();

        #pragma unroll
        for (int kk = 0; kk < BK; ++kk) {
            float a[TM], b[TN];
            #pragma unroll
            for (int i = 0; i < TM; ++i) a[i] = As[kk][ty * TM + i];
            #pragma unroll
            for (int j = 0; j < TN; ++j) b[j] = Bs[kk][tx * TN + j];
            #pragma unroll
            for (int i = 0; i < TM; ++i)
                #pragma unroll
                for (int j = 0; j < TN; ++j)
                    acc[i][j] = fmaf(a[i], b[j], acc[i][j]);
        }
        __syncthreads();
    }

    float* base = part + (size_t)blockIdx.z * BT * N;
    #pragma unroll
    for (int i = 0; i < TM; ++i) {
        float* outp = &base[(size_t)(m0 + ty * TM + i) * N + n0 + tx * TN];
        float4 v;
        v.x = acc[i][0]; v.y = acc[i][1]; v.z = acc[i][2]; v.w = acc[i][3];
        *reinterpret_cast<float4*>(outp) = v;
    }
}

__global__ void reduce_splitk(const float* __restrict__ part,
                              float* __restrict__ outp, int n) {
    const int idx = blockIdx.x * 256 + threadIdx.x;
    if (idx >= n) return;
    float s = 0.f;
    #pragma unroll
    for (int kc = 0; kc < KSPLIT; ++kc)
        s += part[(size_t)kc * n + idx];
    outp[idx] = s;
}

// ===========================================================================
// bf16 helpers
// ===========================================================================
__device__ __forceinline__ u16 rne_bf16(float x) {
    unsigned int u = __float_as_uint(x);
    unsigned int r = u + 0x7FFFu + ((u >> 16) & 1u);
    return (u16)(r >> 16);
}

// One pass converting: x -> (hi,lo); W_in -> hi; W_out -> hi.
__global__ void prep_kernel(const float* __restrict__ x,
                            const float* __restrict__ Win,
                            const float* __restrict__ Wout,
                            u16* __restrict__ xhi, u16* __restrict__ xlo,
                            u16* __restrict__ winh, u16* __restrict__ wouth) {
    const size_t M2 = 2u * 1024u * 1024u;
    size_t i = ((size_t)blockIdx.x * 256 + threadIdx.x) * 8;
    if (i < M2) {
        float4 a = *reinterpret_cast<const float4*>(&x[i]);
        float4 b = *reinterpret_cast<const float4*>(&x[i + 4]);
        float xs[8] = {a.x, a.y, a.z, a.w, b.x, b.y, b.z, b.w};
        unsigned int hw[4], lw[4];
        #pragma unroll
        for (int q = 0; q < 4; ++q) {
            u16 h0 = rne_bf16(xs[2*q]);
            u16 h1 = rne_bf16(xs[2*q+1]);
            float d0 = xs[2*q]   - __uint_as_float((unsigned int)h0 << 16);
            float d1 = xs[2*q+1] - __uint_as_float((unsigned int)h1 << 16);
            hw[q] = (unsigned int)h0 | ((unsigned int)h1 << 16);
            lw[q] = (unsigned int)rne_bf16(d0) | ((unsigned int)rne_bf16(d1) << 16);
        }
        *reinterpret_cast<v4i*>(&xhi[i]) = *reinterpret_cast<v4i*>(hw);
        *reinterpret_cast<v4i*>(&xlo[i]) = *reinterpret_cast<v4i*>(lw);
    } else if (i < 3 * M2) {
        size_t j = i - M2;
        float4 a = *reinterpret_cast<const float4*>(&Win[j]);
        float4 b = *reinterpret_cast<const float4*>(&Win[j + 4]);
        float xs[8] = {a.x, a.y, a.z, a.w, b.x, b.y, b.z, b.w};
        unsigned int hw[4];
        #pragma unroll
        for (int q = 0; q < 4; ++q)
            hw[q] = (unsigned int)rne_bf16(xs[2*q]) | ((unsigned int)rne_bf16(xs[2*q+1]) << 16);
        *reinterpret_cast<v4i*>(&winh[j]) = *reinterpret_cast<v4i*>(hw);
    } else {
        size_t j = i - 3 * M2;
        float4 a = *reinterpret_cast<const float4*>(&Wout[j]);
        float4 b = *reinterpret_cast<const float4*>(&Wout[j + 4]);
        float xs[8] = {a.x, a.y, a.z, a.w, b.x, b.y, b.z, b.w};
        unsigned int hw[4];
        #pragma unroll
        for (int q = 0; q < 4; ++q)
            hw[q] = (unsigned int)rne_bf16(xs[2*q]) | ((unsigned int)rne_bf16(xs[2*q+1]) << 16);
        *reinterpret_cast<v4i*>(&wouth[j]) = *reinterpret_cast<v4i*>(hw);
    }
}

// ===========================================================================
// 2-term split-bf16 MFMA GEMM: C = (Ahi+Alo) @ Bhi^T, fp32 accumulate.
// ===========================================================================
#define MFMA_B16(ACC, Af, Bf) \
    asm("v_mfma_f32_16x16x32_bf16 %0, %1, %2, %0" : "+v"(ACC) : "v"(Af), "v"(Bf))

template<int BM, int BN, int WM, int WN>
__launch_bounds__(256)
__global__ void gemm_mfma2(const u16* __restrict__ Ahi, const u16* __restrict__ Alo, int lda,
                           const u16* __restrict__ Bhi, int ldb,
                           float* __restrict__ C, int ldc, int K) {
    constexpr int ACH = BM / 64;
    constexpr int BCH = BN / 64;
    constexpr int WMF = WM / 16;
    constexpr int WNF = WN / 16;
    constexpr int SA  = BM * 40;
    constexpr int SB  = BN * 40;
    constexpr int BUFSZ = 2 * SA + SB;
    constexpr int WCOLS = BN / WN;

    __shared__ u16 smem[2 * BUFSZ];

    const int tid  = threadIdx.x;
    const int lane = tid & 63;
    const int wave = tid >> 6;
    const int wr   = wave / WCOLS, wc = wave % WCOLS;
    const int m0   = blockIdx.y * BM, n0 = blockIdx.x * BN;

    size_t aBase[ACH]; int aW[ACH];
    #pragma unroll
    for (int q = 0; q < ACH; ++q) {
        int c = tid + q * 256, row = c >> 2, slot = c & 3;
        aBase[q] = (size_t)(m0 + row) * lda + slot * 8;
        aW[q] = row * 40 + slot * 8;
    }
    size_t bBase[BCH]; int bW[BCH];
    #pragma unroll
    for (int q = 0; q < BCH; ++q) {
        int c = tid + q * 256, row = c >> 2, slot = c & 3;
        bBase[q] = (size_t)(n0 + row) * ldb + slot * 8;
        bW[q] = row * 40 + slot * 8;
    }

    const int fr = lane & 15;
    const int fk = (lane >> 4) * 8;
    const int fq = lane >> 4;
    int aOff[WMF], bOff[WNF];
    #pragma unroll
    for (int i = 0; i < WMF; ++i) aOff[i] = (wr * WM + i * 16 + fr) * 40 + fk;
    #pragma unroll
    for (int j = 0; j < WNF; ++j) bOff[j] = (wc * WN + j * 16 + fr) * 40 + fk;

    v4f acc[WMF][WNF];
    #pragma unroll
    for (int i = 0; i < WMF; ++i)
        #pragma unroll
        for (int j = 0; j < WNF; ++j)
            acc[i][j] = (v4f)0.f;

    v4i rAh[ACH], rAl[ACH], rBh[BCH];
    #pragma unroll
    for (int q = 0; q < ACH; ++q) {
        rAh[q] = *reinterpret_cast<const v4i*>(Ahi + aBase[q]);
        rAl[q] = *reinterpret_cast<const v4i*>(Alo + aBase[q]);
    }
    #pragma unroll
    for (int q = 0; q < BCH; ++q)
        rBh[q] = *reinterpret_cast<const v4i*>(Bhi + bBase[q]);
    #pragma unroll
    for (int q = 0; q < ACH; ++q) {
        *reinterpret_cast<v4i*>(&smem[aW[q]]) = rAh[q];
        *reinterpret_cast<v4i*>(&smem[SA + aW[q]]) = rAl[q];
    }
    #pragma unroll
    for (int q = 0; q < BCH; ++q)
        *reinterpret_cast<v4i*>(&smem[2 * SA + bW[q]]) = rBh[q];
    __syncthreads();

    const int NK = K / 32;
    for (int k = 0; k < NK; ++k) {
        u16* sc = smem + (k & 1) * BUFSZ;
        if (k + 1 < NK) {
            const int k0 = (k + 1) * 32;
            #pragma unroll
            for (int q = 0; q < ACH; ++q) {
                rAh[q] = *reinterpret_cast<const v4i*>(Ahi + aBase[q] + k0);
                rAl[q] = *reinterpret_cast<const v4i*>(Alo + aBase[q] + k0);
            }
            #pragma unroll
            for (int q = 0; q < BCH; ++q)
                rBh[q] = *reinterpret_cast<const v4i*>(Bhi + bBase[q] + k0);
        }

        v4i ah[WMF], al[WMF];
        #pragma unroll
        for (int i = 0; i < WMF; ++i) {
            ah[i] = *reinterpret_cast<const v4i*>(&sc[aOff[i]]);
            al[i] = *reinterpret_cast<const v4i*>(&sc[SA + aOff[i]]);
        }
        #pragma unroll
        for (int j = 0; j < WNF; ++j) {
            v4i bh = *reinterpret_cast<const v4i*>(&sc[2 * SA + bOff[j]]);
            #pragma unroll
            for (int i = 0; i < WMF; ++i) {
                MFMA_B16(acc[i][j], ah[i], bh);
                MFMA_B16(acc[i][j], al[i], bh);
            }
        }

        if (k + 1 < NK) {
            u16* sn = smem + ((k + 1) & 1) * BUFSZ;
            #pragma unroll
            for (int q = 0; q < ACH; ++q) {
                *reinterpret_cast<v4i*>(&sn[aW[q]]) = rAh[q];
                *reinterpret_cast<v4i*>(&sn[SA + aW[q]]) = rAl[q];
            }
            #pragma unroll
            for (int q = 0; q < BCH; ++q)
                *reinterpret_cast<v4i*>(&sn[2 * SA + bW[q]]) = rBh[q];
            __syncthreads();
        }
    }

    asm volatile("s_nop 7\n\ts_nop 7\n\ts_nop 7" ::: "memory");

    #pragma unroll
    for (int i = 0; i < WMF; ++i) {
        const int row = m0 + wr * WM + i * 16 + fq * 4;
        #pragma unroll
        for (int j = 0; j < WNF; ++j) {
            const int col = n0 + wc * WN + j * 16 + fr;
            #pragma unroll
            for (int r = 0; r < 4; ++r)
                C[(size_t)(row + r) * ldc + col] = acc[i][j][r];
        }
    }
}

// ===========================================================================
// Depthwise causal conv (width 4) + bias + SiLU.
// ===========================================================================
__global__ void conv_silu_kernel(const float* __restrict__ x_in, int xld,
                                 const float* __restrict__ w,
                                 const float* __restrict__ b,
                                 float* __restrict__ x_act) {
    const int idx = blockIdx.x * blockDim.x + threadIdx.x;
    const int ch = idx % D_INNER;
    const int m  = idx / D_INNER;
    const int t  = m % SEQ;

    float acc = b[ch];
    #pragma unroll
    for (int j = 0; j < D_CONV; ++j) {
        int tt = t - (D_CONV - 1) + j;
        if (tt >= 0)
            acc = fmaf(w[ch * D_CONV + j], x_in[(size_t)(m - (D_CONV - 1) + j) * xld + ch], acc);
    }
    x_act[idx] = acc / (1.f + __expf(-acc));
}

// ===========================================================================
// Chunked selective scan. NCHUNK=32, CLEN=32. 8-deep load batching.
// __launch_bounds__(256,2): VGPR cap 256 -> no scratch spill (round-6 bug:
// default clamp at 64 VGPR spilled A/h/Pp arrays -> 10x HBM traffic).
// ===========================================================================
__launch_bounds__(256, 2)
__global__ void scan_part1(const float* __restrict__ dt,
                           const float* __restrict__ x_act,
                           const float* __restrict__ dbc,
                           const float* __restrict__ A_log,
                           float* __restrict__ P, float* __restrict__ F) {
    __shared__ float Bsh[CLEN][D_STATE];
    const int tid = threadIdx.x;
    const int d = blockIdx.x * 256 + tid;
    const int c = blockIdx.y;
    const int b = blockIdx.z;
    const int mbase = b * SEQ + c * CLEN;

    {   // stage B rows: CLEN*16 = 512 floats, 2 per thread
        const int s = tid & 15, t0 = tid >> 4;
        #pragma unroll
        for (int q = 0; q < 2; ++q)
            Bsh[t0 + 16 * q][s] = dbc[(size_t)(mbase + t0 + 16 * q) * 96 + DT_RANK + s];
    }
    float A[16];
    #pragma unroll
    for (int q = 0; q < 4; ++q) {
        float4 v = *reinterpret_cast<const float4*>(&A_log[d * 16 + q * 4]);
        A[q*4+0] = -__expf(v.x); A[q*4+1] = -__expf(v.y);
        A[q*4+2] = -__expf(v.z); A[q*4+3] = -__expf(v.w);
    }
    __syncthreads();

    float h[16] = {};
    float Pp[16];
    #pragma unroll
    for (int s = 0; s < 16; ++s) Pp[s] = 1.f;

    for (int t0 = 0; t0 < CLEN; t0 += 8) {
        float dtb[8], ub[8];
        #pragma unroll
        for (int q = 0; q < 8; ++q) {
            const int m = mbase + t0 + q;
            dtb[q] = dt[(size_t)m * D_INNER + d];
            ub[q]  = x_act[(size_t)m * D_INNER + d];
        }
        #pragma unroll
        for (int q = 0; q < 8; ++q) {
            const float dtv = dtb[q];
            const float du  = dtv * ub[q];
            float Bv[16];
            #pragma unroll
            for (int r = 0; r < 4; ++r) {
                float4 v = *reinterpret_cast<const float4*>(&Bsh[t0 + q][r * 4]);
                Bv[r*4+0] = v.x; Bv[r*4+1] = v.y; Bv[r*4+2] = v.z; Bv[r*4+3] = v.w;
            }
            #pragma unroll
            for (int s = 0; s < 16; ++s) {
                const float dA = __expf(dtv * A[s]);
                Pp[s] *= dA;
                h[s] = fmaf(dA, h[s], du * Bv[s]);
            }
        }
    }
    const size_t base = ((size_t)(b * NCHUNK + c) * 16) * D_INNER + d;
    #pragma unroll
    for (int s = 0; s < 16; ++s) {
        P[base + (size_t)s * D_INNER] = Pp[s];
        F[base + (size_t)s * D_INNER] = h[s];
    }
}

// Batch-load all chunk summaries to registers, serial combine, store back.
__launch_bounds__(256, 2)
__global__ void scan_combine(const float* __restrict__ P, float* F) {
    const int idx = blockIdx.x * 256 + threadIdx.x;    // over B*16*D_INNER
    const int d  = idx % D_INNER;
    const int bs = idx / D_INNER;
    const int b  = bs >> 4, s = bs & 15;
    const size_t base0 = ((size_t)b * NCHUNK * 16 + s) * D_INNER + d;
    const size_t cstep = (size_t)16 * D_INNER;

    float Pv[NCHUNK], Fv[NCHUNK];
    #pragma unroll
    for (int c = 0; c < NCHUNK; ++c) {
        Pv[c] = P[base0 + c * cstep];
        Fv[c] = F[base0 + c * cstep];
    }
    float G = 0.f;
    #pragma unroll
    for (int c = 0; c < NCHUNK; ++c) {
        const float f = Fv[c];
        Fv[c] = G;                       // initial state for chunk c
        G = fmaf(Pv[c], G, f);
    }
    #pragma unroll
    for (int c = 0; c < NCHUNK; ++c)
        F[base0 + c * cstep] = Fv[c];
}

// BF16OUT=1: emit yf as bf16 (hi,lo) for the MFMA out_proj.
// BF16OUT=0: fp32 yf (fallback; zp may alias yf -> z loaded before stores).
template<int BF16OUT>
__launch_bounds__(256, 2)
__global__ void scan_part2(const float* __restrict__ dt,
                           const float* __restrict__ x_act,
                           const float* __restrict__ dbc,
                           const float* __restrict__ A_log,
                           const float* __restrict__ Dp,
                           const float* __restrict__ Ginit,
                           const float* zp, int zld,
                           float* yf, u16* yh, u16* yl) {
    __shared__ float BCs[CLEN][32];   // [t][0:16]=B, [16:32]=C ; 4 KB
    const int tid = threadIdx.x;
    const int d = blockIdx.x * 256 + tid;
    const int c = blockIdx.y;
    const int b = blockIdx.z;
    const int mbase = b * SEQ + c * CLEN;

    {   // stage B+C: CLEN*32 = 1024 floats, one float4 per thread
        const int t0 = tid >> 3;            // 0..31
        const int j  = (tid & 7) * 4;       // 0..28
        float4 v = *reinterpret_cast<const float4*>(
            &dbc[(size_t)(mbase + t0) * 96 + DT_RANK + j]);
        *reinterpret_cast<float4*>(&BCs[t0][j]) = v;
    }
    float A[16];
    #pragma unroll
    for (int q = 0; q < 4; ++q) {
        float4 v = *reinterpret_cast<const float4*>(&A_log[d * 16 + q * 4]);
        A[q*4+0] = -__expf(v.x); A[q*4+1] = -__expf(v.y);
        A[q*4+2] = -__expf(v.z); A[q*4+3] = -__expf(v.w);
    }
    float h[16];
    const size_t gbase = ((size_t)(b * NCHUNK + c) * 16) * D_INNER + d;
    #pragma unroll
    for (int s = 0; s < 16; ++s) h[s] = Ginit[gbase + (size_t)s * D_INNER];
    const float Dv = Dp[d];
    __syncthreads();

    for (int t0 = 0; t0 < CLEN; t0 += 8) {
        float dtb[8], ub[8], zb[8];
        #pragma unroll
        for (int q = 0; q < 8; ++q) {
            const int m = mbase + t0 + q;
            dtb[q] = dt[(size_t)m * D_INNER + d];
            ub[q]  = x_act[(size_t)m * D_INNER + d];
            zb[q]  = zp[(size_t)m * zld + d];
        }
        #pragma unroll
        for (int q = 0; q < 8; ++q) {
            const int m = mbase + t0 + q;
            const float dtv = dtb[q];
            const float u   = ub[q];
            const float du  = dtv * u;
            float Bv[16], Cv[16];
            #pragma unroll
            for (int r = 0; r < 4; ++r) {
                float4 vb = *reinterpret_cast<const float4*>(&BCs[t0 + q][r * 4]);
                float4 vc = *reinterpret_cast<const float4*>(&BCs[t0 + q][16 + r * 4]);
                Bv[r*4+0] = vb.x; Bv[r*4+1] = vb.y; Bv[r*4+2] = vb.z; Bv[r*4+3] = vb.w;
                Cv[r*4+0] = vc.x; Cv[r*4+1] = vc.y; Cv[r*4+2] = vc.z; Cv[r*4+3] = vc.w;
            }
            float y0 = 0.f, y1 = 0.f;
            #pragma unroll
            for (int s = 0; s < 16; s += 2) {
                const float dA0 = __expf(dtv * A[s]);
                const float dA1 = __expf(dtv * A[s + 1]);
                h[s]     = fmaf(dA0, h[s],     du * Bv[s]);
                h[s + 1] = fmaf(dA1, h[s + 1], du * Bv[s + 1]);
                y0 = fmaf(h[s],     Cv[s],     y0);
                y1 = fmaf(h[s + 1], Cv[s + 1], y1);
            }
            float y = y0 + y1;
            y = fmaf(u, Dv, y);
            const float zv = zb[q];
            const float g  = zv / (1.f + __expf(-zv));
            const float val = y * g;
            if (BF16OUT) {
                const u16 hh = rne_bf16(val);
                yh[(size_t)m * D_INNER + d] = hh;
                yl[(size_t)m * D_INNER + d] =
                    rne_bf16(val - __uint_as_float((unsigned int)hh << 16));
            } else {
                yf[(size_t)m * D_INNER + d] = val;
            }
        }
    }
}

// ===========================================================================
extern "C" void kernel_launch(void* const* d_in, const int* in_sizes, int n_in,
                              void* d_out, int out_size, void* d_ws, size_t ws_size,
                              hipStream_t stream) {
    const float* x      = (const float*)d_in[0];
    const float* W_in   = (const float*)d_in[1];
    const float* conv_w = (const float*)d_in[2];
    const float* conv_b = (const float*)d_in[3];
    const float* W_x    = (const float*)d_in[4];
    const float* W_dt   = (const float*)d_in[5];
    const float* b_dt   = (const float*)d_in[6];
    const float* A_log  = (const float*)d_in[7];
    const float* Dp     = (const float*)d_in[8];
    const float* W_out  = (const float*)d_in[9];
    float* out = (float*)d_out;

    const size_t M1 = 1024u * 1024u;
    // floats: xz 8M | x_act 4M | dbc .1875M | dt 4M
    // shorts: xhi 2M | xlo 2M | winh 4M | wouth 2M | yh 4M | yl 4M
    // P (2M floats) aliases xhi+xlo; F (2M floats) aliases winh (dead after
    // in_proj). dbc split-K partials alias yh/yl (dead until scan_part2).
    const size_t fXZ = 8 * M1, fXACT = 4 * M1, fDBC = (size_t)BT * 96,
                 fDT = 4 * M1;
    const size_t need = (fXZ + fXACT + fDBC + fDT) * 4 + 18 * M1 * 2;

    if (ws_size >= need) {
        float* ws    = (float*)d_ws;
        float* xz    = ws;
        float* x_act = xz    + fXZ;
        float* dbc   = x_act + fXACT;
        float* dtbuf = dbc   + fDBC;
        u16* xhi   = (u16*)(dtbuf + fDT);
        u16* xlo   = xhi   + 2 * M1;
        u16* winh  = xlo   + 2 * M1;
        u16* wouth = winh  + 4 * M1;
        u16* yh    = wouth + 2 * M1;   // 4M shorts
        u16* yl    = yh    + 4 * M1;   // 4M shorts
        float* Pbuf = (float*)xhi;     // 2M floats (xhi+xlo region)
        float* Fbuf = (float*)winh;    // 2M floats (winh region)
        float* dbc_part = (float*)yh;  // 12.6 MB < 16 MB

        // 1) convert: x -> hi/lo, W_in -> hi, W_out -> hi
        prep_kernel<<<dim3((8 * M1) / 2048), 256, 0, stream>>>(
            x, W_in, W_out, xhi, xlo, winh, wouth);

        // 2) in_proj: xz[2048][4096] = x @ W_in^T
        gemm_mfma2<128, 256, 64, 128><<<dim3(4096 / 256, BT / 128), 256, 0, stream>>>(
            xhi, xlo, D_MODEL, winh, D_MODEL, xz, 4096, D_MODEL);

        // 3) conv + SiLU (x_in = xz[:, :2048])
        conv_silu_kernel<<<dim3((BT * D_INNER) / 256), 256, 0, stream>>>(
            xz, 4096, conv_w, conv_b, x_act);

        // 4) dbc = x_act @ W_x^T (fp32 split-K)
        gemm_nt_splitk<64,32,16,4,4><<<dim3(96 / 32, BT / 64, KSPLIT), 128, 0, stream>>>(
            x_act, D_INNER, W_x, D_INNER, dbc_part, 96, D_INNER / KSPLIT);
        reduce_splitk<<<dim3((BT * 96 + 255) / 256), 256, 0, stream>>>(
            dbc_part, dbc, BT * 96);

        // 5) dt = softplus(dbc[:, :64] @ W_dt^T + b_dt) (fp32)
        gemm_nt<64,64,16,4,4,1><<<dim3(D_INNER / 64, BT / 64), 256, 0, stream>>>(
            dbc, 96, W_dt, DT_RANK, dtbuf, D_INNER, DT_RANK, b_dt);

        // 6) chunked scan + skip + gate; emit yf as bf16 hi/lo
        scan_part1<<<dim3(D_INNER / 256, NCHUNK, BATCH), 256, 0, stream>>>(
            dtbuf, x_act, dbc, A_log, Pbuf, Fbuf);
        scan_combine<<<dim3((BATCH * 16 * D_INNER) / 256), 256, 0, stream>>>(
            Pbuf, Fbuf);
        scan_part2<1><<<dim3(D_INNER / 256, NCHUNK, BATCH), 256, 0, stream>>>(
            dtbuf, x_act, dbc, A_log, Dp, Fbuf, xz + D_INNER, 4096,
            nullptr, yh, yl);

        // 7) out_proj: out = yf @ W_out^T
        gemm_mfma2<64, 128, 32, 64><<<dim3(D_MODEL / 128, BT / 64), 256, 0, stream>>>(
            yh, yl, D_INNER, wouth, D_INNER, out, D_MODEL, D_INNER);
    } else {
        // ------------------- fallback: all-fp32 path -----------------------
        float* ws    = (float*)d_ws;
        float* x_in  = ws;
        float* z     = x_in  + (size_t)BT * D_INNER;
        float* x_act = z     + (size_t)BT * D_INNER;
        float* dbc   = x_act + (size_t)BT * D_INNER;
        float* Pbuf  = dbc   + (size_t)BT * 96;
        float* Fbuf  = Pbuf  + (size_t)BATCH * NCHUNK * 16 * D_INNER;
        float* dtbuf = x_in;
        float* yf    = z;

        gemm_nt<64,64,16,4,4,0><<<dim3(D_INNER/64, BT/64), 256, 0, stream>>>(
            x, D_MODEL, W_in, D_MODEL, x_in, D_INNER, D_MODEL, nullptr);
        gemm_nt<64,64,16,4,4,0><<<dim3(D_INNER/64, BT/64), 256, 0, stream>>>(
            x, D_MODEL, W_in + (size_t)D_INNER * D_MODEL, D_MODEL, z, D_INNER, D_MODEL, nullptr);
        conv_silu_kernel<<<dim3((BT * D_INNER) / 256), 256, 0, stream>>>(
            x_in, D_INNER, conv_w, conv_b, x_act);
        gemm_nt<64,32,16,4,4,0><<<dim3(96/32, BT/64), 128, 0, stream>>>(
            x_act, D_INNER, W_x, D_INNER, dbc, 96, D_INNER, nullptr);
        gemm_nt<64,64,16,4,4,1><<<dim3(D_INNER/64, BT/64), 256, 0, stream>>>(
            dbc, 96, W_dt, DT_RANK, dtbuf, D_INNER, DT_RANK, b_dt);
        scan_part1<<<dim3(D_INNER/256, NCHUNK, BATCH), 256, 0, stream>>>(
            dtbuf, x_act, dbc, A_log, Pbuf, Fbuf);
        scan_combine<<<dim3((BATCH * 16 * D_INNER) / 256), 256, 0, stream>>>(
            Pbuf, Fbuf);
        scan_part2<0><<<dim3(D_INNER/256, NCHUNK, BATCH), 256, 0, stream>>>(
            dtbuf, x_act, dbc, A_log, Dp, Fbuf, z, D_INNER, yf, nullptr, nullptr);
        gemm_nt<64,64,16,4,4,0><<<dim3(D_MODEL/64, BT/64), 256, 0, stream>>>(
            yf, D_INNER, W_out, D_INNER, out, D_MODEL, D_INNER, nullptr);
    }
}

// Round 8
// 220.755 us; speedup vs baseline: 1.5148x; 1.3653x over previous
//
#include <hip/hip_runtime.h>
#include <math.h>

#define D_MODEL 1024
#define D_STATE 16
#define D_CONV  4
#define DT_RANK 64
#define D_INNER 2048
#define BATCH   2
#define SEQ     1024
#define BT      (BATCH*SEQ)   // 2048 rows
#define NCHUNK  32
#define CLEN    (SEQ/NCHUNK)  // 32
#define KSPLIT  16            // split-K factor for dbc GEMM

typedef int   v4i __attribute__((ext_vector_type(4)));
typedef float v4f __attribute__((ext_vector_type(4)));
typedef unsigned short u16;

// ===========================================================================
// fp32 GEMM (dt projection + fallback path)
// ===========================================================================
template<int BM, int BN, int BK, int TM, int TN, int EPI>
__launch_bounds__(256)
__global__ void gemm_nt(const float* __restrict__ A, int lda,
                        const float* __restrict__ B, int ldb,
                        float* __restrict__ C, int ldc,
                        int K, const float* __restrict__ bias) {
    constexpr int BX = BN / TN;
    constexpr int BY = BM / TM;
    constexpr int THREADS = BX * BY;

    __shared__ float As[BK][BM + 1];
    __shared__ float Bs[BK][BN + 1];

    const int tid = threadIdx.x;
    const int tx  = tid % BX;
    const int ty  = tid / BX;
    const int m0  = blockIdx.y * BM;
    const int n0  = blockIdx.x * BN;

    float acc[TM][TN] = {};

    for (int k0 = 0; k0 < K; k0 += BK) {
        #pragma unroll
        for (int l = 0; l < (BM * BK) / (THREADS * 4); ++l) {
            int idx = (tid + l * THREADS) * 4;
            int row = idx / BK, col = idx % BK;
            const float4 v = *reinterpret_cast<const float4*>(
                &A[(size_t)(m0 + row) * lda + k0 + col]);
            As[col + 0][row] = v.x; As[col + 1][row] = v.y;
            As[col + 2][row] = v.z; As[col + 3][row] = v.w;
        }
        #pragma unroll
        for (int l = 0; l < (BN * BK) / (THREADS * 4); ++l) {
            int idx = (tid + l * THREADS) * 4;
            int row = idx / BK, col = idx % BK;
            const float4 v = *reinterpret_cast<const float4*>(
                &B[(size_t)(n0 + row) * ldb + k0 + col]);
            Bs[col + 0][row] = v.x; Bs[col + 1][row] = v.y;
            Bs[col + 2][row] = v.z; Bs[col + 3][row] = v.w;
        }
        __syncthreads();

        #pragma unroll
        for (int kk = 0; kk < BK; ++kk) {
            float a[TM], b[TN];
            #pragma unroll
            for (int i = 0; i < TM; ++i) a[i] = As[kk][ty * TM + i];
            #pragma unroll
            for (int j = 0; j < TN; ++j) b[j] = Bs[kk][tx * TN + j];
            #pragma unroll
            for (int i = 0; i < TM; ++i)
                #pragma unroll
                for (int j = 0; j < TN; ++j)
                    acc[i][j] = fmaf(a[i], b[j], acc[i][j]);
        }
        __syncthreads();
    }

    #pragma unroll
    for (int i = 0; i < TM; ++i) {
        float* outp = &C[(size_t)(m0 + ty * TM + i) * ldc + n0 + tx * TN];
        float vals[4];
        #pragma unroll
        for (int j = 0; j < TN; ++j) {
            float val = acc[i][j];
            if (EPI == 1) {
                val += bias[n0 + tx * TN + j];
                val = (val > 20.f) ? val : log1pf(expf(val));
            }
            vals[j] = val;
        }
        float4 v;
        v.x = vals[0]; v.y = vals[1]; v.z = vals[2]; v.w = vals[3];
        *reinterpret_cast<float4*>(outp) = v;
    }
}

// ===========================================================================
// Split-K fp32 GEMM for the skinny dbc projection (N=96, K=2048).
// ===========================================================================
template<int BM, int BN, int BK, int TM, int TN>
__launch_bounds__(128)
__global__ void gemm_nt_splitk(const float* __restrict__ A, int lda,
                               const float* __restrict__ B, int ldb,
                               float* __restrict__ part, int N, int kchunk) {
    constexpr int BX = BN / TN;
    constexpr int BY = BM / TM;
    constexpr int THREADS = BX * BY;

    __shared__ float As[BK][BM + 1];
    __shared__ float Bs[BK][BN + 1];

    const int tid = threadIdx.x;
    const int tx  = tid % BX;
    const int ty  = tid / BX;
    const int m0  = blockIdx.y * BM;
    const int n0  = blockIdx.x * BN;
    const int kb  = blockIdx.z * kchunk;

    float acc[TM][TN] = {};

    for (int k0 = kb; k0 < kb + kchunk; k0 += BK) {
        #pragma unroll
        for (int l = 0; l < (BM * BK) / (THREADS * 4); ++l) {
            int idx = (tid + l * THREADS) * 4;
            int row = idx / BK, col = idx % BK;
            const float4 v = *reinterpret_cast<const float4*>(
                &A[(size_t)(m0 + row) * lda + k0 + col]);
            As[col + 0][row] = v.x; As[col + 1][row] = v.y;
            As[col + 2][row] = v.z; As[col + 3][row] = v.w;
        }
        #pragma unroll
        for (int l = 0; l < (BN * BK) / (THREADS * 4); ++l) {
            int idx = (tid + l * THREADS) * 4;
            int row = idx / BK, col = idx % BK;
            const float4 v = *reinterpret_cast<const float4*>(
                &B[(size_t)(n0 + row) * ldb + k0 + col]);
            Bs[col + 0][row] = v.x; Bs[col + 1][row] = v.y;
            Bs[col + 2][row] = v.z; Bs[col + 3][row] = v.w;
        }
        __syncthreads();

        #pragma unroll
        for (int kk = 0; kk < BK; ++kk) {
            float a[TM], b[TN];
            #pragma unroll
            for (int i = 0; i < TM; ++i) a[i] = As[kk][ty * TM + i];
            #pragma unroll
            for (int j = 0; j < TN; ++j) b[j] = Bs[kk][tx * TN + j];
            #pragma unroll
            for (int i = 0; i < TM; ++i)
                #pragma unroll
                for (int j = 0; j < TN; ++j)
                    acc[i][j] = fmaf(a[i], b[j], acc[i][j]);
        }
        __syncthreads();
    }

    float* base = part + (size_t)blockIdx.z * BT * N;
    #pragma unroll
    for (int i = 0; i < TM; ++i) {
        float* outp = &base[(size_t)(m0 + ty * TM + i) * N + n0 + tx * TN];
        float4 v;
        v.x = acc[i][0]; v.y = acc[i][1]; v.z = acc[i][2]; v.w = acc[i][3];
        *reinterpret_cast<float4*>(outp) = v;
    }
}

__global__ void reduce_splitk(const float* __restrict__ part,
                              float* __restrict__ outp, int n) {
    const int idx = blockIdx.x * 256 + threadIdx.x;
    if (idx >= n) return;
    float s = 0.f;
    #pragma unroll
    for (int kc = 0; kc < KSPLIT; ++kc)
        s += part[(size_t)kc * n + idx];
    outp[idx] = s;
}

// ===========================================================================
// bf16 helpers
// ===========================================================================
__device__ __forceinline__ u16 rne_bf16(float x) {
    unsigned int u = __float_as_uint(x);
    unsigned int r = u + 0x7FFFu + ((u >> 16) & 1u);
    return (u16)(r >> 16);
}

// One pass converting: x -> (hi,lo); W_in -> hi; W_out -> hi.
__global__ void prep_kernel(const float* __restrict__ x,
                            const float* __restrict__ Win,
                            const float* __restrict__ Wout,
                            u16* __restrict__ xhi, u16* __restrict__ xlo,
                            u16* __restrict__ winh, u16* __restrict__ wouth) {
    const size_t M2 = 2u * 1024u * 1024u;
    size_t i = ((size_t)blockIdx.x * 256 + threadIdx.x) * 8;
    if (i < M2) {
        float4 a = *reinterpret_cast<const float4*>(&x[i]);
        float4 b = *reinterpret_cast<const float4*>(&x[i + 4]);
        float xs[8] = {a.x, a.y, a.z, a.w, b.x, b.y, b.z, b.w};
        unsigned int hw[4], lw[4];
        #pragma unroll
        for (int q = 0; q < 4; ++q) {
            u16 h0 = rne_bf16(xs[2*q]);
            u16 h1 = rne_bf16(xs[2*q+1]);
            float d0 = xs[2*q]   - __uint_as_float((unsigned int)h0 << 16);
            float d1 = xs[2*q+1] - __uint_as_float((unsigned int)h1 << 16);
            hw[q] = (unsigned int)h0 | ((unsigned int)h1 << 16);
            lw[q] = (unsigned int)rne_bf16(d0) | ((unsigned int)rne_bf16(d1) << 16);
        }
        *reinterpret_cast<v4i*>(&xhi[i]) = *reinterpret_cast<v4i*>(hw);
        *reinterpret_cast<v4i*>(&xlo[i]) = *reinterpret_cast<v4i*>(lw);
    } else if (i < 3 * M2) {
        size_t j = i - M2;
        float4 a = *reinterpret_cast<const float4*>(&Win[j]);
        float4 b = *reinterpret_cast<const float4*>(&Win[j + 4]);
        float xs[8] = {a.x, a.y, a.z, a.w, b.x, b.y, b.z, b.w};
        unsigned int hw[4];
        #pragma unroll
        for (int q = 0; q < 4; ++q)
            hw[q] = (unsigned int)rne_bf16(xs[2*q]) | ((unsigned int)rne_bf16(xs[2*q+1]) << 16);
        *reinterpret_cast<v4i*>(&winh[j]) = *reinterpret_cast<v4i*>(hw);
    } else {
        size_t j = i - 3 * M2;
        float4 a = *reinterpret_cast<const float4*>(&Wout[j]);
        float4 b = *reinterpret_cast<const float4*>(&Wout[j + 4]);
        float xs[8] = {a.x, a.y, a.z, a.w, b.x, b.y, b.z, b.w};
        unsigned int hw[4];
        #pragma unroll
        for (int q = 0; q < 4; ++q)
            hw[q] = (unsigned int)rne_bf16(xs[2*q]) | ((unsigned int)rne_bf16(xs[2*q+1]) << 16);
        *reinterpret_cast<v4i*>(&wouth[j]) = *reinterpret_cast<v4i*>(hw);
    }
}

// ===========================================================================
// 2-term split-bf16 MFMA GEMM: C = (Ahi+Alo) @ Bhi^T, fp32 accumulate.
// ===========================================================================
#define MFMA_B16(ACC, Af, Bf) \
    asm("v_mfma_f32_16x16x32_bf16 %0, %1, %2, %0" : "+v"(ACC) : "v"(Af), "v"(Bf))

template<int BM, int BN, int WM, int WN>
__launch_bounds__(256)
__global__ void gemm_mfma2(const u16* __restrict__ Ahi, const u16* __restrict__ Alo, int lda,
                           const u16* __restrict__ Bhi, int ldb,
                           float* __restrict__ C, int ldc, int K) {
    constexpr int ACH = BM / 64;
    constexpr int BCH = BN / 64;
    constexpr int WMF = WM / 16;
    constexpr int WNF = WN / 16;
    constexpr int SA  = BM * 40;
    constexpr int SB  = BN * 40;
    constexpr int BUFSZ = 2 * SA + SB;
    constexpr int WCOLS = BN / WN;

    __shared__ u16 smem[2 * BUFSZ];

    const int tid  = threadIdx.x;
    const int lane = tid & 63;
    const int wave = tid >> 6;
    const int wr   = wave / WCOLS, wc = wave % WCOLS;
    const int m0   = blockIdx.y * BM, n0 = blockIdx.x * BN;

    size_t aBase[ACH]; int aW[ACH];
    #pragma unroll
    for (int q = 0; q < ACH; ++q) {
        int c = tid + q * 256, row = c >> 2, slot = c & 3;
        aBase[q] = (size_t)(m0 + row) * lda + slot * 8;
        aW[q] = row * 40 + slot * 8;
    }
    size_t bBase[BCH]; int bW[BCH];
    #pragma unroll
    for (int q = 0; q < BCH; ++q) {
        int c = tid + q * 256, row = c >> 2, slot = c & 3;
        bBase[q] = (size_t)(n0 + row) * ldb + slot * 8;
        bW[q] = row * 40 + slot * 8;
    }

    const int fr = lane & 15;
    const int fk = (lane >> 4) * 8;
    const int fq = lane >> 4;
    int aOff[WMF], bOff[WNF];
    #pragma unroll
    for (int i = 0; i < WMF; ++i) aOff[i] = (wr * WM + i * 16 + fr) * 40 + fk;
    #pragma unroll
    for (int j = 0; j < WNF; ++j) bOff[j] = (wc * WN + j * 16 + fr) * 40 + fk;

    v4f acc[WMF][WNF];
    #pragma unroll
    for (int i = 0; i < WMF; ++i)
        #pragma unroll
        for (int j = 0; j < WNF; ++j)
            acc[i][j] = (v4f)0.f;

    v4i rAh[ACH], rAl[ACH], rBh[BCH];
    #pragma unroll
    for (int q = 0; q < ACH; ++q) {
        rAh[q] = *reinterpret_cast<const v4i*>(Ahi + aBase[q]);
        rAl[q] = *reinterpret_cast<const v4i*>(Alo + aBase[q]);
    }
    #pragma unroll
    for (int q = 0; q < BCH; ++q)
        rBh[q] = *reinterpret_cast<const v4i*>(Bhi + bBase[q]);
    #pragma unroll
    for (int q = 0; q < ACH; ++q) {
        *reinterpret_cast<v4i*>(&smem[aW[q]]) = rAh[q];
        *reinterpret_cast<v4i*>(&smem[SA + aW[q]]) = rAl[q];
    }
    #pragma unroll
    for (int q = 0; q < BCH; ++q)
        *reinterpret_cast<v4i*>(&smem[2 * SA + bW[q]]) = rBh[q];
    __syncthreads();

    const int NK = K / 32;
    for (int k = 0; k < NK; ++k) {
        u16* sc = smem + (k & 1) * BUFSZ;
        if (k + 1 < NK) {
            const int k0 = (k + 1) * 32;
            #pragma unroll
            for (int q = 0; q < ACH; ++q) {
                rAh[q] = *reinterpret_cast<const v4i*>(Ahi + aBase[q] + k0);
                rAl[q] = *reinterpret_cast<const v4i*>(Alo + aBase[q] + k0);
            }
            #pragma unroll
            for (int q = 0; q < BCH; ++q)
                rBh[q] = *reinterpret_cast<const v4i*>(Bhi + bBase[q] + k0);
        }

        v4i ah[WMF], al[WMF];
        #pragma unroll
        for (int i = 0; i < WMF; ++i) {
            ah[i] = *reinterpret_cast<const v4i*>(&sc[aOff[i]]);
            al[i] = *reinterpret_cast<const v4i*>(&sc[SA + aOff[i]]);
        }
        #pragma unroll
        for (int j = 0; j < WNF; ++j) {
            v4i bh = *reinterpret_cast<const v4i*>(&sc[2 * SA + bOff[j]]);
            #pragma unroll
            for (int i = 0; i < WMF; ++i) {
                MFMA_B16(acc[i][j], ah[i], bh);
                MFMA_B16(acc[i][j], al[i], bh);
            }
        }

        if (k + 1 < NK) {
            u16* sn = smem + ((k + 1) & 1) * BUFSZ;
            #pragma unroll
            for (int q = 0; q < ACH; ++q) {
                *reinterpret_cast<v4i*>(&sn[aW[q]]) = rAh[q];
                *reinterpret_cast<v4i*>(&sn[SA + aW[q]]) = rAl[q];
            }
            #pragma unroll
            for (int q = 0; q < BCH; ++q)
                *reinterpret_cast<v4i*>(&sn[2 * SA + bW[q]]) = rBh[q];
            __syncthreads();
        }
    }

    asm volatile("s_nop 7\n\ts_nop 7\n\ts_nop 7" ::: "memory");

    #pragma unroll
    for (int i = 0; i < WMF; ++i) {
        const int row = m0 + wr * WM + i * 16 + fq * 4;
        #pragma unroll
        for (int j = 0; j < WNF; ++j) {
            const int col = n0 + wc * WN + j * 16 + fr;
            #pragma unroll
            for (int r = 0; r < 4; ++r)
                C[(size_t)(row + r) * ldc + col] = acc[i][j][r];
        }
    }
}

// ===========================================================================
// Depthwise causal conv (width 4) + bias + SiLU.
// ===========================================================================
__global__ void conv_silu_kernel(const float* __restrict__ x_in, int xld,
                                 const float* __restrict__ w,
                                 const float* __restrict__ b,
                                 float* __restrict__ x_act) {
    const int idx = blockIdx.x * blockDim.x + threadIdx.x;
    const int ch = idx % D_INNER;
    const int m  = idx / D_INNER;
    const int t  = m % SEQ;

    float acc = b[ch];
    #pragma unroll
    for (int j = 0; j < D_CONV; ++j) {
        int tt = t - (D_CONV - 1) + j;
        if (tt >= 0)
            acc = fmaf(w[ch * D_CONV + j], x_in[(size_t)(m - (D_CONV - 1) + j) * xld + ch], acc);
    }
    x_act[idx] = acc / (1.f + __expf(-acc));
}

// ===========================================================================
// Chunked selective scan. NCHUNK=32 (512 blocks, 8 waves/CU) with the
// round-5 simple per-step bodies (VGPR ~56, no spill). NOTE: no manual
// load batching here — h/Pp/A[16x3] leaves no VGPR headroom (round 6/7
// lesson: batching arrays -> scratch spill -> 10x HBM traffic).
// ===========================================================================
__launch_bounds__(256)
__global__ void scan_part1(const float* __restrict__ dt,
                           const float* __restrict__ x_act,
                           const float* __restrict__ dbc,
                           const float* __restrict__ A_log,
                           float* __restrict__ P, float* __restrict__ F) {
    __shared__ float Bsh[CLEN][D_STATE];   // 2 KB
    const int tid = threadIdx.x;
    const int d = blockIdx.x * 256 + tid;
    const int c = blockIdx.y;
    const int b = blockIdx.z;
    const int mbase = b * SEQ + c * CLEN;

    {   // stage B rows: CLEN*16 = 512 floats, 2 per thread
        const int s = tid & 15, t0 = tid >> 4;
        #pragma unroll
        for (int q = 0; q < 2; ++q)
            Bsh[t0 + 16 * q][s] = dbc[(size_t)(mbase + t0 + 16 * q) * 96 + DT_RANK + s];
    }
    float A[16];
    #pragma unroll
    for (int q = 0; q < 4; ++q) {
        float4 v = *reinterpret_cast<const float4*>(&A_log[d * 16 + q * 4]);
        A[q*4+0] = -__expf(v.x); A[q*4+1] = -__expf(v.y);
        A[q*4+2] = -__expf(v.z); A[q*4+3] = -__expf(v.w);
    }
    __syncthreads();

    float h[16] = {};
    float Pp[16];
    #pragma unroll
    for (int s = 0; s < 16; ++s) Pp[s] = 1.f;

    for (int t = 0; t < CLEN; ++t) {
        const int m = mbase + t;
        const float dtv = dt[(size_t)m * D_INNER + d];
        const float u   = x_act[(size_t)m * D_INNER + d];
        const float du  = dtv * u;
        float Bv[16];
        #pragma unroll
        for (int q = 0; q < 4; ++q) {
            float4 v = *reinterpret_cast<const float4*>(&Bsh[t][q * 4]);
            Bv[q*4+0] = v.x; Bv[q*4+1] = v.y; Bv[q*4+2] = v.z; Bv[q*4+3] = v.w;
        }
        #pragma unroll
        for (int s = 0; s < 16; ++s) {
            const float dA = __expf(dtv * A[s]);
            Pp[s] *= dA;
            h[s] = fmaf(dA, h[s], du * Bv[s]);
        }
    }
    const size_t base = ((size_t)(b * NCHUNK + c) * 16) * D_INNER + d;
    #pragma unroll
    for (int s = 0; s < 16; ++s) {
        P[base + (size_t)s * D_INNER] = Pp[s];
        F[base + (size_t)s * D_INNER] = h[s];
    }
}

// Batch-load all chunk summaries to registers, serial combine, store back.
__launch_bounds__(256, 2)
__global__ void scan_combine(const float* __restrict__ P, float* F) {
    const int idx = blockIdx.x * 256 + threadIdx.x;    // over B*16*D_INNER
    const int d  = idx % D_INNER;
    const int bs = idx / D_INNER;
    const int b  = bs >> 4, s = bs & 15;
    const size_t base0 = ((size_t)b * NCHUNK * 16 + s) * D_INNER + d;
    const size_t cstep = (size_t)16 * D_INNER;

    float Pv[NCHUNK], Fv[NCHUNK];
    #pragma unroll
    for (int c = 0; c < NCHUNK; ++c) {
        Pv[c] = P[base0 + c * cstep];
        Fv[c] = F[base0 + c * cstep];
    }
    float G = 0.f;
    #pragma unroll
    for (int c = 0; c < NCHUNK; ++c) {
        const float f = Fv[c];
        Fv[c] = G;                       // initial state for chunk c
        G = fmaf(Pv[c], G, f);
    }
    #pragma unroll
    for (int c = 0; c < NCHUNK; ++c)
        F[base0 + c * cstep] = Fv[c];
}

// BF16OUT=1: emit yf as bf16 (hi,lo) for the MFMA out_proj (no z/y alias).
// BF16OUT=0: fp32 yf (fallback; zp aliases yf -> z preloaded per half).
template<int BF16OUT>
__launch_bounds__(256)
__global__ void scan_part2(const float* __restrict__ dt,
                           const float* __restrict__ x_act,
                           const float* __restrict__ dbc,
                           const float* __restrict__ A_log,
                           const float* __restrict__ Dp,
                           const float* __restrict__ Ginit,
                           const float* zp, int zld,
                           float* yf, u16* yh, u16* yl) {
    __shared__ float BCs[CLEN][32];   // [t][0:16]=B, [16:32]=C ; 4 KB
    const int tid = threadIdx.x;
    const int d = blockIdx.x * 256 + tid;
    const int c = blockIdx.y;
    const int b = blockIdx.z;
    const int mbase = b * SEQ + c * CLEN;

    {   // stage B+C: CLEN*32 = 1024 floats, one float4 per thread
        const int t0 = tid >> 3;            // 0..31
        const int j  = (tid & 7) * 4;       // 0..28
        float4 v = *reinterpret_cast<const float4*>(
            &dbc[(size_t)(mbase + t0) * 96 + DT_RANK + j]);
        *reinterpret_cast<float4*>(&BCs[t0][j]) = v;
    }
    float A[16];
    #pragma unroll
    for (int q = 0; q < 4; ++q) {
        float4 v = *reinterpret_cast<const float4*>(&A_log[d * 16 + q * 4]);
        A[q*4+0] = -__expf(v.x); A[q*4+1] = -__expf(v.y);
        A[q*4+2] = -__expf(v.z); A[q*4+3] = -__expf(v.w);
    }
    float h[16];
    const size_t gbase = ((size_t)(b * NCHUNK + c) * 16) * D_INNER + d;
    #pragma unroll
    for (int s = 0; s < 16; ++s) h[s] = Ginit[gbase + (size_t)s * D_INNER];
    const float Dv = Dp[d];
    __syncthreads();

    for (int half = 0; half < 2; ++half) {
        const int tb = half * (CLEN / 2);
        float zreg[CLEN / 2];
        #pragma unroll
        for (int t = 0; t < CLEN / 2; ++t)
            zreg[t] = zp[(size_t)(mbase + tb + t) * zld + d];

        for (int t = 0; t < CLEN / 2; ++t) {
            const int m = mbase + tb + t;
            const float dtv = dt[(size_t)m * D_INNER + d];
            const float u   = x_act[(size_t)m * D_INNER + d];
            const float du  = dtv * u;
            float Bv[16], Cv[16];
            #pragma unroll
            for (int q = 0; q < 4; ++q) {
                float4 vb = *reinterpret_cast<const float4*>(&BCs[tb + t][q * 4]);
                float4 vc = *reinterpret_cast<const float4*>(&BCs[tb + t][16 + q * 4]);
                Bv[q*4+0] = vb.x; Bv[q*4+1] = vb.y; Bv[q*4+2] = vb.z; Bv[q*4+3] = vb.w;
                Cv[q*4+0] = vc.x; Cv[q*4+1] = vc.y; Cv[q*4+2] = vc.z; Cv[q*4+3] = vc.w;
            }
            float y0 = 0.f, y1 = 0.f;
            #pragma unroll
            for (int s = 0; s < 16; s += 2) {
                const float dA0 = __expf(dtv * A[s]);
                const float dA1 = __expf(dtv * A[s + 1]);
                h[s]     = fmaf(dA0, h[s],     du * Bv[s]);
                h[s + 1] = fmaf(dA1, h[s + 1], du * Bv[s + 1]);
                y0 = fmaf(h[s],     Cv[s],     y0);
                y1 = fmaf(h[s + 1], Cv[s + 1], y1);
            }
            float y = y0 + y1;
            y = fmaf(u, Dv, y);
            const float zv = zreg[t];
            const float g  = zv / (1.f + __expf(-zv));
            const float val = y * g;
            if (BF16OUT) {
                const u16 hh = rne_bf16(val);
                yh[(size_t)m * D_INNER + d] = hh;
                yl[(size_t)m * D_INNER + d] =
                    rne_bf16(val - __uint_as_float((unsigned int)hh << 16));
            } else {
                yf[(size_t)m * D_INNER + d] = val;
            }
        }
    }
}

// ===========================================================================
extern "C" void kernel_launch(void* const* d_in, const int* in_sizes, int n_in,
                              void* d_out, int out_size, void* d_ws, size_t ws_size,
                              hipStream_t stream) {
    const float* x      = (const float*)d_in[0];
    const float* W_in   = (const float*)d_in[1];
    const float* conv_w = (const float*)d_in[2];
    const float* conv_b = (const float*)d_in[3];
    const float* W_x    = (const float*)d_in[4];
    const float* W_dt   = (const float*)d_in[5];
    const float* b_dt   = (const float*)d_in[6];
    const float* A_log  = (const float*)d_in[7];
    const float* Dp     = (const float*)d_in[8];
    const float* W_out  = (const float*)d_in[9];
    float* out = (float*)d_out;

    const size_t M1 = 1024u * 1024u;
    // floats: xz 8M | x_act 4M | dbc .1875M | dt 4M
    // shorts: xhi 2M | xlo 2M | winh 4M | wouth 2M | yh 4M | yl 4M
    // P (2M floats) aliases xhi+xlo; F (2M floats) aliases winh (dead after
    // in_proj). dbc split-K partials alias yh/yl (dead until scan_part2).
    const size_t fXZ = 8 * M1, fXACT = 4 * M1, fDBC = (size_t)BT * 96,
                 fDT = 4 * M1;
    const size_t need = (fXZ + fXACT + fDBC + fDT) * 4 + 18 * M1 * 2;

    if (ws_size >= need) {
        float* ws    = (float*)d_ws;
        float* xz    = ws;
        float* x_act = xz    + fXZ;
        float* dbc   = x_act + fXACT;
        float* dtbuf = dbc   + fDBC;
        u16* xhi   = (u16*)(dtbuf + fDT);
        u16* xlo   = xhi   + 2 * M1;
        u16* winh  = xlo   + 2 * M1;
        u16* wouth = winh  + 4 * M1;
        u16* yh    = wouth + 2 * M1;   // 4M shorts
        u16* yl    = yh    + 4 * M1;   // 4M shorts
        float* Pbuf = (float*)xhi;     // 2M floats (xhi+xlo region)
        float* Fbuf = (float*)winh;    // 2M floats (winh region)
        float* dbc_part = (float*)yh;  // 12.6 MB < 16 MB

        // 1) convert: x -> hi/lo, W_in -> hi, W_out -> hi
        prep_kernel<<<dim3((8 * M1) / 2048), 256, 0, stream>>>(
            x, W_in, W_out, xhi, xlo, winh, wouth);

        // 2) in_proj: xz[2048][4096] = x @ W_in^T
        gemm_mfma2<128, 256, 64, 128><<<dim3(4096 / 256, BT / 128), 256, 0, stream>>>(
            xhi, xlo, D_MODEL, winh, D_MODEL, xz, 4096, D_MODEL);

        // 3) conv + SiLU (x_in = xz[:, :2048])
        conv_silu_kernel<<<dim3((BT * D_INNER) / 256), 256, 0, stream>>>(
            xz, 4096, conv_w, conv_b, x_act);

        // 4) dbc = x_act @ W_x^T (fp32 split-K)
        gemm_nt_splitk<64,32,16,4,4><<<dim3(96 / 32, BT / 64, KSPLIT), 128, 0, stream>>>(
            x_act, D_INNER, W_x, D_INNER, dbc_part, 96, D_INNER / KSPLIT);
        reduce_splitk<<<dim3((BT * 96 + 255) / 256), 256, 0, stream>>>(
            dbc_part, dbc, BT * 96);

        // 5) dt = softplus(dbc[:, :64] @ W_dt^T + b_dt) (fp32)
        gemm_nt<64,64,16,4,4,1><<<dim3(D_INNER / 64, BT / 64), 256, 0, stream>>>(
            dbc, 96, W_dt, DT_RANK, dtbuf, D_INNER, DT_RANK, b_dt);

        // 6) chunked scan + skip + gate; emit yf as bf16 hi/lo
        scan_part1<<<dim3(D_INNER / 256, NCHUNK, BATCH), 256, 0, stream>>>(
            dtbuf, x_act, dbc, A_log, Pbuf, Fbuf);
        scan_combine<<<dim3((BATCH * 16 * D_INNER) / 256), 256, 0, stream>>>(
            Pbuf, Fbuf);
        scan_part2<1><<<dim3(D_INNER / 256, NCHUNK, BATCH), 256, 0, stream>>>(
            dtbuf, x_act, dbc, A_log, Dp, Fbuf, xz + D_INNER, 4096,
            nullptr, yh, yl);

        // 7) out_proj: out = yf @ W_out^T
        gemm_mfma2<64, 128, 32, 64><<<dim3(D_MODEL / 128, BT / 64), 256, 0, stream>>>(
            yh, yl, D_INNER, wouth, D_INNER, out, D_MODEL, D_INNER);
    } else {
        // ------------------- fallback: all-fp32 path -----------------------
        float* ws    = (float*)d_ws;
        float* x_in  = ws;
        float* z     = x_in  + (size_t)BT * D_INNER;
        float* x_act = z     + (size_t)BT * D_INNER;
        float* dbc   = x_act + (size_t)BT * D_INNER;
        float* Pbuf  = dbc   + (size_t)BT * 96;
        float* Fbuf  = Pbuf  + (size_t)BATCH * NCHUNK * 16 * D_INNER;
        float* dtbuf = x_in;
        float* yf    = z;

        gemm_nt<64,64,16,4,4,0><<<dim3(D_INNER/64, BT/64), 256, 0, stream>>>(
            x, D_MODEL, W_in, D_MODEL, x_in, D_INNER, D_MODEL, nullptr);
        gemm_nt<64,64,16,4,4,0><<<dim3(D_INNER/64, BT/64), 256, 0, stream>>>(
            x, D_MODEL, W_in + (size_t)D_INNER * D_MODEL, D_MODEL, z, D_INNER, D_MODEL, nullptr);
        conv_silu_kernel<<<dim3((BT * D_INNER) / 256), 256, 0, stream>>>(
            x_in, D_INNER, conv_w, conv_b, x_act);
        gemm_nt<64,32,16,4,4,0><<<dim3(96/32, BT/64), 128, 0, stream>>>(
            x_act, D_INNER, W_x, D_INNER, dbc, 96, D_INNER, nullptr);
        gemm_nt<64,64,16,4,4,1><<<dim3(D_INNER/64, BT/64), 256, 0, stream>>>(
            dbc, 96, W_dt, DT_RANK, dtbuf, D_INNER, DT_RANK, b_dt);
        scan_part1<<<dim3(D_INNER/256, NCHUNK, BATCH), 256, 0, stream>>>(
            dtbuf, x_act, dbc, A_log, Pbuf, Fbuf);
        scan_combine<<<dim3((BATCH * 16 * D_INNER) / 256), 256, 0, stream>>>(
            Pbuf, Fbuf);
        scan_part2<0><<<dim3(D_INNER/256, NCHUNK, BATCH), 256, 0, stream>>>(
            dtbuf, x_act, dbc, A_log, Dp, Fbuf, z, D_INNER, yf, nullptr, nullptr);
        gemm_nt<64,64,16,4,4,0><<<dim3(D_MODEL/64, BT/64), 256, 0, stream>>>(
            yf, D_INNER, W_out, D_INNER, out, D_MODEL, D_INNER, nullptr);
    }
}

// Round 9
// 216.099 us; speedup vs baseline: 1.5475x; 1.0215x over previous
//
#include <hip/hip_runtime.h>
#include <math.h>

#define D_MODEL 1024
#define D_STATE 16
#define D_CONV  4
#define DT_RANK 64
#define D_INNER 2048
#define BATCH   2
#define SEQ     1024
#define BT      (BATCH*SEQ)   // 2048 rows
#define NCHUNK  32
#define CLEN    (SEQ/NCHUNK)  // 32
#define KSPLIT  16            // split-K factor for dbc GEMM

typedef int   v4i __attribute__((ext_vector_type(4)));
typedef float v4f __attribute__((ext_vector_type(4)));
typedef short s8v __attribute__((ext_vector_type(8)));
typedef unsigned short u16;

// ===========================================================================
// fp32 GEMM (dt projection + fallback path)
// ===========================================================================
template<int BM, int BN, int BK, int TM, int TN, int EPI>
__launch_bounds__(256)
__global__ void gemm_nt(const float* __restrict__ A, int lda,
                        const float* __restrict__ B, int ldb,
                        float* __restrict__ C, int ldc,
                        int K, const float* __restrict__ bias) {
    constexpr int BX = BN / TN;
    constexpr int BY = BM / TM;
    constexpr int THREADS = BX * BY;

    __shared__ float As[BK][BM + 1];
    __shared__ float Bs[BK][BN + 1];

    const int tid = threadIdx.x;
    const int tx  = tid % BX;
    const int ty  = tid / BX;
    const int m0  = blockIdx.y * BM;
    const int n0  = blockIdx.x * BN;

    float acc[TM][TN] = {};

    for (int k0 = 0; k0 < K; k0 += BK) {
        #pragma unroll
        for (int l = 0; l < (BM * BK) / (THREADS * 4); ++l) {
            int idx = (tid + l * THREADS) * 4;
            int row = idx / BK, col = idx % BK;
            const float4 v = *reinterpret_cast<const float4*>(
                &A[(size_t)(m0 + row) * lda + k0 + col]);
            As[col + 0][row] = v.x; As[col + 1][row] = v.y;
            As[col + 2][row] = v.z; As[col + 3][row] = v.w;
        }
        #pragma unroll
        for (int l = 0; l < (BN * BK) / (THREADS * 4); ++l) {
            int idx = (tid + l * THREADS) * 4;
            int row = idx / BK, col = idx % BK;
            const float4 v = *reinterpret_cast<const float4*>(
                &B[(size_t)(n0 + row) * ldb + k0 + col]);
            Bs[col + 0][row] = v.x; Bs[col + 1][row] = v.y;
            Bs[col + 2][row] = v.z; Bs[col + 3][row] = v.w;
        }
        __syncthreads();

        #pragma unroll
        for (int kk = 0; kk < BK; ++kk) {
            float a[TM], b[TN];
            #pragma unroll
            for (int i = 0; i < TM; ++i) a[i] = As[kk][ty * TM + i];
            #pragma unroll
            for (int j = 0; j < TN; ++j) b[j] = Bs[kk][tx * TN + j];
            #pragma unroll
            for (int i = 0; i < TM; ++i)
                #pragma unroll
                for (int j = 0; j < TN; ++j)
                    acc[i][j] = fmaf(a[i], b[j], acc[i][j]);
        }
        __syncthreads();
    }

    #pragma unroll
    for (int i = 0; i < TM; ++i) {
        float* outp = &C[(size_t)(m0 + ty * TM + i) * ldc + n0 + tx * TN];
        float vals[4];
        #pragma unroll
        for (int j = 0; j < TN; ++j) {
            float val = acc[i][j];
            if (EPI == 1) {
                val += bias[n0 + tx * TN + j];
                val = (val > 20.f) ? val : log1pf(expf(val));
            }
            vals[j] = val;
        }
        float4 v;
        v.x = vals[0]; v.y = vals[1]; v.z = vals[2]; v.w = vals[3];
        *reinterpret_cast<float4*>(outp) = v;
    }
}

// ===========================================================================
// Split-K fp32 GEMM for the skinny dbc projection (N=96, K=2048).
// ===========================================================================
template<int BM, int BN, int BK, int TM, int TN>
__launch_bounds__(128)
__global__ void gemm_nt_splitk(const float* __restrict__ A, int lda,
                               const float* __restrict__ B, int ldb,
                               float* __restrict__ part, int N, int kchunk) {
    constexpr int BX = BN / TN;
    constexpr int BY = BM / TM;
    constexpr int THREADS = BX * BY;

    __shared__ float As[BK][BM + 1];
    __shared__ float Bs[BK][BN + 1];

    const int tid = threadIdx.x;
    const int tx  = tid % BX;
    const int ty  = tid / BX;
    const int m0  = blockIdx.y * BM;
    const int n0  = blockIdx.x * BN;
    const int kb  = blockIdx.z * kchunk;

    float acc[TM][TN] = {};

    for (int k0 = kb; k0 < kb + kchunk; k0 += BK) {
        #pragma unroll
        for (int l = 0; l < (BM * BK) / (THREADS * 4); ++l) {
            int idx = (tid + l * THREADS) * 4;
            int row = idx / BK, col = idx % BK;
            const float4 v = *reinterpret_cast<const float4*>(
                &A[(size_t)(m0 + row) * lda + k0 + col]);
            As[col + 0][row] = v.x; As[col + 1][row] = v.y;
            As[col + 2][row] = v.z; As[col + 3][row] = v.w;
        }
        #pragma unroll
        for (int l = 0; l < (BN * BK) / (THREADS * 4); ++l) {
            int idx = (tid + l * THREADS) * 4;
            int row = idx / BK, col = idx % BK;
            const float4 v = *reinterpret_cast<const float4*>(
                &B[(size_t)(n0 + row) * ldb + k0 + col]);
            Bs[col + 0][row] = v.x; Bs[col + 1][row] = v.y;
            Bs[col + 2][row] = v.z; Bs[col + 3][row] = v.w;
        }
        __syncthreads();

        #pragma unroll
        for (int kk = 0; kk < BK; ++kk) {
            float a[TM], b[TN];
            #pragma unroll
            for (int i = 0; i < TM; ++i) a[i] = As[kk][ty * TM + i];
            #pragma unroll
            for (int j = 0; j < TN; ++j) b[j] = Bs[kk][tx * TN + j];
            #pragma unroll
            for (int i = 0; i < TM; ++i)
                #pragma unroll
                for (int j = 0; j < TN; ++j)
                    acc[i][j] = fmaf(a[i], b[j], acc[i][j]);
        }
        __syncthreads();
    }

    float* base = part + (size_t)blockIdx.z * BT * N;
    #pragma unroll
    for (int i = 0; i < TM; ++i) {
        float* outp = &base[(size_t)(m0 + ty * TM + i) * N + n0 + tx * TN];
        float4 v;
        v.x = acc[i][0]; v.y = acc[i][1]; v.z = acc[i][2]; v.w = acc[i][3];
        *reinterpret_cast<float4*>(outp) = v;
    }
}

__global__ void reduce_splitk(const float* __restrict__ part,
                              float* __restrict__ outp, int n) {
    const int idx = blockIdx.x * 256 + threadIdx.x;
    if (idx >= n) return;
    float s = 0.f;
    #pragma unroll
    for (int kc = 0; kc < KSPLIT; ++kc)
        s += part[(size_t)kc * n + idx];
    outp[idx] = s;
}

// ===========================================================================
// bf16 helpers
// ===========================================================================
__device__ __forceinline__ u16 rne_bf16(float x) {
    unsigned int u = __float_as_uint(x);
    unsigned int r = u + 0x7FFFu + ((u >> 16) & 1u);
    return (u16)(r >> 16);
}

// One pass converting: x -> (hi,lo); W_in -> hi; W_out -> hi.
__global__ void prep_kernel(const float* __restrict__ x,
                            const float* __restrict__ Win,
                            const float* __restrict__ Wout,
                            u16* __restrict__ xhi, u16* __restrict__ xlo,
                            u16* __restrict__ winh, u16* __restrict__ wouth) {
    const size_t M2 = 2u * 1024u * 1024u;
    size_t i = ((size_t)blockIdx.x * 256 + threadIdx.x) * 8;
    if (i < M2) {
        float4 a = *reinterpret_cast<const float4*>(&x[i]);
        float4 b = *reinterpret_cast<const float4*>(&x[i + 4]);
        float xs[8] = {a.x, a.y, a.z, a.w, b.x, b.y, b.z, b.w};
        unsigned int hw[4], lw[4];
        #pragma unroll
        for (int q = 0; q < 4; ++q) {
            u16 h0 = rne_bf16(xs[2*q]);
            u16 h1 = rne_bf16(xs[2*q+1]);
            float d0 = xs[2*q]   - __uint_as_float((unsigned int)h0 << 16);
            float d1 = xs[2*q+1] - __uint_as_float((unsigned int)h1 << 16);
            hw[q] = (unsigned int)h0 | ((unsigned int)h1 << 16);
            lw[q] = (unsigned int)rne_bf16(d0) | ((unsigned int)rne_bf16(d1) << 16);
        }
        *reinterpret_cast<v4i*>(&xhi[i]) = *reinterpret_cast<v4i*>(hw);
        *reinterpret_cast<v4i*>(&xlo[i]) = *reinterpret_cast<v4i*>(lw);
    } else if (i < 3 * M2) {
        size_t j = i - M2;
        float4 a = *reinterpret_cast<const float4*>(&Win[j]);
        float4 b = *reinterpret_cast<const float4*>(&Win[j + 4]);
        float xs[8] = {a.x, a.y, a.z, a.w, b.x, b.y, b.z, b.w};
        unsigned int hw[4];
        #pragma unroll
        for (int q = 0; q < 4; ++q)
            hw[q] = (unsigned int)rne_bf16(xs[2*q]) | ((unsigned int)rne_bf16(xs[2*q+1]) << 16);
        *reinterpret_cast<v4i*>(&winh[j]) = *reinterpret_cast<v4i*>(hw);
    } else {
        size_t j = i - 3 * M2;
        float4 a = *reinterpret_cast<const float4*>(&Wout[j]);
        float4 b = *reinterpret_cast<const float4*>(&Wout[j + 4]);
        float xs[8] = {a.x, a.y, a.z, a.w, b.x, b.y, b.z, b.w};
        unsigned int hw[4];
        #pragma unroll
        for (int q = 0; q < 4; ++q)
            hw[q] = (unsigned int)rne_bf16(xs[2*q]) | ((unsigned int)rne_bf16(xs[2*q+1]) << 16);
        *reinterpret_cast<v4i*>(&wouth[j]) = *reinterpret_cast<v4i*>(hw);
    }
}

// ===========================================================================
// 2-term split-bf16 MFMA GEMM: C = (Ahi+Alo) @ Bhi^T, fp32 accumulate.
// v3: builtin MFMA (compiler-schedulable), ONE barrier per k-iter:
//   iter k = { write tile k+1 -> other buf | issue global k+2 |
//              read frags k + MFMA k | barrier }
// LDS writes of buf^1 overlap reads of buf^0 between barriers.
// Pitch 40 shorts (80B): uniform bank coverage for b128 ops.
// ===========================================================================
template<int BM, int BN, int WM, int WN>
__launch_bounds__(256)
__global__ void gemm_mfma2(const u16* __restrict__ Ahi, const u16* __restrict__ Alo, int lda,
                           const u16* __restrict__ Bhi, int ldb,
                           float* __restrict__ C, int ldc, int K) {
    constexpr int ACH = BM / 64;          // 16B chunks per thread per A comp
    constexpr int BCH = BN / 64;
    constexpr int WMF = WM / 16;
    constexpr int WNF = WN / 16;
    constexpr int SA  = BM * 40;          // shorts per A component
    constexpr int SB  = BN * 40;
    constexpr int BUFSZ = 2 * SA + SB;
    constexpr int WCOLS = BN / WN;

    __shared__ u16 smem[2 * BUFSZ];

    const int tid  = threadIdx.x;
    const int lane = tid & 63;
    const int wave = tid >> 6;
    const int wr   = wave / WCOLS, wc = wave % WCOLS;
    const int m0   = blockIdx.y * BM, n0 = blockIdx.x * BN;

    size_t aBase[ACH]; int aW[ACH];
    #pragma unroll
    for (int q = 0; q < ACH; ++q) {
        int c = tid + q * 256, row = c >> 2, slot = c & 3;
        aBase[q] = (size_t)(m0 + row) * lda + slot * 8;
        aW[q] = row * 40 + slot * 8;
    }
    size_t bBase[BCH]; int bW[BCH];
    #pragma unroll
    for (int q = 0; q < BCH; ++q) {
        int c = tid + q * 256, row = c >> 2, slot = c & 3;
        bBase[q] = (size_t)(n0 + row) * ldb + slot * 8;
        bW[q] = row * 40 + slot * 8;
    }

    const int fr = lane & 15;
    const int fk = (lane >> 4) * 8;
    const int fq = lane >> 4;
    int aOff[WMF], bOff[WNF];
    #pragma unroll
    for (int i = 0; i < WMF; ++i) aOff[i] = (wr * WM + i * 16 + fr) * 40 + fk;
    #pragma unroll
    for (int j = 0; j < WNF; ++j) bOff[j] = (wc * WN + j * 16 + fr) * 40 + fk;

    v4f acc[WMF][WNF];
    #pragma unroll
    for (int i = 0; i < WMF; ++i)
        #pragma unroll
        for (int j = 0; j < WNF; ++j)
            acc[i][j] = (v4f)0.f;

    v4i rAh[ACH], rAl[ACH], rBh[BCH];

    auto loadg = [&](int k0) {
        #pragma unroll
        for (int q = 0; q < ACH; ++q) {
            rAh[q] = *reinterpret_cast<const v4i*>(Ahi + aBase[q] + k0);
            rAl[q] = *reinterpret_cast<const v4i*>(Alo + aBase[q] + k0);
        }
        #pragma unroll
        for (int q = 0; q < BCH; ++q)
            rBh[q] = *reinterpret_cast<const v4i*>(Bhi + bBase[q] + k0);
    };
    auto writelds = [&](u16* buf) {
        #pragma unroll
        for (int q = 0; q < ACH; ++q) {
            *reinterpret_cast<v4i*>(&buf[aW[q]]) = rAh[q];
            *reinterpret_cast<v4i*>(&buf[SA + aW[q]]) = rAl[q];
        }
        #pragma unroll
        for (int q = 0; q < BCH; ++q)
            *reinterpret_cast<v4i*>(&buf[2 * SA + bW[q]]) = rBh[q];
    };

    const int NK = K / 32;
    // prolog: tile 0 -> buf0; tile 1 in flight
    loadg(0);
    writelds(smem);
    if (NK > 1) loadg(32);
    __syncthreads();

    for (int k = 0; k < NK; ++k) {
        u16* cur = smem + (k & 1) * BUFSZ;
        if (k + 1 < NK) {
            writelds(smem + ((k + 1) & 1) * BUFSZ);   // tile k+1 (regs)
            if (k + 2 < NK) loadg((k + 2) * 32);      // tile k+2 in flight
        }

        s8v ah[WMF], al[WMF];
        #pragma unroll
        for (int i = 0; i < WMF; ++i) {
            ah[i] = *reinterpret_cast<const s8v*>(&cur[aOff[i]]);
            al[i] = *reinterpret_cast<const s8v*>(&cur[SA + aOff[i]]);
        }
        #pragma unroll
        for (int j = 0; j < WNF; ++j) {
            const s8v bh = *reinterpret_cast<const s8v*>(&cur[2 * SA + bOff[j]]);
            #pragma unroll
            for (int i = 0; i < WMF; ++i)
                acc[i][j] = __builtin_amdgcn_mfma_f32_16x16x32_bf16(ah[i], bh, acc[i][j], 0, 0, 0);
            #pragma unroll
            for (int i = 0; i < WMF; ++i)
                acc[i][j] = __builtin_amdgcn_mfma_f32_16x16x32_bf16(al[i], bh, acc[i][j], 0, 0, 0);
        }
        __syncthreads();
    }

    #pragma unroll
    for (int i = 0; i < WMF; ++i) {
        const int row = m0 + wr * WM + i * 16 + fq * 4;
        #pragma unroll
        for (int j = 0; j < WNF; ++j) {
            const int col = n0 + wc * WN + j * 16 + fr;
            #pragma unroll
            for (int r = 0; r < 4; ++r)
                C[(size_t)(row + r) * ldc + col] = acc[i][j][r];
        }
    }
}

// ===========================================================================
// Depthwise causal conv (width 4) + bias + SiLU.
// ===========================================================================
__global__ void conv_silu_kernel(const float* __restrict__ x_in, int xld,
                                 const float* __restrict__ w,
                                 const float* __restrict__ b,
                                 float* __restrict__ x_act) {
    const int idx = blockIdx.x * blockDim.x + threadIdx.x;
    const int ch = idx % D_INNER;
    const int m  = idx / D_INNER;
    const int t  = m % SEQ;

    float acc = b[ch];
    #pragma unroll
    for (int j = 0; j < D_CONV; ++j) {
        int tt = t - (D_CONV - 1) + j;
        if (tt >= 0)
            acc = fmaf(w[ch * D_CONV + j], x_in[(size_t)(m - (D_CONV - 1) + j) * xld + ch], acc);
    }
    x_act[idx] = acc / (1.f + __expf(-acc));
}

// ===========================================================================
// Chunked selective scan. NCHUNK=32 (512 blocks, 8 waves/CU), simple
// per-step bodies (VGPR ~56, no spill; manual ILP batching spills — r6/7).
// ===========================================================================
__launch_bounds__(256)
__global__ void scan_part1(const float* __restrict__ dt,
                           const float* __restrict__ x_act,
                           const float* __restrict__ dbc,
                           const float* __restrict__ A_log,
                           float* __restrict__ P, float* __restrict__ F) {
    __shared__ float Bsh[CLEN][D_STATE];   // 2 KB
    const int tid = threadIdx.x;
    const int d = blockIdx.x * 256 + tid;
    const int c = blockIdx.y;
    const int b = blockIdx.z;
    const int mbase = b * SEQ + c * CLEN;

    {   // stage B rows: CLEN*16 = 512 floats, 2 per thread
        const int s = tid & 15, t0 = tid >> 4;
        #pragma unroll
        for (int q = 0; q < 2; ++q)
            Bsh[t0 + 16 * q][s] = dbc[(size_t)(mbase + t0 + 16 * q) * 96 + DT_RANK + s];
    }
    float A[16];
    #pragma unroll
    for (int q = 0; q < 4; ++q) {
        float4 v = *reinterpret_cast<const float4*>(&A_log[d * 16 + q * 4]);
        A[q*4+0] = -__expf(v.x); A[q*4+1] = -__expf(v.y);
        A[q*4+2] = -__expf(v.z); A[q*4+3] = -__expf(v.w);
    }
    __syncthreads();

    float h[16] = {};
    float Pp[16];
    #pragma unroll
    for (int s = 0; s < 16; ++s) Pp[s] = 1.f;

    for (int t = 0; t < CLEN; ++t) {
        const int m = mbase + t;
        const float dtv = dt[(size_t)m * D_INNER + d];
        const float u   = x_act[(size_t)m * D_INNER + d];
        const float du  = dtv * u;
        float Bv[16];
        #pragma unroll
        for (int q = 0; q < 4; ++q) {
            float4 v = *reinterpret_cast<const float4*>(&Bsh[t][q * 4]);
            Bv[q*4+0] = v.x; Bv[q*4+1] = v.y; Bv[q*4+2] = v.z; Bv[q*4+3] = v.w;
        }
        #pragma unroll
        for (int s = 0; s < 16; ++s) {
            const float dA = __expf(dtv * A[s]);
            Pp[s] *= dA;
            h[s] = fmaf(dA, h[s], du * Bv[s]);
        }
    }
    const size_t base = ((size_t)(b * NCHUNK + c) * 16) * D_INNER + d;
    #pragma unroll
    for (int s = 0; s < 16; ++s) {
        P[base + (size_t)s * D_INNER] = Pp[s];
        F[base + (size_t)s * D_INNER] = h[s];
    }
}

// Batch-load all chunk summaries to registers, serial combine, store back.
__launch_bounds__(256, 2)
__global__ void scan_combine(const float* __restrict__ P, float* F) {
    const int idx = blockIdx.x * 256 + threadIdx.x;    // over B*16*D_INNER
    const int d  = idx % D_INNER;
    const int bs = idx / D_INNER;
    const int b  = bs >> 4, s = bs & 15;
    const size_t base0 = ((size_t)b * NCHUNK * 16 + s) * D_INNER + d;
    const size_t cstep = (size_t)16 * D_INNER;

    float Pv[NCHUNK], Fv[NCHUNK];
    #pragma unroll
    for (int c = 0; c < NCHUNK; ++c) {
        Pv[c] = P[base0 + c * cstep];
        Fv[c] = F[base0 + c * cstep];
    }
    float G = 0.f;
    #pragma unroll
    for (int c = 0; c < NCHUNK; ++c) {
        const float f = Fv[c];
        Fv[c] = G;                       // initial state for chunk c
        G = fmaf(Pv[c], G, f);
    }
    #pragma unroll
    for (int c = 0; c < NCHUNK; ++c)
        F[base0 + c * cstep] = Fv[c];
}

// BF16OUT=1: emit yf as bf16 (hi,lo) for the MFMA out_proj (no z/y alias).
// BF16OUT=0: fp32 yf (fallback; zp aliases yf -> z preloaded per half).
template<int BF16OUT>
__launch_bounds__(256)
__global__ void scan_part2(const float* __restrict__ dt,
                           const float* __restrict__ x_act,
                           const float* __restrict__ dbc,
                           const float* __restrict__ A_log,
                           const float* __restrict__ Dp,
                           const float* __restrict__ Ginit,
                           const float* zp, int zld,
                           float* yf, u16* yh, u16* yl) {
    __shared__ float BCs[CLEN][32];   // [t][0:16]=B, [16:32]=C ; 4 KB
    const int tid = threadIdx.x;
    const int d = blockIdx.x * 256 + tid;
    const int c = blockIdx.y;
    const int b = blockIdx.z;
    const int mbase = b * SEQ + c * CLEN;

    {   // stage B+C: CLEN*32 = 1024 floats, one float4 per thread
        const int t0 = tid >> 3;            // 0..31
        const int j  = (tid & 7) * 4;       // 0..28
        float4 v = *reinterpret_cast<const float4*>(
            &dbc[(size_t)(mbase + t0) * 96 + DT_RANK + j]);
        *reinterpret_cast<float4*>(&BCs[t0][j]) = v;
    }
    float A[16];
    #pragma unroll
    for (int q = 0; q < 4; ++q) {
        float4 v = *reinterpret_cast<const float4*>(&A_log[d * 16 + q * 4]);
        A[q*4+0] = -__expf(v.x); A[q*4+1] = -__expf(v.y);
        A[q*4+2] = -__expf(v.z); A[q*4+3] = -__expf(v.w);
    }
    float h[16];
    const size_t gbase = ((size_t)(b * NCHUNK + c) * 16) * D_INNER + d;
    #pragma unroll
    for (int s = 0; s < 16; ++s) h[s] = Ginit[gbase + (size_t)s * D_INNER];
    const float Dv = Dp[d];
    __syncthreads();

    for (int half = 0; half < 2; ++half) {
        const int tb = half * (CLEN / 2);
        float zreg[CLEN / 2];
        #pragma unroll
        for (int t = 0; t < CLEN / 2; ++t)
            zreg[t] = zp[(size_t)(mbase + tb + t) * zld + d];

        for (int t = 0; t < CLEN / 2; ++t) {
            const int m = mbase + tb + t;
            const float dtv = dt[(size_t)m * D_INNER + d];
            const float u   = x_act[(size_t)m * D_INNER + d];
            const float du  = dtv * u;
            float Bv[16], Cv[16];
            #pragma unroll
            for (int q = 0; q < 4; ++q) {
                float4 vb = *reinterpret_cast<const float4*>(&BCs[tb + t][q * 4]);
                float4 vc = *reinterpret_cast<const float4*>(&BCs[tb + t][16 + q * 4]);
                Bv[q*4+0] = vb.x; Bv[q*4+1] = vb.y; Bv[q*4+2] = vb.z; Bv[q*4+3] = vb.w;
                Cv[q*4+0] = vc.x; Cv[q*4+1] = vc.y; Cv[q*4+2] = vc.z; Cv[q*4+3] = vc.w;
            }
            float y0 = 0.f, y1 = 0.f;
            #pragma unroll
            for (int s = 0; s < 16; s += 2) {
                const float dA0 = __expf(dtv * A[s]);
                const float dA1 = __expf(dtv * A[s + 1]);
                h[s]     = fmaf(dA0, h[s],     du * Bv[s]);
                h[s + 1] = fmaf(dA1, h[s + 1], du * Bv[s + 1]);
                y0 = fmaf(h[s],     Cv[s],     y0);
                y1 = fmaf(h[s + 1], Cv[s + 1], y1);
            }
            float y = y0 + y1;
            y = fmaf(u, Dv, y);
            const float zv = zreg[t];
            const float g  = zv / (1.f + __expf(-zv));
            const float val = y * g;
            if (BF16OUT) {
                const u16 hh = rne_bf16(val);
                yh[(size_t)m * D_INNER + d] = hh;
                yl[(size_t)m * D_INNER + d] =
                    rne_bf16(val - __uint_as_float((unsigned int)hh << 16));
            } else {
                yf[(size_t)m * D_INNER + d] = val;
            }
        }
    }
}

// ===========================================================================
extern "C" void kernel_launch(void* const* d_in, const int* in_sizes, int n_in,
                              void* d_out, int out_size, void* d_ws, size_t ws_size,
                              hipStream_t stream) {
    const float* x      = (const float*)d_in[0];
    const float* W_in   = (const float*)d_in[1];
    const float* conv_w = (const float*)d_in[2];
    const float* conv_b = (const float*)d_in[3];
    const float* W_x    = (const float*)d_in[4];
    const float* W_dt   = (const float*)d_in[5];
    const float* b_dt   = (const float*)d_in[6];
    const float* A_log  = (const float*)d_in[7];
    const float* Dp     = (const float*)d_in[8];
    const float* W_out  = (const float*)d_in[9];
    float* out = (float*)d_out;

    const size_t M1 = 1024u * 1024u;
    // floats: xz 8M | x_act 4M | dbc .1875M | dt 4M
    // shorts: xhi 2M | xlo 2M | winh 4M | wouth 2M | yh 4M | yl 4M
    // P (2M floats) aliases xhi+xlo; F (2M floats) aliases winh (dead after
    // in_proj). dbc split-K partials alias yh/yl (dead until scan_part2).
    const size_t fXZ = 8 * M1, fXACT = 4 * M1, fDBC = (size_t)BT * 96,
                 fDT = 4 * M1;
    const size_t need = (fXZ + fXACT + fDBC + fDT) * 4 + 18 * M1 * 2;

    if (ws_size >= need) {
        float* ws    = (float*)d_ws;
        float* xz    = ws;
        float* x_act = xz    + fXZ;
        float* dbc   = x_act + fXACT;
        float* dtbuf = dbc   + fDBC;
        u16* xhi   = (u16*)(dtbuf + fDT);
        u16* xlo   = xhi   + 2 * M1;
        u16* winh  = xlo   + 2 * M1;
        u16* wouth = winh  + 4 * M1;
        u16* yh    = wouth + 2 * M1;   // 4M shorts
        u16* yl    = yh    + 4 * M1;   // 4M shorts
        float* Pbuf = (float*)xhi;     // 2M floats (xhi+xlo region)
        float* Fbuf = (float*)winh;    // 2M floats (winh region)
        float* dbc_part = (float*)yh;  // 12.6 MB < 16 MB

        // 1) convert: x -> hi/lo, W_in -> hi, W_out -> hi
        prep_kernel<<<dim3((8 * M1) / 2048), 256, 0, stream>>>(
            x, W_in, W_out, xhi, xlo, winh, wouth);

        // 2) in_proj: xz[2048][4096] = x @ W_in^T
        gemm_mfma2<128, 256, 64, 128><<<dim3(4096 / 256, BT / 128), 256, 0, stream>>>(
            xhi, xlo, D_MODEL, winh, D_MODEL, xz, 4096, D_MODEL);

        // 3) conv + SiLU (x_in = xz[:, :2048])
        conv_silu_kernel<<<dim3((BT * D_INNER) / 256), 256, 0, stream>>>(
            xz, 4096, conv_w, conv_b, x_act);

        // 4) dbc = x_act @ W_x^T (fp32 split-K)
        gemm_nt_splitk<64,32,16,4,4><<<dim3(96 / 32, BT / 64, KSPLIT), 128, 0, stream>>>(
            x_act, D_INNER, W_x, D_INNER, dbc_part, 96, D_INNER / KSPLIT);
        reduce_splitk<<<dim3((BT * 96 + 255) / 256), 256, 0, stream>>>(
            dbc_part, dbc, BT * 96);

        // 5) dt = softplus(dbc[:, :64] @ W_dt^T + b_dt) (fp32)
        gemm_nt<64,64,16,4,4,1><<<dim3(D_INNER / 64, BT / 64), 256, 0, stream>>>(
            dbc, 96, W_dt, DT_RANK, dtbuf, D_INNER, DT_RANK, b_dt);

        // 6) chunked scan + skip + gate; emit yf as bf16 hi/lo
        scan_part1<<<dim3(D_INNER / 256, NCHUNK, BATCH), 256, 0, stream>>>(
            dtbuf, x_act, dbc, A_log, Pbuf, Fbuf);
        scan_combine<<<dim3((BATCH * 16 * D_INNER) / 256), 256, 0, stream>>>(
            Pbuf, Fbuf);
        scan_part2<1><<<dim3(D_INNER / 256, NCHUNK, BATCH), 256, 0, stream>>>(
            dtbuf, x_act, dbc, A_log, Dp, Fbuf, xz + D_INNER, 4096,
            nullptr, yh, yl);

        // 7) out_proj: out = yf @ W_out^T
        gemm_mfma2<64, 128, 32, 64><<<dim3(D_MODEL / 128, BT / 64), 256, 0, stream>>>(
            yh, yl, D_INNER, wouth, D_INNER, out, D_MODEL, D_INNER);
    } else {
        // ------------------- fallback: all-fp32 path -----------------------
        float* ws    = (float*)d_ws;
        float* x_in  = ws;
        float* z     = x_in  + (size_t)BT * D_INNER;
        float* x_act = z     + (size_t)BT * D_INNER;
        float* dbc   = x_act + (size_t)BT * D_INNER;
        float* Pbuf  = dbc   + (size_t)BT * 96;
        float* Fbuf  = Pbuf  + (size_t)BATCH * NCHUNK * 16 * D_INNER;
        float* dtbuf = x_in;
        float* yf    = z;

        gemm_nt<64,64,16,4,4,0><<<dim3(D_INNER/64, BT/64), 256, 0, stream>>>(
            x, D_MODEL, W_in, D_MODEL, x_in, D_INNER, D_MODEL, nullptr);
        gemm_nt<64,64,16,4,4,0><<<dim3(D_INNER/64, BT/64), 256, 0, stream>>>(
            x, D_MODEL, W_in + (size_t)D_INNER * D_MODEL, D_MODEL, z, D_INNER, D_MODEL, nullptr);
        conv_silu_kernel<<<dim3((BT * D_INNER) / 256), 256, 0, stream>>>(
            x_in, D_INNER, conv_w, conv_b, x_act);
        gemm_nt<64,32,16,4,4,0><<<dim3(96/32, BT/64), 128, 0, stream>>>(
            x_act, D_INNER, W_x, D_INNER, dbc, 96, D_INNER, nullptr);
        gemm_nt<64,64,16,4,4,1><<<dim3(D_INNER/64, BT/64), 256, 0, stream>>>(
            dbc, 96, W_dt, DT_RANK, dtbuf, D_INNER, DT_RANK, b_dt);
        scan_part1<<<dim3(D_INNER/256, NCHUNK, BATCH), 256, 0, stream>>>(
            dtbuf, x_act, dbc, A_log, Pbuf, Fbuf);
        scan_combine<<<dim3((BATCH * 16 * D_INNER) / 256), 256, 0, stream>>>(
            Pbuf, Fbuf);
        scan_part2<0><<<dim3(D_INNER/256, NCHUNK, BATCH), 256, 0, stream>>>(
            dtbuf, x_act, dbc, A_log, Dp, Fbuf, z, D_INNER, yf, nullptr, nullptr);
        gemm_nt<64,64,16,4,4,0><<<dim3(D_MODEL/64, BT/64), 256, 0, stream>>>(
            yf, D_INNER, W_out, D_INNER, out, D_MODEL, D_INNER, nullptr);
    }
}

// Round 10
// 193.388 us; speedup vs baseline: 1.7292x; 1.1174x over previous
//
#include <hip/hip_runtime.h>
#include <math.h>

#define D_MODEL 1024
#define D_STATE 16
#define D_CONV  4
#define DT_RANK 64
#define D_INNER 2048
#define BATCH   2
#define SEQ     1024
#define BT      (BATCH*SEQ)   // 2048 rows
#define NCHUNK  32
#define CLEN    (SEQ/NCHUNK)  // 32
#define KSPLIT  16            // split-K factor for dbc GEMM

typedef int   v4i __attribute__((ext_vector_type(4)));
typedef float v4f __attribute__((ext_vector_type(4)));
typedef short s8v __attribute__((ext_vector_type(8)));
typedef unsigned short u16;

// ===========================================================================
// fp32 GEMM (dt projection + fallback path)
// ===========================================================================
template<int BM, int BN, int BK, int TM, int TN, int EPI>
__launch_bounds__(256)
__global__ void gemm_nt(const float* __restrict__ A, int lda,
                        const float* __restrict__ B, int ldb,
                        float* __restrict__ C, int ldc,
                        int K, const float* __restrict__ bias) {
    constexpr int BX = BN / TN;
    constexpr int BY = BM / TM;
    constexpr int THREADS = BX * BY;

    __shared__ float As[BK][BM + 1];
    __shared__ float Bs[BK][BN + 1];

    const int tid = threadIdx.x;
    const int tx  = tid % BX;
    const int ty  = tid / BX;
    const int m0  = blockIdx.y * BM;
    const int n0  = blockIdx.x * BN;

    float acc[TM][TN] = {};

    for (int k0 = 0; k0 < K; k0 += BK) {
        #pragma unroll
        for (int l = 0; l < (BM * BK) / (THREADS * 4); ++l) {
            int idx = (tid + l * THREADS) * 4;
            int row = idx / BK, col = idx % BK;
            const float4 v = *reinterpret_cast<const float4*>(
                &A[(size_t)(m0 + row) * lda + k0 + col]);
            As[col + 0][row] = v.x; As[col + 1][row] = v.y;
            As[col + 2][row] = v.z; As[col + 3][row] = v.w;
        }
        #pragma unroll
        for (int l = 0; l < (BN * BK) / (THREADS * 4); ++l) {
            int idx = (tid + l * THREADS) * 4;
            int row = idx / BK, col = idx % BK;
            const float4 v = *reinterpret_cast<const float4*>(
                &B[(size_t)(n0 + row) * ldb + k0 + col]);
            Bs[col + 0][row] = v.x; Bs[col + 1][row] = v.y;
            Bs[col + 2][row] = v.z; Bs[col + 3][row] = v.w;
        }
        __syncthreads();

        #pragma unroll
        for (int kk = 0; kk < BK; ++kk) {
            float a[TM], b[TN];
            #pragma unroll
            for (int i = 0; i < TM; ++i) a[i] = As[kk][ty * TM + i];
            #pragma unroll
            for (int j = 0; j < TN; ++j) b[j] = Bs[kk][tx * TN + j];
            #pragma unroll
            for (int i = 0; i < TM; ++i)
                #pragma unroll
                for (int j = 0; j < TN; ++j)
                    acc[i][j] = fmaf(a[i], b[j], acc[i][j]);
        }
        __syncthreads();
    }

    #pragma unroll
    for (int i = 0; i < TM; ++i) {
        float* outp = &C[(size_t)(m0 + ty * TM + i) * ldc + n0 + tx * TN];
        float vals[4];
        #pragma unroll
        for (int j = 0; j < TN; ++j) {
            float val = acc[i][j];
            if (EPI == 1) {
                val += bias[n0 + tx * TN + j];
                val = (val > 20.f) ? val : log1pf(expf(val));
            }
            vals[j] = val;
        }
        float4 v;
        v.x = vals[0]; v.y = vals[1]; v.z = vals[2]; v.w = vals[3];
        *reinterpret_cast<float4*>(outp) = v;
    }
}

// ===========================================================================
// Split-K fp32 GEMM for the skinny dbc projection (N=96, K=2048).
// ===========================================================================
template<int BM, int BN, int BK, int TM, int TN>
__launch_bounds__(128)
__global__ void gemm_nt_splitk(const float* __restrict__ A, int lda,
                               const float* __restrict__ B, int ldb,
                               float* __restrict__ part, int N, int kchunk) {
    constexpr int BX = BN / TN;
    constexpr int BY = BM / TM;
    constexpr int THREADS = BX * BY;

    __shared__ float As[BK][BM + 1];
    __shared__ float Bs[BK][BN + 1];

    const int tid = threadIdx.x;
    const int tx  = tid % BX;
    const int ty  = tid / BX;
    const int m0  = blockIdx.y * BM;
    const int n0  = blockIdx.x * BN;
    const int kb  = blockIdx.z * kchunk;

    float acc[TM][TN] = {};

    for (int k0 = kb; k0 < kb + kchunk; k0 += BK) {
        #pragma unroll
        for (int l = 0; l < (BM * BK) / (THREADS * 4); ++l) {
            int idx = (tid + l * THREADS) * 4;
            int row = idx / BK, col = idx % BK;
            const float4 v = *reinterpret_cast<const float4*>(
                &A[(size_t)(m0 + row) * lda + k0 + col]);
            As[col + 0][row] = v.x; As[col + 1][row] = v.y;
            As[col + 2][row] = v.z; As[col + 3][row] = v.w;
        }
        #pragma unroll
        for (int l = 0; l < (BN * BK) / (THREADS * 4); ++l) {
            int idx = (tid + l * THREADS) * 4;
            int row = idx / BK, col = idx % BK;
            const float4 v = *reinterpret_cast<const float4*>(
                &B[(size_t)(n0 + row) * ldb + k0 + col]);
            Bs[col + 0][row] = v.x; Bs[col + 1][row] = v.y;
            Bs[col + 2][row] = v.z; Bs[col + 3][row] = v.w;
        }
        __syncthreads();

        #pragma unroll
        for (int kk = 0; kk < BK; ++kk) {
            float a[TM], b[TN];
            #pragma unroll
            for (int i = 0; i < TM; ++i) a[i] = As[kk][ty * TM + i];
            #pragma unroll
            for (int j = 0; j < TN; ++j) b[j] = Bs[kk][tx * TN + j];
            #pragma unroll
            for (int i = 0; i < TM; ++i)
                #pragma unroll
                for (int j = 0; j < TN; ++j)
                    acc[i][j] = fmaf(a[i], b[j], acc[i][j]);
        }
        __syncthreads();
    }

    float* base = part + (size_t)blockIdx.z * BT * N;
    #pragma unroll
    for (int i = 0; i < TM; ++i) {
        float* outp = &base[(size_t)(m0 + ty * TM + i) * N + n0 + tx * TN];
        float4 v;
        v.x = acc[i][0]; v.y = acc[i][1]; v.z = acc[i][2]; v.w = acc[i][3];
        *reinterpret_cast<float4*>(outp) = v;
    }
}

__global__ void reduce_splitk(const float* __restrict__ part,
                              float* __restrict__ outp, int n) {
    const int idx = blockIdx.x * 256 + threadIdx.x;
    if (idx >= n) return;
    float s = 0.f;
    #pragma unroll
    for (int kc = 0; kc < KSPLIT; ++kc)
        s += part[(size_t)kc * n + idx];
    outp[idx] = s;
}

// ===========================================================================
// bf16 helpers
// ===========================================================================
__device__ __forceinline__ u16 rne_bf16(float x) {
    unsigned int u = __float_as_uint(x);
    unsigned int r = u + 0x7FFFu + ((u >> 16) & 1u);
    return (u16)(r >> 16);
}

// One pass converting to bf16 (hi only): x, W_in, W_out.
// Segments (elements): [0,2M) x | [2M,6M) W_in | [6M,8M) W_out
__global__ void prep_kernel(const float* __restrict__ x,
                            const float* __restrict__ Win,
                            const float* __restrict__ Wout,
                            u16* __restrict__ xh,
                            u16* __restrict__ winh, u16* __restrict__ wouth) {
    const size_t M2 = 2u * 1024u * 1024u;
    size_t i = ((size_t)blockIdx.x * 256 + threadIdx.x) * 8;
    const float* src;
    u16* dst;
    size_t j;
    if (i < M2)            { src = x;    dst = xh;    j = i; }
    else if (i < 3 * M2)   { src = Win;  dst = winh;  j = i - M2; }
    else                   { src = Wout; dst = wouth; j = i - 3 * M2; }
    float4 a = *reinterpret_cast<const float4*>(&src[j]);
    float4 b = *reinterpret_cast<const float4*>(&src[j + 4]);
    float xs[8] = {a.x, a.y, a.z, a.w, b.x, b.y, b.z, b.w};
    unsigned int hw[4];
    #pragma unroll
    for (int q = 0; q < 4; ++q)
        hw[q] = (unsigned int)rne_bf16(xs[2*q]) | ((unsigned int)rne_bf16(xs[2*q+1]) << 16);
    *reinterpret_cast<v4i*>(&dst[j]) = *reinterpret_cast<v4i*>(hw);
}

// ===========================================================================
// Plain bf16 MFMA GEMM: C = bf16(A) @ bf16(B)^T, fp32 accumulate.
// m97-proven shape: 128x128 tile, 4 waves (64x64 each), BK=32, 8 ds_read
// per 16 MFMA per wave per iter. Double-buffered LDS, one barrier/iter,
// k+2 global prefetch in regs. Pitch 40 shorts (80B) -> ~2-way conflicts.
// ===========================================================================
template<int BM, int BN, int WM, int WN>
__launch_bounds__(256)
__global__ void gemm_bf16(const u16* __restrict__ Ahi, int lda,
                          const u16* __restrict__ Bhi, int ldb,
                          float* __restrict__ C, int ldc, int K) {
    constexpr int ACH = BM / 64;          // 16B chunks per thread for A
    constexpr int BCH = BN / 64;
    constexpr int WMF = WM / 16;
    constexpr int WNF = WN / 16;
    constexpr int SA  = BM * 40;          // shorts for A tile
    constexpr int SB  = BN * 40;
    constexpr int BUFSZ = SA + SB;
    constexpr int WCOLS = BN / WN;

    __shared__ u16 smem[2 * BUFSZ];

    const int tid  = threadIdx.x;
    const int lane = tid & 63;
    const int wave = tid >> 6;
    const int wr   = wave / WCOLS, wc = wave % WCOLS;
    const int m0   = blockIdx.y * BM, n0 = blockIdx.x * BN;

    size_t aBase[ACH]; int aW[ACH];
    #pragma unroll
    for (int q = 0; q < ACH; ++q) {
        int c = tid + q * 256, row = c >> 2, slot = c & 3;
        aBase[q] = (size_t)(m0 + row) * lda + slot * 8;
        aW[q] = row * 40 + slot * 8;
    }
    size_t bBase[BCH]; int bW[BCH];
    #pragma unroll
    for (int q = 0; q < BCH; ++q) {
        int c = tid + q * 256, row = c >> 2, slot = c & 3;
        bBase[q] = (size_t)(n0 + row) * ldb + slot * 8;
        bW[q] = row * 40 + slot * 8;
    }

    const int fr = lane & 15;
    const int fk = (lane >> 4) * 8;
    const int fq = lane >> 4;
    int aOff[WMF], bOff[WNF];
    #pragma unroll
    for (int i = 0; i < WMF; ++i) aOff[i] = (wr * WM + i * 16 + fr) * 40 + fk;
    #pragma unroll
    for (int j = 0; j < WNF; ++j) bOff[j] = (wc * WN + j * 16 + fr) * 40 + fk;

    v4f acc[WMF][WNF];
    #pragma unroll
    for (int i = 0; i < WMF; ++i)
        #pragma unroll
        for (int j = 0; j < WNF; ++j)
            acc[i][j] = (v4f)0.f;

    v4i rA[ACH], rB[BCH];

    auto loadg = [&](int k0) {
        #pragma unroll
        for (int q = 0; q < ACH; ++q)
            rA[q] = *reinterpret_cast<const v4i*>(Ahi + aBase[q] + k0);
        #pragma unroll
        for (int q = 0; q < BCH; ++q)
            rB[q] = *reinterpret_cast<const v4i*>(Bhi + bBase[q] + k0);
    };
    auto writelds = [&](u16* buf) {
        #pragma unroll
        for (int q = 0; q < ACH; ++q)
            *reinterpret_cast<v4i*>(&buf[aW[q]]) = rA[q];
        #pragma unroll
        for (int q = 0; q < BCH; ++q)
            *reinterpret_cast<v4i*>(&buf[SA + bW[q]]) = rB[q];
    };

    const int NK = K / 32;
    loadg(0);
    writelds(smem);
    if (NK > 1) loadg(32);
    __syncthreads();

    for (int k = 0; k < NK; ++k) {
        u16* cur = smem + (k & 1) * BUFSZ;
        if (k + 1 < NK) {
            writelds(smem + ((k + 1) & 1) * BUFSZ);   // tile k+1 (in regs)
            if (k + 2 < NK) loadg((k + 2) * 32);      // tile k+2 in flight
        }

        s8v ah[WMF];
        #pragma unroll
        for (int i = 0; i < WMF; ++i)
            ah[i] = *reinterpret_cast<const s8v*>(&cur[aOff[i]]);
        #pragma unroll
        for (int j = 0; j < WNF; ++j) {
            const s8v bh = *reinterpret_cast<const s8v*>(&cur[SA + bOff[j]]);
            #pragma unroll
            for (int i = 0; i < WMF; ++i)
                acc[i][j] = __builtin_amdgcn_mfma_f32_16x16x32_bf16(ah[i], bh, acc[i][j], 0, 0, 0);
        }
        __syncthreads();
    }

    #pragma unroll
    for (int i = 0; i < WMF; ++i) {
        const int row = m0 + wr * WM + i * 16 + fq * 4;
        #pragma unroll
        for (int j = 0; j < WNF; ++j) {
            const int col = n0 + wc * WN + j * 16 + fr;
            #pragma unroll
            for (int r = 0; r < 4; ++r)
                C[(size_t)(row + r) * ldc + col] = acc[i][j][r];
        }
    }
}

// ===========================================================================
// Depthwise causal conv (width 4) + bias + SiLU.
// ===========================================================================
__global__ void conv_silu_kernel(const float* __restrict__ x_in, int xld,
                                 const float* __restrict__ w,
                                 const float* __restrict__ b,
                                 float* __restrict__ x_act) {
    const int idx = blockIdx.x * blockDim.x + threadIdx.x;
    const int ch = idx % D_INNER;
    const int m  = idx / D_INNER;
    const int t  = m % SEQ;

    float acc = b[ch];
    #pragma unroll
    for (int j = 0; j < D_CONV; ++j) {
        int tt = t - (D_CONV - 1) + j;
        if (tt >= 0)
            acc = fmaf(w[ch * D_CONV + j], x_in[(size_t)(m - (D_CONV - 1) + j) * xld + ch], acc);
    }
    x_act[idx] = acc / (1.f + __expf(-acc));
}

// ===========================================================================
// Chunked selective scan. NCHUNK=32 (512 blocks, 8 waves/CU), simple
// per-step bodies (VGPR ~56, no spill; manual ILP batching spills — r6/7).
// ===========================================================================
__launch_bounds__(256)
__global__ void scan_part1(const float* __restrict__ dt,
                           const float* __restrict__ x_act,
                           const float* __restrict__ dbc,
                           const float* __restrict__ A_log,
                           float* __restrict__ P, float* __restrict__ F) {
    __shared__ float Bsh[CLEN][D_STATE];   // 2 KB
    const int tid = threadIdx.x;
    const int d = blockIdx.x * 256 + tid;
    const int c = blockIdx.y;
    const int b = blockIdx.z;
    const int mbase = b * SEQ + c * CLEN;

    {   // stage B rows: CLEN*16 = 512 floats, 2 per thread
        const int s = tid & 15, t0 = tid >> 4;
        #pragma unroll
        for (int q = 0; q < 2; ++q)
            Bsh[t0 + 16 * q][s] = dbc[(size_t)(mbase + t0 + 16 * q) * 96 + DT_RANK + s];
    }
    float A[16];
    #pragma unroll
    for (int q = 0; q < 4; ++q) {
        float4 v = *reinterpret_cast<const float4*>(&A_log[d * 16 + q * 4]);
        A[q*4+0] = -__expf(v.x); A[q*4+1] = -__expf(v.y);
        A[q*4+2] = -__expf(v.z); A[q*4+3] = -__expf(v.w);
    }
    __syncthreads();

    float h[16] = {};
    float Pp[16];
    #pragma unroll
    for (int s = 0; s < 16; ++s) Pp[s] = 1.f;

    for (int t = 0; t < CLEN; ++t) {
        const int m = mbase + t;
        const float dtv = dt[(size_t)m * D_INNER + d];
        const float u   = x_act[(size_t)m * D_INNER + d];
        const float du  = dtv * u;
        float Bv[16];
        #pragma unroll
        for (int q = 0; q < 4; ++q) {
            float4 v = *reinterpret_cast<const float4*>(&Bsh[t][q * 4]);
            Bv[q*4+0] = v.x; Bv[q*4+1] = v.y; Bv[q*4+2] = v.z; Bv[q*4+3] = v.w;
        }
        #pragma unroll
        for (int s = 0; s < 16; ++s) {
            const float dA = __expf(dtv * A[s]);
            Pp[s] *= dA;
            h[s] = fmaf(dA, h[s], du * Bv[s]);
        }
    }
    const size_t base = ((size_t)(b * NCHUNK + c) * 16) * D_INNER + d;
    #pragma unroll
    for (int s = 0; s < 16; ++s) {
        P[base + (size_t)s * D_INNER] = Pp[s];
        F[base + (size_t)s * D_INNER] = h[s];
    }
}

// Batch-load all chunk summaries to registers, serial combine, store back.
__launch_bounds__(256, 2)
__global__ void scan_combine(const float* __restrict__ P, float* F) {
    const int idx = blockIdx.x * 256 + threadIdx.x;    // over B*16*D_INNER
    const int d  = idx % D_INNER;
    const int bs = idx / D_INNER;
    const int b  = bs >> 4, s = bs & 15;
    const size_t base0 = ((size_t)b * NCHUNK * 16 + s) * D_INNER + d;
    const size_t cstep = (size_t)16 * D_INNER;

    float Pv[NCHUNK], Fv[NCHUNK];
    #pragma unroll
    for (int c = 0; c < NCHUNK; ++c) {
        Pv[c] = P[base0 + c * cstep];
        Fv[c] = F[base0 + c * cstep];
    }
    float G = 0.f;
    #pragma unroll
    for (int c = 0; c < NCHUNK; ++c) {
        const float f = Fv[c];
        Fv[c] = G;                       // initial state for chunk c
        G = fmaf(Pv[c], G, f);
    }
    #pragma unroll
    for (int c = 0; c < NCHUNK; ++c)
        F[base0 + c * cstep] = Fv[c];
}

// BF16OUT=1: emit yf as bf16 (hi only) for the MFMA out_proj (no z/y alias).
// BF16OUT=0: fp32 yf (fallback; zp aliases yf -> z preloaded per half).
template<int BF16OUT>
__launch_bounds__(256)
__global__ void scan_part2(const float* __restrict__ dt,
                           const float* __restrict__ x_act,
                           const float* __restrict__ dbc,
                           const float* __restrict__ A_log,
                           const float* __restrict__ Dp,
                           const float* __restrict__ Ginit,
                           const float* zp, int zld,
                           float* yf, u16* yh) {
    __shared__ float BCs[CLEN][32];   // [t][0:16]=B, [16:32]=C ; 4 KB
    const int tid = threadIdx.x;
    const int d = blockIdx.x * 256 + tid;
    const int c = blockIdx.y;
    const int b = blockIdx.z;
    const int mbase = b * SEQ + c * CLEN;

    {   // stage B+C: CLEN*32 = 1024 floats, one float4 per thread
        const int t0 = tid >> 3;            // 0..31
        const int j  = (tid & 7) * 4;       // 0..28
        float4 v = *reinterpret_cast<const float4*>(
            &dbc[(size_t)(mbase + t0) * 96 + DT_RANK + j]);
        *reinterpret_cast<float4*>(&BCs[t0][j]) = v;
    }
    float A[16];
    #pragma unroll
    for (int q = 0; q < 4; ++q) {
        float4 v = *reinterpret_cast<const float4*>(&A_log[d * 16 + q * 4]);
        A[q*4+0] = -__expf(v.x); A[q*4+1] = -__expf(v.y);
        A[q*4+2] = -__expf(v.z); A[q*4+3] = -__expf(v.w);
    }
    float h[16];
    const size_t gbase = ((size_t)(b * NCHUNK + c) * 16) * D_INNER + d;
    #pragma unroll
    for (int s = 0; s < 16; ++s) h[s] = Ginit[gbase + (size_t)s * D_INNER];
    const float Dv = Dp[d];
    __syncthreads();

    for (int half = 0; half < 2; ++half) {
        const int tb = half * (CLEN / 2);
        float zreg[CLEN / 2];
        #pragma unroll
        for (int t = 0; t < CLEN / 2; ++t)
            zreg[t] = zp[(size_t)(mbase + tb + t) * zld + d];

        for (int t = 0; t < CLEN / 2; ++t) {
            const int m = mbase + tb + t;
            const float dtv = dt[(size_t)m * D_INNER + d];
            const float u   = x_act[(size_t)m * D_INNER + d];
            const float du  = dtv * u;
            float Bv[16], Cv[16];
            #pragma unroll
            for (int q = 0; q < 4; ++q) {
                float4 vb = *reinterpret_cast<const float4*>(&BCs[tb + t][q * 4]);
                float4 vc = *reinterpret_cast<const float4*>(&BCs[tb + t][16 + q * 4]);
                Bv[q*4+0] = vb.x; Bv[q*4+1] = vb.y; Bv[q*4+2] = vb.z; Bv[q*4+3] = vb.w;
                Cv[q*4+0] = vc.x; Cv[q*4+1] = vc.y; Cv[q*4+2] = vc.z; Cv[q*4+3] = vc.w;
            }
            float y0 = 0.f, y1 = 0.f;
            #pragma unroll
            for (int s = 0; s < 16; s += 2) {
                const float dA0 = __expf(dtv * A[s]);
                const float dA1 = __expf(dtv * A[s + 1]);
                h[s]     = fmaf(dA0, h[s],     du * Bv[s]);
                h[s + 1] = fmaf(dA1, h[s + 1], du * Bv[s + 1]);
                y0 = fmaf(h[s],     Cv[s],     y0);
                y1 = fmaf(h[s + 1], Cv[s + 1], y1);
            }
            float y = y0 + y1;
            y = fmaf(u, Dv, y);
            const float zv = zreg[t];
            const float g  = zv / (1.f + __expf(-zv));
            const float val = y * g;
            if (BF16OUT) {
                yh[(size_t)m * D_INNER + d] = rne_bf16(val);
            } else {
                yf[(size_t)m * D_INNER + d] = val;
            }
        }
    }
}

// ===========================================================================
extern "C" void kernel_launch(void* const* d_in, const int* in_sizes, int n_in,
                              void* d_out, int out_size, void* d_ws, size_t ws_size,
                              hipStream_t stream) {
    const float* x      = (const float*)d_in[0];
    const float* W_in   = (const float*)d_in[1];
    const float* conv_w = (const float*)d_in[2];
    const float* conv_b = (const float*)d_in[3];
    const float* W_x    = (const float*)d_in[4];
    const float* W_dt   = (const float*)d_in[5];
    const float* b_dt   = (const float*)d_in[6];
    const float* A_log  = (const float*)d_in[7];
    const float* Dp     = (const float*)d_in[8];
    const float* W_out  = (const float*)d_in[9];
    float* out = (float*)d_out;

    const size_t M1 = 1024u * 1024u;
    // floats: xz 8M | x_act 4M | dbc .1875M | dt 4M | P 2M | F 2M
    // shorts: xh 2M | winh 4M | wouth 2M | yh 4M
    // dbc split-K partials (12.6 MB) alias P+F (16 MB, dead until scan_part1)
    const size_t fXZ = 8 * M1, fXACT = 4 * M1, fDBC = (size_t)BT * 96,
                 fDT = 4 * M1, fP = 2 * M1, fF = 2 * M1;
    const size_t need = (fXZ + fXACT + fDBC + fDT + fP + fF) * 4 + 12 * M1 * 2;

    if (ws_size >= need) {
        float* ws    = (float*)d_ws;
        float* xz    = ws;
        float* x_act = xz    + fXZ;
        float* dbc   = x_act + fXACT;
        float* dtbuf = dbc   + fDBC;
        float* Pbuf  = dtbuf + fDT;
        float* Fbuf  = Pbuf  + fP;
        u16* xh    = (u16*)(Fbuf + fF);
        u16* winh  = xh    + 2 * M1;
        u16* wouth = winh  + 4 * M1;
        u16* yh    = wouth + 2 * M1;   // 4M shorts
        float* dbc_part = Pbuf;        // 12.6 MB < 16 MB (P+F)

        // 1) convert to bf16-hi: x, W_in, W_out
        prep_kernel<<<dim3((8 * M1) / 2048), 256, 0, stream>>>(
            x, W_in, W_out, xh, winh, wouth);

        // 2) in_proj: xz[2048][4096] = x @ W_in^T   (128x128, 512 blocks)
        gemm_bf16<128, 128, 64, 64><<<dim3(4096 / 128, BT / 128), 256, 0, stream>>>(
            xh, D_MODEL, winh, D_MODEL, xz, 4096, D_MODEL);

        // 3) conv + SiLU (x_in = xz[:, :2048])
        conv_silu_kernel<<<dim3((BT * D_INNER) / 256), 256, 0, stream>>>(
            xz, 4096, conv_w, conv_b, x_act);

        // 4) dbc = x_act @ W_x^T (fp32 split-K)
        gemm_nt_splitk<64,32,16,4,4><<<dim3(96 / 32, BT / 64, KSPLIT), 128, 0, stream>>>(
            x_act, D_INNER, W_x, D_INNER, dbc_part, 96, D_INNER / KSPLIT);
        reduce_splitk<<<dim3((BT * 96 + 255) / 256), 256, 0, stream>>>(
            dbc_part, dbc, BT * 96);

        // 5) dt = softplus(dbc[:, :64] @ W_dt^T + b_dt) (fp32)
        gemm_nt<64,64,16,4,4,1><<<dim3(D_INNER / 64, BT / 64), 256, 0, stream>>>(
            dbc, 96, W_dt, DT_RANK, dtbuf, D_INNER, DT_RANK, b_dt);

        // 6) chunked scan + skip + gate; emit yf as bf16 hi
        scan_part1<<<dim3(D_INNER / 256, NCHUNK, BATCH), 256, 0, stream>>>(
            dtbuf, x_act, dbc, A_log, Pbuf, Fbuf);
        scan_combine<<<dim3((BATCH * 16 * D_INNER) / 256), 256, 0, stream>>>(
            Pbuf, Fbuf);
        scan_part2<1><<<dim3(D_INNER / 256, NCHUNK, BATCH), 256, 0, stream>>>(
            dtbuf, x_act, dbc, A_log, Dp, Fbuf, xz + D_INNER, 4096,
            nullptr, yh);

        // 7) out_proj: out = yf @ W_out^T   (64x128 -> 256 blocks)
        gemm_bf16<64, 128, 32, 64><<<dim3(D_MODEL / 128, BT / 64), 256, 0, stream>>>(
            yh, D_INNER, wouth, D_INNER, out, D_MODEL, D_INNER);
    } else {
        // ------------------- fallback: all-fp32 path -----------------------
        float* ws    = (float*)d_ws;
        float* x_in  = ws;
        float* z     = x_in  + (size_t)BT * D_INNER;
        float* x_act = z     + (size_t)BT * D_INNER;
        float* dbc   = x_act + (size_t)BT * D_INNER;
        float* Pbuf  = dbc   + (size_t)BT * 96;
        float* Fbuf  = Pbuf  + (size_t)BATCH * NCHUNK * 16 * D_INNER;
        float* dtbuf = x_in;
        float* yf    = z;

        gemm_nt<64,64,16,4,4,0><<<dim3(D_INNER/64, BT/64), 256, 0, stream>>>(
            x, D_MODEL, W_in, D_MODEL, x_in, D_INNER, D_MODEL, nullptr);
        gemm_nt<64,64,16,4,4,0><<<dim3(D_INNER/64, BT/64), 256, 0, stream>>>(
            x, D_MODEL, W_in + (size_t)D_INNER * D_MODEL, D_MODEL, z, D_INNER, D_MODEL, nullptr);
        conv_silu_kernel<<<dim3((BT * D_INNER) / 256), 256, 0, stream>>>(
            x_in, D_INNER, conv_w, conv_b, x_act);
        gemm_nt<64,32,16,4,4,0><<<dim3(96/32, BT/64), 128, 0, stream>>>(
            x_act, D_INNER, W_x, D_INNER, dbc, 96, D_INNER, nullptr);
        gemm_nt<64,64,16,4,4,1><<<dim3(D_INNER/64, BT/64), 256, 0, stream>>>(
            dbc, 96, W_dt, DT_RANK, dtbuf, D_INNER, DT_RANK, b_dt);
        scan_part1<<<dim3(D_INNER/256, NCHUNK, BATCH), 256, 0, stream>>>(
            dtbuf, x_act, dbc, A_log, Pbuf, Fbuf);
        scan_combine<<<dim3((BATCH * 16 * D_INNER) / 256), 256, 0, stream>>>(
            Pbuf, Fbuf);
        scan_part2<0><<<dim3(D_INNER/256, NCHUNK, BATCH), 256, 0, stream>>>(
            dtbuf, x_act, dbc, A_log, Dp, Fbuf, z, D_INNER, yf, nullptr);
        gemm_nt<64,64,16,4,4,0><<<dim3(D_MODEL/64, BT/64), 256, 0, stream>>>(
            yf, D_INNER, W_out, D_INNER, out, D_MODEL, D_INNER, nullptr);
    }
}

// Round 11
// 181.753 us; speedup vs baseline: 1.8399x; 1.0640x over previous
//
#include <hip/hip_runtime.h>
#include <math.h>

#define D_MODEL 1024
#define D_STATE 16
#define D_CONV  4
#define DT_RANK 64
#define D_INNER 2048
#define BATCH   2
#define SEQ     1024
#define BT      (BATCH*SEQ)   // 2048 rows
#define KSPLIT  16            // split-K factor for dbc GEMM

typedef int   v4i __attribute__((ext_vector_type(4)));
typedef float v4f __attribute__((ext_vector_type(4)));
typedef short s8v __attribute__((ext_vector_type(8)));
typedef unsigned short u16;

// ===========================================================================
// fp32 GEMM (dt projection + fallback path)
// ===========================================================================
template<int BM, int BN, int BK, int TM, int TN, int EPI>
__launch_bounds__(256)
__global__ void gemm_nt(const float* __restrict__ A, int lda,
                        const float* __restrict__ B, int ldb,
                        float* __restrict__ C, int ldc,
                        int K, const float* __restrict__ bias) {
    constexpr int BX = BN / TN;
    constexpr int BY = BM / TM;
    constexpr int THREADS = BX * BY;

    __shared__ float As[BK][BM + 1];
    __shared__ float Bs[BK][BN + 1];

    const int tid = threadIdx.x;
    const int tx  = tid % BX;
    const int ty  = tid / BX;
    const int m0  = blockIdx.y * BM;
    const int n0  = blockIdx.x * BN;

    float acc[TM][TN] = {};

    for (int k0 = 0; k0 < K; k0 += BK) {
        #pragma unroll
        for (int l = 0; l < (BM * BK) / (THREADS * 4); ++l) {
            int idx = (tid + l * THREADS) * 4;
            int row = idx / BK, col = idx % BK;
            const float4 v = *reinterpret_cast<const float4*>(
                &A[(size_t)(m0 + row) * lda + k0 + col]);
            As[col + 0][row] = v.x; As[col + 1][row] = v.y;
            As[col + 2][row] = v.z; As[col + 3][row] = v.w;
        }
        #pragma unroll
        for (int l = 0; l < (BN * BK) / (THREADS * 4); ++l) {
            int idx = (tid + l * THREADS) * 4;
            int row = idx / BK, col = idx % BK;
            const float4 v = *reinterpret_cast<const float4*>(
                &B[(size_t)(n0 + row) * ldb + k0 + col]);
            Bs[col + 0][row] = v.x; Bs[col + 1][row] = v.y;
            Bs[col + 2][row] = v.z; Bs[col + 3][row] = v.w;
        }
        __syncthreads();

        #pragma unroll
        for (int kk = 0; kk < BK; ++kk) {
            float a[TM], b[TN];
            #pragma unroll
            for (int i = 0; i < TM; ++i) a[i] = As[kk][ty * TM + i];
            #pragma unroll
            for (int j = 0; j < TN; ++j) b[j] = Bs[kk][tx * TN + j];
            #pragma unroll
            for (int i = 0; i < TM; ++i)
                #pragma unroll
                for (int j = 0; j < TN; ++j)
                    acc[i][j] = fmaf(a[i], b[j], acc[i][j]);
        }
        __syncthreads();
    }

    #pragma unroll
    for (int i = 0; i < TM; ++i) {
        float* outp = &C[(size_t)(m0 + ty * TM + i) * ldc + n0 + tx * TN];
        float vals[4];
        #pragma unroll
        for (int j = 0; j < TN; ++j) {
            float val = acc[i][j];
            if (EPI == 1) {
                val += bias[n0 + tx * TN + j];
                val = (val > 20.f) ? val : log1pf(expf(val));
            }
            vals[j] = val;
        }
        float4 v;
        v.x = vals[0]; v.y = vals[1]; v.z = vals[2]; v.w = vals[3];
        *reinterpret_cast<float4*>(outp) = v;
    }
}

// ===========================================================================
// Split-K fp32 GEMM for the skinny dbc projection (N=96, K=2048).
// ===========================================================================
template<int BM, int BN, int BK, int TM, int TN>
__launch_bounds__(128)
__global__ void gemm_nt_splitk(const float* __restrict__ A, int lda,
                               const float* __restrict__ B, int ldb,
                               float* __restrict__ part, int N, int kchunk) {
    constexpr int BX = BN / TN;
    constexpr int BY = BM / TM;
    constexpr int THREADS = BX * BY;

    __shared__ float As[BK][BM + 1];
    __shared__ float Bs[BK][BN + 1];

    const int tid = threadIdx.x;
    const int tx  = tid % BX;
    const int ty  = tid / BX;
    const int m0  = blockIdx.y * BM;
    const int n0  = blockIdx.x * BN;
    const int kb  = blockIdx.z * kchunk;

    float acc[TM][TN] = {};

    for (int k0 = kb; k0 < kb + kchunk; k0 += BK) {
        #pragma unroll
        for (int l = 0; l < (BM * BK) / (THREADS * 4); ++l) {
            int idx = (tid + l * THREADS) * 4;
            int row = idx / BK, col = idx % BK;
            const float4 v = *reinterpret_cast<const float4*>(
                &A[(size_t)(m0 + row) * lda + k0 + col]);
            As[col + 0][row] = v.x; As[col + 1][row] = v.y;
            As[col + 2][row] = v.z; As[col + 3][row] = v.w;
        }
        #pragma unroll
        for (int l = 0; l < (BN * BK) / (THREADS * 4); ++l) {
            int idx = (tid + l * THREADS) * 4;
            int row = idx / BK, col = idx % BK;
            const float4 v = *reinterpret_cast<const float4*>(
                &B[(size_t)(n0 + row) * ldb + k0 + col]);
            Bs[col + 0][row] = v.x; Bs[col + 1][row] = v.y;
            Bs[col + 2][row] = v.z; Bs[col + 3][row] = v.w;
        }
        __syncthreads();

        #pragma unroll
        for (int kk = 0; kk < BK; ++kk) {
            float a[TM], b[TN];
            #pragma unroll
            for (int i = 0; i < TM; ++i) a[i] = As[kk][ty * TM + i];
            #pragma unroll
            for (int j = 0; j < TN; ++j) b[j] = Bs[kk][tx * TN + j];
            #pragma unroll
            for (int i = 0; i < TM; ++i)
                #pragma unroll
                for (int j = 0; j < TN; ++j)
                    acc[i][j] = fmaf(a[i], b[j], acc[i][j]);
        }
        __syncthreads();
    }

    float* base = part + (size_t)blockIdx.z * BT * N;
    #pragma unroll
    for (int i = 0; i < TM; ++i) {
        float* outp = &base[(size_t)(m0 + ty * TM + i) * N + n0 + tx * TN];
        float4 v;
        v.x = acc[i][0]; v.y = acc[i][1]; v.z = acc[i][2]; v.w = acc[i][3];
        *reinterpret_cast<float4*>(outp) = v;
    }
}

__global__ void reduce_splitk(const float* __restrict__ part,
                              float* __restrict__ outp, int n) {
    const int idx = blockIdx.x * 256 + threadIdx.x;
    if (idx >= n) return;
    float s = 0.f;
    #pragma unroll
    for (int kc = 0; kc < KSPLIT; ++kc)
        s += part[(size_t)kc * n + idx];
    outp[idx] = s;
}

// ===========================================================================
// bf16 helpers
// ===========================================================================
__device__ __forceinline__ u16 rne_bf16(float x) {
    unsigned int u = __float_as_uint(x);
    unsigned int r = u + 0x7FFFu + ((u >> 16) & 1u);
    return (u16)(r >> 16);
}

// One pass converting to bf16 (hi only): x, W_in, W_out.
__global__ void prep_kernel(const float* __restrict__ x,
                            const float* __restrict__ Win,
                            const float* __restrict__ Wout,
                            u16* __restrict__ xh,
                            u16* __restrict__ winh, u16* __restrict__ wouth) {
    const size_t M2 = 2u * 1024u * 1024u;
    size_t i = ((size_t)blockIdx.x * 256 + threadIdx.x) * 8;
    const float* src;
    u16* dst;
    size_t j;
    if (i < M2)            { src = x;    dst = xh;    j = i; }
    else if (i < 3 * M2)   { src = Win;  dst = winh;  j = i - M2; }
    else                   { src = Wout; dst = wouth; j = i - 3 * M2; }
    float4 a = *reinterpret_cast<const float4*>(&src[j]);
    float4 b = *reinterpret_cast<const float4*>(&src[j + 4]);
    float xs[8] = {a.x, a.y, a.z, a.w, b.x, b.y, b.z, b.w};
    unsigned int hw[4];
    #pragma unroll
    for (int q = 0; q < 4; ++q)
        hw[q] = (unsigned int)rne_bf16(xs[2*q]) | ((unsigned int)rne_bf16(xs[2*q+1]) << 16);
    *reinterpret_cast<v4i*>(&dst[j]) = *reinterpret_cast<v4i*>(hw);
}

// ===========================================================================
// Plain bf16 MFMA GEMM (m97 shape): 128-tile, dbuf LDS, 1 barrier/iter.
// ===========================================================================
template<int BM, int BN, int WM, int WN>
__launch_bounds__(256)
__global__ void gemm_bf16(const u16* __restrict__ Ahi, int lda,
                          const u16* __restrict__ Bhi, int ldb,
                          float* __restrict__ C, int ldc, int K) {
    constexpr int ACH = BM / 64;
    constexpr int BCH = BN / 64;
    constexpr int WMF = WM / 16;
    constexpr int WNF = WN / 16;
    constexpr int SA  = BM * 40;
    constexpr int SB  = BN * 40;
    constexpr int BUFSZ = SA + SB;
    constexpr int WCOLS = BN / WN;

    __shared__ u16 smem[2 * BUFSZ];

    const int tid  = threadIdx.x;
    const int lane = tid & 63;
    const int wave = tid >> 6;
    const int wr   = wave / WCOLS, wc = wave % WCOLS;
    const int m0   = blockIdx.y * BM, n0 = blockIdx.x * BN;

    size_t aBase[ACH]; int aW[ACH];
    #pragma unroll
    for (int q = 0; q < ACH; ++q) {
        int c = tid + q * 256, row = c >> 2, slot = c & 3;
        aBase[q] = (size_t)(m0 + row) * lda + slot * 8;
        aW[q] = row * 40 + slot * 8;
    }
    size_t bBase[BCH]; int bW[BCH];
    #pragma unroll
    for (int q = 0; q < BCH; ++q) {
        int c = tid + q * 256, row = c >> 2, slot = c & 3;
        bBase[q] = (size_t)(n0 + row) * ldb + slot * 8;
        bW[q] = row * 40 + slot * 8;
    }

    const int fr = lane & 15;
    const int fk = (lane >> 4) * 8;
    const int fq = lane >> 4;
    int aOff[WMF], bOff[WNF];
    #pragma unroll
    for (int i = 0; i < WMF; ++i) aOff[i] = (wr * WM + i * 16 + fr) * 40 + fk;
    #pragma unroll
    for (int j = 0; j < WNF; ++j) bOff[j] = (wc * WN + j * 16 + fr) * 40 + fk;

    v4f acc[WMF][WNF];
    #pragma unroll
    for (int i = 0; i < WMF; ++i)
        #pragma unroll
        for (int j = 0; j < WNF; ++j)
            acc[i][j] = (v4f)0.f;

    v4i rA[ACH], rB[BCH];

    auto loadg = [&](int k0) {
        #pragma unroll
        for (int q = 0; q < ACH; ++q)
            rA[q] = *reinterpret_cast<const v4i*>(Ahi + aBase[q] + k0);
        #pragma unroll
        for (int q = 0; q < BCH; ++q)
            rB[q] = *reinterpret_cast<const v4i*>(Bhi + bBase[q] + k0);
    };
    auto writelds = [&](u16* buf) {
        #pragma unroll
        for (int q = 0; q < ACH; ++q)
            *reinterpret_cast<v4i*>(&buf[aW[q]]) = rA[q];
        #pragma unroll
        for (int q = 0; q < BCH; ++q)
            *reinterpret_cast<v4i*>(&buf[SA + bW[q]]) = rB[q];
    };

    const int NK = K / 32;
    loadg(0);
    writelds(smem);
    if (NK > 1) loadg(32);
    __syncthreads();

    for (int k = 0; k < NK; ++k) {
        u16* cur = smem + (k & 1) * BUFSZ;
        if (k + 1 < NK) {
            writelds(smem + ((k + 1) & 1) * BUFSZ);
            if (k + 2 < NK) loadg((k + 2) * 32);
        }

        s8v ah[WMF];
        #pragma unroll
        for (int i = 0; i < WMF; ++i)
            ah[i] = *reinterpret_cast<const s8v*>(&cur[aOff[i]]);
        #pragma unroll
        for (int j = 0; j < WNF; ++j) {
            const s8v bh = *reinterpret_cast<const s8v*>(&cur[SA + bOff[j]]);
            #pragma unroll
            for (int i = 0; i < WMF; ++i)
                acc[i][j] = __builtin_amdgcn_mfma_f32_16x16x32_bf16(ah[i], bh, acc[i][j], 0, 0, 0);
        }
        __syncthreads();
    }

    #pragma unroll
    for (int i = 0; i < WMF; ++i) {
        const int row = m0 + wr * WM + i * 16 + fq * 4;
        #pragma unroll
        for (int j = 0; j < WNF; ++j) {
            const int col = n0 + wc * WN + j * 16 + fr;
            #pragma unroll
            for (int r = 0; r < 4; ++r)
                C[(size_t)(row + r) * ldc + col] = acc[i][j][r];
        }
    }
}

// ===========================================================================
// Depthwise causal conv (width 4) + bias + SiLU. Vectorized: 4 channels
// per thread (float4 loads/stores).
// ===========================================================================
__global__ void conv_silu_kernel(const float* __restrict__ x_in, int xld,
                                 const float* __restrict__ w,
                                 const float* __restrict__ b,
                                 float* __restrict__ x_act) {
    const int idx = blockIdx.x * blockDim.x + threadIdx.x;   // over BT*D_INNER/4
    const int ch4 = (idx * 4) % D_INNER;
    const int m   = (idx * 4) / D_INNER;
    const int t   = m % SEQ;

    float4 wrow[4];
    #pragma unroll
    for (int c = 0; c < 4; ++c)
        wrow[c] = *reinterpret_cast<const float4*>(&w[(ch4 + c) * D_CONV]);
    float4 acc = *reinterpret_cast<const float4*>(&b[ch4]);

    #pragma unroll
    for (int j = 0; j < D_CONV; ++j) {
        const int tt = t - (D_CONV - 1) + j;
        if (tt >= 0) {
            const float4 xi = *reinterpret_cast<const float4*>(
                &x_in[(size_t)(m - (D_CONV - 1) + j) * xld + ch4]);
            acc.x = fmaf(((const float*)&wrow[0])[j], xi.x, acc.x);
            acc.y = fmaf(((const float*)&wrow[1])[j], xi.y, acc.y);
            acc.z = fmaf(((const float*)&wrow[2])[j], xi.z, acc.z);
            acc.w = fmaf(((const float*)&wrow[3])[j], xi.w, acc.w);
        }
    }
    acc.x = acc.x / (1.f + __expf(-acc.x));
    acc.y = acc.y / (1.f + __expf(-acc.y));
    acc.z = acc.z / (1.f + __expf(-acc.z));
    acc.w = acc.w / (1.f + __expf(-acc.w));
    *reinterpret_cast<float4*>(&x_act[(size_t)idx * 4]) = acc;
}

// ===========================================================================
// Chunked selective scan, templated on NC (chunk count). Simple per-step
// bodies (VGPR ~64, no spill; manual ILP batching spills — r6/7 lesson).
// NC=64 -> 1024 blocks -> 16 waves/CU latency hiding.
// ===========================================================================
template<int NC>
__launch_bounds__(256)
__global__ void scan_part1(const float* __restrict__ dt,
                           const float* __restrict__ x_act,
                           const float* __restrict__ dbc,
                           const float* __restrict__ A_log,
                           float* __restrict__ P, float* __restrict__ F) {
    constexpr int CL = SEQ / NC;
    __shared__ float Bsh[CL][D_STATE];
    const int tid = threadIdx.x;
    const int d = blockIdx.x * 256 + tid;
    const int c = blockIdx.y;
    const int b = blockIdx.z;
    const int mbase = b * SEQ + c * CL;

    {   // stage B rows: CL*16 floats, CL/16 per thread
        const int s = tid & 15, t0 = tid >> 4;
        #pragma unroll
        for (int q = 0; q < CL / 16; ++q)
            Bsh[t0 + 16 * q][s] = dbc[(size_t)(mbase + t0 + 16 * q) * 96 + DT_RANK + s];
    }
    float A[16];
    #pragma unroll
    for (int q = 0; q < 4; ++q) {
        float4 v = *reinterpret_cast<const float4*>(&A_log[d * 16 + q * 4]);
        A[q*4+0] = -__expf(v.x); A[q*4+1] = -__expf(v.y);
        A[q*4+2] = -__expf(v.z); A[q*4+3] = -__expf(v.w);
    }
    __syncthreads();

    float h[16] = {};
    float Pp[16];
    #pragma unroll
    for (int s = 0; s < 16; ++s) Pp[s] = 1.f;

    for (int t = 0; t < CL; ++t) {
        const int m = mbase + t;
        const float dtv = dt[(size_t)m * D_INNER + d];
        const float u   = x_act[(size_t)m * D_INNER + d];
        const float du  = dtv * u;
        float Bv[16];
        #pragma unroll
        for (int q = 0; q < 4; ++q) {
            float4 v = *reinterpret_cast<const float4*>(&Bsh[t][q * 4]);
            Bv[q*4+0] = v.x; Bv[q*4+1] = v.y; Bv[q*4+2] = v.z; Bv[q*4+3] = v.w;
        }
        #pragma unroll
        for (int s = 0; s < 16; ++s) {
            const float dA = __expf(dtv * A[s]);
            Pp[s] *= dA;
            h[s] = fmaf(dA, h[s], du * Bv[s]);
        }
    }
    const size_t base = ((size_t)(b * NC + c) * 16) * D_INNER + d;
    #pragma unroll
    for (int s = 0; s < 16; ++s) {
        P[base + (size_t)s * D_INNER] = Pp[s];
        F[base + (size_t)s * D_INNER] = h[s];
    }
}

// Batch-load all chunk summaries to registers, serial combine, store back.
template<int NC>
__launch_bounds__(256, 2)
__global__ void scan_combine(const float* __restrict__ P, float* F) {
    const int idx = blockIdx.x * 256 + threadIdx.x;    // over B*16*D_INNER
    const int d  = idx % D_INNER;
    const int bs = idx / D_INNER;
    const int b  = bs >> 4, s = bs & 15;
    const size_t base0 = ((size_t)b * NC * 16 + s) * D_INNER + d;
    const size_t cstep = (size_t)16 * D_INNER;

    float Pv[NC], Fv[NC];
    #pragma unroll
    for (int c = 0; c < NC; ++c) {
        Pv[c] = P[base0 + c * cstep];
        Fv[c] = F[base0 + c * cstep];
    }
    float G = 0.f;
    #pragma unroll
    for (int c = 0; c < NC; ++c) {
        const float f = Fv[c];
        Fv[c] = G;
        G = fmaf(Pv[c], G, f);
    }
    #pragma unroll
    for (int c = 0; c < NC; ++c)
        F[base0 + c * cstep] = Fv[c];
}

// BF16OUT=1: emit yf as bf16 (hi only). BF16OUT=0: fp32 yf (fallback,
// zp aliases yf -> z preloaded per half-chunk).
template<int NC, int BF16OUT>
__launch_bounds__(256)
__global__ void scan_part2(const float* __restrict__ dt,
                           const float* __restrict__ x_act,
                           const float* __restrict__ dbc,
                           const float* __restrict__ A_log,
                           const float* __restrict__ Dp,
                           const float* __restrict__ Ginit,
                           const float* zp, int zld,
                           float* yf, u16* yh) {
    constexpr int CL = SEQ / NC;
    __shared__ float BCs[CL][32];
    const int tid = threadIdx.x;
    const int d = blockIdx.x * 256 + tid;
    const int c = blockIdx.y;
    const int b = blockIdx.z;
    const int mbase = b * SEQ + c * CL;

    {   // stage B+C: CL*32 floats as float4s
        const int t0 = tid >> 3;            // 0..31
        const int j  = (tid & 7) * 4;
        if (t0 < CL) {
            float4 v = *reinterpret_cast<const float4*>(
                &dbc[(size_t)(mbase + t0) * 96 + DT_RANK + j]);
            *reinterpret_cast<float4*>(&BCs[t0][j]) = v;
        }
    }
    float A[16];
    #pragma unroll
    for (int q = 0; q < 4; ++q) {
        float4 v = *reinterpret_cast<const float4*>(&A_log[d * 16 + q * 4]);
        A[q*4+0] = -__expf(v.x); A[q*4+1] = -__expf(v.y);
        A[q*4+2] = -__expf(v.z); A[q*4+3] = -__expf(v.w);
    }
    float h[16];
    const size_t gbase = ((size_t)(b * NC + c) * 16) * D_INNER + d;
    #pragma unroll
    for (int s = 0; s < 16; ++s) h[s] = Ginit[gbase + (size_t)s * D_INNER];
    const float Dv = Dp[d];
    __syncthreads();

    for (int half = 0; half < 2; ++half) {
        const int tb = half * (CL / 2);
        float zreg[CL / 2];
        #pragma unroll
        for (int t = 0; t < CL / 2; ++t)
            zreg[t] = zp[(size_t)(mbase + tb + t) * zld + d];

        for (int t = 0; t < CL / 2; ++t) {
            const int m = mbase + tb + t;
            const float dtv = dt[(size_t)m * D_INNER + d];
            const float u   = x_act[(size_t)m * D_INNER + d];
            const float du  = dtv * u;
            float Bv[16], Cv[16];
            #pragma unroll
            for (int q = 0; q < 4; ++q) {
                float4 vb = *reinterpret_cast<const float4*>(&BCs[tb + t][q * 4]);
                float4 vc = *reinterpret_cast<const float4*>(&BCs[tb + t][16 + q * 4]);
                Bv[q*4+0] = vb.x; Bv[q*4+1] = vb.y; Bv[q*4+2] = vb.z; Bv[q*4+3] = vb.w;
                Cv[q*4+0] = vc.x; Cv[q*4+1] = vc.y; Cv[q*4+2] = vc.z; Cv[q*4+3] = vc.w;
            }
            float y0 = 0.f, y1 = 0.f;
            #pragma unroll
            for (int s = 0; s < 16; s += 2) {
                const float dA0 = __expf(dtv * A[s]);
                const float dA1 = __expf(dtv * A[s + 1]);
                h[s]     = fmaf(dA0, h[s],     du * Bv[s]);
                h[s + 1] = fmaf(dA1, h[s + 1], du * Bv[s + 1]);
                y0 = fmaf(h[s],     Cv[s],     y0);
                y1 = fmaf(h[s + 1], Cv[s + 1], y1);
            }
            float y = y0 + y1;
            y = fmaf(u, Dv, y);
            const float zv = zreg[t];
            const float g  = zv / (1.f + __expf(-zv));
            const float val = y * g;
            if (BF16OUT) {
                yh[(size_t)m * D_INNER + d] = rne_bf16(val);
            } else {
                yf[(size_t)m * D_INNER + d] = val;
            }
        }
    }
}

// ===========================================================================
extern "C" void kernel_launch(void* const* d_in, const int* in_sizes, int n_in,
                              void* d_out, int out_size, void* d_ws, size_t ws_size,
                              hipStream_t stream) {
    const float* x      = (const float*)d_in[0];
    const float* W_in   = (const float*)d_in[1];
    const float* conv_w = (const float*)d_in[2];
    const float* conv_b = (const float*)d_in[3];
    const float* W_x    = (const float*)d_in[4];
    const float* W_dt   = (const float*)d_in[5];
    const float* b_dt   = (const float*)d_in[6];
    const float* A_log  = (const float*)d_in[7];
    const float* Dp     = (const float*)d_in[8];
    const float* W_out  = (const float*)d_in[9];
    float* out = (float*)d_out;

    const size_t M1 = 1024u * 1024u;
    const size_t fXZ = 8 * M1, fXACT = 4 * M1, fDBC = (size_t)BT * 96,
                 fDT = 4 * M1;
    // P/F sizes depend on NC: B*NC*16*D_INNER floats each
    const size_t fPF32 = 2 * M1;   // per buffer at NC=32
    const size_t fPF64 = 4 * M1;   // per buffer at NC=64
    const size_t shorts = 12 * M1; // xh 2M | winh 4M | wouth 2M | yh 4M
    const size_t need32 = (fXZ + fXACT + fDBC + fDT + 2 * fPF32) * 4 + shorts * 2;
    const size_t need64 = (fXZ + fXACT + fDBC + fDT + 2 * fPF64) * 4 + shorts * 2;

    if (ws_size >= need32) {
        const bool big = (ws_size >= need64);
        const size_t fPF = big ? fPF64 : fPF32;

        float* ws    = (float*)d_ws;
        float* xz    = ws;
        float* x_act = xz    + fXZ;
        float* dbc   = x_act + fXACT;
        float* dtbuf = dbc   + fDBC;
        float* Pbuf  = dtbuf + fDT;
        float* Fbuf  = Pbuf  + fPF;
        u16* xh    = (u16*)(Fbuf + fPF);
        u16* winh  = xh    + 2 * M1;
        u16* wouth = winh  + 4 * M1;
        u16* yh    = wouth + 2 * M1;   // 4M shorts
        float* dbc_part = Pbuf;        // 12.6 MB <= P+F (16 or 32 MB)

        // 1) convert to bf16-hi: x, W_in, W_out
        prep_kernel<<<dim3((8 * M1) / 2048), 256, 0, stream>>>(
            x, W_in, W_out, xh, winh, wouth);

        // 2) in_proj: xz[2048][4096] = x @ W_in^T
        gemm_bf16<128, 128, 64, 64><<<dim3(4096 / 128, BT / 128), 256, 0, stream>>>(
            xh, D_MODEL, winh, D_MODEL, xz, 4096, D_MODEL);

        // 3) conv + SiLU (x_in = xz[:, :2048]) — 4 channels/thread
        conv_silu_kernel<<<dim3((BT * D_INNER) / 1024), 256, 0, stream>>>(
            xz, 4096, conv_w, conv_b, x_act);

        // 4) dbc = x_act @ W_x^T (fp32 split-K)
        gemm_nt_splitk<64,32,16,4,4><<<dim3(96 / 32, BT / 64, KSPLIT), 128, 0, stream>>>(
            x_act, D_INNER, W_x, D_INNER, dbc_part, 96, D_INNER / KSPLIT);
        reduce_splitk<<<dim3((BT * 96 + 255) / 256), 256, 0, stream>>>(
            dbc_part, dbc, BT * 96);

        // 5) dt = softplus(dbc[:, :64] @ W_dt^T + b_dt) (fp32)
        gemm_nt<64,64,16,4,4,1><<<dim3(D_INNER / 64, BT / 64), 256, 0, stream>>>(
            dbc, 96, W_dt, DT_RANK, dtbuf, D_INNER, DT_RANK, b_dt);

        // 6) chunked scan + skip + gate; emit yf as bf16 hi
        if (big) {
            scan_part1<64><<<dim3(D_INNER / 256, 64, BATCH), 256, 0, stream>>>(
                dtbuf, x_act, dbc, A_log, Pbuf, Fbuf);
            scan_combine<64><<<dim3((BATCH * 16 * D_INNER) / 256), 256, 0, stream>>>(
                Pbuf, Fbuf);
            scan_part2<64, 1><<<dim3(D_INNER / 256, 64, BATCH), 256, 0, stream>>>(
                dtbuf, x_act, dbc, A_log, Dp, Fbuf, xz + D_INNER, 4096,
                nullptr, yh);
        } else {
            scan_part1<32><<<dim3(D_INNER / 256, 32, BATCH), 256, 0, stream>>>(
                dtbuf, x_act, dbc, A_log, Pbuf, Fbuf);
            scan_combine<32><<<dim3((BATCH * 16 * D_INNER) / 256), 256, 0, stream>>>(
                Pbuf, Fbuf);
            scan_part2<32, 1><<<dim3(D_INNER / 256, 32, BATCH), 256, 0, stream>>>(
                dtbuf, x_act, dbc, A_log, Dp, Fbuf, xz + D_INNER, 4096,
                nullptr, yh);
        }

        // 7) out_proj: out = yf @ W_out^T
        gemm_bf16<64, 128, 32, 64><<<dim3(D_MODEL / 128, BT / 64), 256, 0, stream>>>(
            yh, D_INNER, wouth, D_INNER, out, D_MODEL, D_INNER);
    } else {
        // ------------------- fallback: all-fp32 path (NC=32) ---------------
        float* ws    = (float*)d_ws;
        float* x_in  = ws;
        float* z     = x_in  + (size_t)BT * D_INNER;
        float* x_act = z     + (size_t)BT * D_INNER;
        float* dbc   = x_act + (size_t)BT * D_INNER;
        float* Pbuf  = dbc   + (size_t)BT * 96;
        float* Fbuf  = Pbuf  + (size_t)BATCH * 32 * 16 * D_INNER;
        float* dtbuf = x_in;
        float* yf    = z;

        gemm_nt<64,64,16,4,4,0><<<dim3(D_INNER/64, BT/64), 256, 0, stream>>>(
            x, D_MODEL, W_in, D_MODEL, x_in, D_INNER, D_MODEL, nullptr);
        gemm_nt<64,64,16,4,4,0><<<dim3(D_INNER/64, BT/64), 256, 0, stream>>>(
            x, D_MODEL, W_in + (size_t)D_INNER * D_MODEL, D_MODEL, z, D_INNER, D_MODEL, nullptr);
        conv_silu_kernel<<<dim3((BT * D_INNER) / 1024), 256, 0, stream>>>(
            x_in, D_INNER, conv_w, conv_b, x_act);
        gemm_nt<64,32,16,4,4,0><<<dim3(96/32, BT/64), 128, 0, stream>>>(
            x_act, D_INNER, W_x, D_INNER, dbc, 96, D_INNER, nullptr);
        gemm_nt<64,64,16,4,4,1><<<dim3(D_INNER/64, BT/64), 256, 0, stream>>>(
            dbc, 96, W_dt, DT_RANK, dtbuf, D_INNER, DT_RANK, b_dt);
        scan_part1<32><<<dim3(D_INNER/256, 32, BATCH), 256, 0, stream>>>(
            dtbuf, x_act, dbc, A_log, Pbuf, Fbuf);
        scan_combine<32><<<dim3((BATCH * 16 * D_INNER) / 256), 256, 0, stream>>>(
            Pbuf, Fbuf);
        scan_part2<32, 0><<<dim3(D_INNER/256, 32, BATCH), 256, 0, stream>>>(
            dtbuf, x_act, dbc, A_log, Dp, Fbuf, z, D_INNER, yf, nullptr);
        gemm_nt<64,64,16,4,4,0><<<dim3(D_MODEL/64, BT/64), 256, 0, stream>>>(
            yf, D_INNER, W_out, D_INNER, out, D_MODEL, D_INNER, nullptr);
    }
}

// Round 12
// 178.741 us; speedup vs baseline: 1.8709x; 1.0169x over previous
//
#include <hip/hip_runtime.h>
#include <math.h>

#define D_MODEL 1024
#define D_STATE 16
#define D_CONV  4
#define DT_RANK 64
#define D_INNER 2048
#define BATCH   2
#define SEQ     1024
#define BT      (BATCH*SEQ)   // 2048 rows
#define KSPLIT  16            // split-K factor for dbc GEMM

typedef int   v4i __attribute__((ext_vector_type(4)));
typedef float v4f __attribute__((ext_vector_type(4)));
typedef short s8v __attribute__((ext_vector_type(8)));
typedef unsigned short u16;

// ===========================================================================
// fp32 GEMM (dt projection + fallback path)
// ===========================================================================
template<int BM, int BN, int BK, int TM, int TN, int EPI>
__launch_bounds__(256)
__global__ void gemm_nt(const float* __restrict__ A, int lda,
                        const float* __restrict__ B, int ldb,
                        float* __restrict__ C, int ldc,
                        int K, const float* __restrict__ bias) {
    constexpr int BX = BN / TN;
    constexpr int BY = BM / TM;
    constexpr int THREADS = BX * BY;

    __shared__ float As[BK][BM + 1];
    __shared__ float Bs[BK][BN + 1];

    const int tid = threadIdx.x;
    const int tx  = tid % BX;
    const int ty  = tid / BX;
    const int m0  = blockIdx.y * BM;
    const int n0  = blockIdx.x * BN;

    float acc[TM][TN] = {};

    for (int k0 = 0; k0 < K; k0 += BK) {
        #pragma unroll
        for (int l = 0; l < (BM * BK) / (THREADS * 4); ++l) {
            int idx = (tid + l * THREADS) * 4;
            int row = idx / BK, col = idx % BK;
            const float4 v = *reinterpret_cast<const float4*>(
                &A[(size_t)(m0 + row) * lda + k0 + col]);
            As[col + 0][row] = v.x; As[col + 1][row] = v.y;
            As[col + 2][row] = v.z; As[col + 3][row] = v.w;
        }
        #pragma unroll
        for (int l = 0; l < (BN * BK) / (THREADS * 4); ++l) {
            int idx = (tid + l * THREADS) * 4;
            int row = idx / BK, col = idx % BK;
            const float4 v = *reinterpret_cast<const float4*>(
                &B[(size_t)(n0 + row) * ldb + k0 + col]);
            Bs[col + 0][row] = v.x; Bs[col + 1][row] = v.y;
            Bs[col + 2][row] = v.z; Bs[col + 3][row] = v.w;
        }
        __syncthreads();

        #pragma unroll
        for (int kk = 0; kk < BK; ++kk) {
            float a[TM], b[TN];
            #pragma unroll
            for (int i = 0; i < TM; ++i) a[i] = As[kk][ty * TM + i];
            #pragma unroll
            for (int j = 0; j < TN; ++j) b[j] = Bs[kk][tx * TN + j];
            #pragma unroll
            for (int i = 0; i < TM; ++i)
                #pragma unroll
                for (int j = 0; j < TN; ++j)
                    acc[i][j] = fmaf(a[i], b[j], acc[i][j]);
        }
        __syncthreads();
    }

    #pragma unroll
    for (int i = 0; i < TM; ++i) {
        float* outp = &C[(size_t)(m0 + ty * TM + i) * ldc + n0 + tx * TN];
        float vals[4];
        #pragma unroll
        for (int j = 0; j < TN; ++j) {
            float val = acc[i][j];
            if (EPI == 1) {
                val += bias[n0 + tx * TN + j];
                val = (val > 20.f) ? val : log1pf(expf(val));
            }
            vals[j] = val;
        }
        float4 v;
        v.x = vals[0]; v.y = vals[1]; v.z = vals[2]; v.w = vals[3];
        *reinterpret_cast<float4*>(outp) = v;
    }
}

// ===========================================================================
// Split-K fp32 GEMM for the skinny dbc projection (N=96, K=2048).
// ===========================================================================
template<int BM, int BN, int BK, int TM, int TN>
__launch_bounds__(128)
__global__ void gemm_nt_splitk(const float* __restrict__ A, int lda,
                               const float* __restrict__ B, int ldb,
                               float* __restrict__ part, int N, int kchunk) {
    constexpr int BX = BN / TN;
    constexpr int BY = BM / TM;
    constexpr int THREADS = BX * BY;

    __shared__ float As[BK][BM + 1];
    __shared__ float Bs[BK][BN + 1];

    const int tid = threadIdx.x;
    const int tx  = tid % BX;
    const int ty  = tid / BX;
    const int m0  = blockIdx.y * BM;
    const int n0  = blockIdx.x * BN;
    const int kb  = blockIdx.z * kchunk;

    float acc[TM][TN] = {};

    for (int k0 = kb; k0 < kb + kchunk; k0 += BK) {
        #pragma unroll
        for (int l = 0; l < (BM * BK) / (THREADS * 4); ++l) {
            int idx = (tid + l * THREADS) * 4;
            int row = idx / BK, col = idx % BK;
            const float4 v = *reinterpret_cast<const float4*>(
                &A[(size_t)(m0 + row) * lda + k0 + col]);
            As[col + 0][row] = v.x; As[col + 1][row] = v.y;
            As[col + 2][row] = v.z; As[col + 3][row] = v.w;
        }
        #pragma unroll
        for (int l = 0; l < (BN * BK) / (THREADS * 4); ++l) {
            int idx = (tid + l * THREADS) * 4;
            int row = idx / BK, col = idx % BK;
            const float4 v = *reinterpret_cast<const float4*>(
                &B[(size_t)(n0 + row) * ldb + k0 + col]);
            Bs[col + 0][row] = v.x; Bs[col + 1][row] = v.y;
            Bs[col + 2][row] = v.z; Bs[col + 3][row] = v.w;
        }
        __syncthreads();

        #pragma unroll
        for (int kk = 0; kk < BK; ++kk) {
            float a[TM], b[TN];
            #pragma unroll
            for (int i = 0; i < TM; ++i) a[i] = As[kk][ty * TM + i];
            #pragma unroll
            for (int j = 0; j < TN; ++j) b[j] = Bs[kk][tx * TN + j];
            #pragma unroll
            for (int i = 0; i < TM; ++i)
                #pragma unroll
                for (int j = 0; j < TN; ++j)
                    acc[i][j] = fmaf(a[i], b[j], acc[i][j]);
        }
        __syncthreads();
    }

    float* base = part + (size_t)blockIdx.z * BT * N;
    #pragma unroll
    for (int i = 0; i < TM; ++i) {
        float* outp = &base[(size_t)(m0 + ty * TM + i) * N + n0 + tx * TN];
        float4 v;
        v.x = acc[i][0]; v.y = acc[i][1]; v.z = acc[i][2]; v.w = acc[i][3];
        *reinterpret_cast<float4*>(outp) = v;
    }
}

__global__ void reduce_splitk(const float* __restrict__ part,
                              float* __restrict__ outp, int n) {
    const int idx = blockIdx.x * 256 + threadIdx.x;
    if (idx >= n) return;
    float s = 0.f;
    #pragma unroll
    for (int kc = 0; kc < KSPLIT; ++kc)
        s += part[(size_t)kc * n + idx];
    outp[idx] = s;
}

// ===========================================================================
// bf16 helpers
// ===========================================================================
__device__ __forceinline__ u16 rne_bf16(float x) {
    unsigned int u = __float_as_uint(x);
    unsigned int r = u + 0x7FFFu + ((u >> 16) & 1u);
    return (u16)(r >> 16);
}
__device__ __forceinline__ float bf2f(u16 h) {
    return __uint_as_float((unsigned int)h << 16);
}
// 8 fp32 -> 8 bf16 packed, via HW pk-convert (4 instructions).
__device__ __forceinline__ v4i pack8_bf16(const float4& a, const float4& b) {
    unsigned int r0, r1, r2, r3;
    asm("v_cvt_pk_bf16_f32 %0, %1, %2" : "=v"(r0) : "v"(a.x), "v"(a.y));
    asm("v_cvt_pk_bf16_f32 %0, %1, %2" : "=v"(r1) : "v"(a.z), "v"(a.w));
    asm("v_cvt_pk_bf16_f32 %0, %1, %2" : "=v"(r2) : "v"(b.x), "v"(b.y));
    asm("v_cvt_pk_bf16_f32 %0, %1, %2" : "=v"(r3) : "v"(b.z), "v"(b.w));
    v4i r; r[0] = (int)r0; r[1] = (int)r1; r[2] = (int)r2; r[3] = (int)r3;
    return r;
}

// ===========================================================================
// bf16 MFMA GEMM with optional fp32 sources (converted during staging) and
// optional bf16 output. m97 shape: 128-tile, dbuf LDS, 1 barrier/iter,
// k+2 global prefetch in regs. Pitch 40 shorts (80B).
// AF32/BF32: operand given as fp32, cvt_pk'd in the reg->LDS write.
// CBF16: epilogue stores bf16 (u16) instead of fp32.
// ===========================================================================
template<int BM, int BN, int WM, int WN, int AF32, int BF32, int CBF16>
__launch_bounds__(256)
__global__ void gemm_mx(const void* __restrict__ Ap, int lda,
                        const void* __restrict__ Bp, int ldb,
                        void* __restrict__ Cp, int ldc, int K) {
    constexpr int ACH = BM / 64;
    constexpr int BCH = BN / 64;
    constexpr int WMF = WM / 16;
    constexpr int WNF = WN / 16;
    constexpr int SA  = BM * 40;
    constexpr int SB  = BN * 40;
    constexpr int BUFSZ = SA + SB;
    constexpr int WCOLS = BN / WN;

    __shared__ u16 smem[2 * BUFSZ];

    const int tid  = threadIdx.x;
    const int lane = tid & 63;
    const int wave = tid >> 6;
    const int wr   = wave / WCOLS, wc = wave % WCOLS;
    const int m0   = blockIdx.y * BM, n0 = blockIdx.x * BN;

    size_t aBase[ACH]; int aW[ACH];
    #pragma unroll
    for (int q = 0; q < ACH; ++q) {
        int c = tid + q * 256, row = c >> 2, slot = c & 3;
        aBase[q] = (size_t)(m0 + row) * lda + slot * 8;
        aW[q] = row * 40 + slot * 8;
    }
    size_t bBase[BCH]; int bW[BCH];
    #pragma unroll
    for (int q = 0; q < BCH; ++q) {
        int c = tid + q * 256, row = c >> 2, slot = c & 3;
        bBase[q] = (size_t)(n0 + row) * ldb + slot * 8;
        bW[q] = row * 40 + slot * 8;
    }

    const int fr = lane & 15;
    const int fk = (lane >> 4) * 8;
    const int fq = lane >> 4;
    int aOff[WMF], bOff[WNF];
    #pragma unroll
    for (int i = 0; i < WMF; ++i) aOff[i] = (wr * WM + i * 16 + fr) * 40 + fk;
    #pragma unroll
    for (int j = 0; j < WNF; ++j) bOff[j] = (wc * WN + j * 16 + fr) * 40 + fk;

    v4f acc[WMF][WNF];
    #pragma unroll
    for (int i = 0; i < WMF; ++i)
        #pragma unroll
        for (int j = 0; j < WNF; ++j)
            acc[i][j] = (v4f)0.f;

    float4 rAf[ACH][2]; v4i rA[ACH];
    float4 rBf[BCH][2]; v4i rB[BCH];

    auto loadg = [&](int k0) {
        if constexpr (AF32) {
            const float* A = (const float*)Ap;
            #pragma unroll
            for (int q = 0; q < ACH; ++q) {
                rAf[q][0] = *reinterpret_cast<const float4*>(A + aBase[q] + k0);
                rAf[q][1] = *reinterpret_cast<const float4*>(A + aBase[q] + k0 + 4);
            }
        } else {
            const u16* A = (const u16*)Ap;
            #pragma unroll
            for (int q = 0; q < ACH; ++q)
                rA[q] = *reinterpret_cast<const v4i*>(A + aBase[q] + k0);
        }
        if constexpr (BF32) {
            const float* B = (const float*)Bp;
            #pragma unroll
            for (int q = 0; q < BCH; ++q) {
                rBf[q][0] = *reinterpret_cast<const float4*>(B + bBase[q] + k0);
                rBf[q][1] = *reinterpret_cast<const float4*>(B + bBase[q] + k0 + 4);
            }
        } else {
            const u16* B = (const u16*)Bp;
            #pragma unroll
            for (int q = 0; q < BCH; ++q)
                rB[q] = *reinterpret_cast<const v4i*>(B + bBase[q] + k0);
        }
    };
    auto writelds = [&](u16* buf) {
        #pragma unroll
        for (int q = 0; q < ACH; ++q) {
            v4i v;
            if constexpr (AF32) v = pack8_bf16(rAf[q][0], rAf[q][1]);
            else v = rA[q];
            *reinterpret_cast<v4i*>(&buf[aW[q]]) = v;
        }
        #pragma unroll
        for (int q = 0; q < BCH; ++q) {
            v4i v;
            if constexpr (BF32) v = pack8_bf16(rBf[q][0], rBf[q][1]);
            else v = rB[q];
            *reinterpret_cast<v4i*>(&buf[SA + bW[q]]) = v;
        }
    };

    const int NK = K / 32;
    loadg(0);
    writelds(smem);
    if (NK > 1) loadg(32);
    __syncthreads();

    for (int k = 0; k < NK; ++k) {
        u16* cur = smem + (k & 1) * BUFSZ;
        if (k + 1 < NK) {
            writelds(smem + ((k + 1) & 1) * BUFSZ);
            if (k + 2 < NK) loadg((k + 2) * 32);
        }

        s8v ah[WMF];
        #pragma unroll
        for (int i = 0; i < WMF; ++i)
            ah[i] = *reinterpret_cast<const s8v*>(&cur[aOff[i]]);
        #pragma unroll
        for (int j = 0; j < WNF; ++j) {
            const s8v bh = *reinterpret_cast<const s8v*>(&cur[SA + bOff[j]]);
            #pragma unroll
            for (int i = 0; i < WMF; ++i)
                acc[i][j] = __builtin_amdgcn_mfma_f32_16x16x32_bf16(ah[i], bh, acc[i][j], 0, 0, 0);
        }
        __syncthreads();
    }

    #pragma unroll
    for (int i = 0; i < WMF; ++i) {
        const int row = m0 + wr * WM + i * 16 + fq * 4;
        #pragma unroll
        for (int j = 0; j < WNF; ++j) {
            const int col = n0 + wc * WN + j * 16 + fr;
            #pragma unroll
            for (int r = 0; r < 4; ++r) {
                if constexpr (CBF16) {
                    ((u16*)Cp)[(size_t)(row + r) * ldc + col] = rne_bf16(acc[i][j][r]);
                } else {
                    ((float*)Cp)[(size_t)(row + r) * ldc + col] = acc[i][j][r];
                }
            }
        }
    }
}

// ===========================================================================
// Depthwise causal conv (width 4) + bias + SiLU. 4 channels per thread.
// INBF16: input stored as bf16 (u16), else fp32. Output always fp32.
// ===========================================================================
template<int INBF16>
__global__ void conv_silu_kernel(const void* __restrict__ x_in, int xld,
                                 const float* __restrict__ w,
                                 const float* __restrict__ b,
                                 float* __restrict__ x_act) {
    const int idx = blockIdx.x * blockDim.x + threadIdx.x;   // over BT*D_INNER/4
    const int ch4 = (idx * 4) % D_INNER;
    const int m   = (idx * 4) / D_INNER;
    const int t   = m % SEQ;

    float4 wrow[4];
    #pragma unroll
    for (int c = 0; c < 4; ++c)
        wrow[c] = *reinterpret_cast<const float4*>(&w[(ch4 + c) * D_CONV]);
    float4 acc = *reinterpret_cast<const float4*>(&b[ch4]);

    #pragma unroll
    for (int j = 0; j < D_CONV; ++j) {
        const int tt = t - (D_CONV - 1) + j;
        if (tt >= 0) {
            float xi[4];
            if (INBF16) {
                const ushort4 v = *reinterpret_cast<const ushort4*>(
                    &((const u16*)x_in)[(size_t)(m - (D_CONV - 1) + j) * xld + ch4]);
                xi[0] = bf2f(v.x); xi[1] = bf2f(v.y);
                xi[2] = bf2f(v.z); xi[3] = bf2f(v.w);
            } else {
                const float4 v = *reinterpret_cast<const float4*>(
                    &((const float*)x_in)[(size_t)(m - (D_CONV - 1) + j) * xld + ch4]);
                xi[0] = v.x; xi[1] = v.y; xi[2] = v.z; xi[3] = v.w;
            }
            acc.x = fmaf(((const float*)&wrow[0])[j], xi[0], acc.x);
            acc.y = fmaf(((const float*)&wrow[1])[j], xi[1], acc.y);
            acc.z = fmaf(((const float*)&wrow[2])[j], xi[2], acc.z);
            acc.w = fmaf(((const float*)&wrow[3])[j], xi[3], acc.w);
        }
    }
    acc.x = acc.x / (1.f + __expf(-acc.x));
    acc.y = acc.y / (1.f + __expf(-acc.y));
    acc.z = acc.z / (1.f + __expf(-acc.z));
    acc.w = acc.w / (1.f + __expf(-acc.w));
    *reinterpret_cast<float4*>(&x_act[(size_t)idx * 4]) = acc;
}

// ===========================================================================
// Chunked selective scan, templated on NC. Simple per-step bodies
// (VGPR ~64, no spill; manual ILP batching spills — r6/7 lesson).
// ===========================================================================
template<int NC>
__launch_bounds__(256)
__global__ void scan_part1(const float* __restrict__ dt,
                           const float* __restrict__ x_act,
                           const float* __restrict__ dbc,
                           const float* __restrict__ A_log,
                           float* __restrict__ P, float* __restrict__ F) {
    constexpr int CL = SEQ / NC;
    __shared__ float Bsh[CL][D_STATE];
    const int tid = threadIdx.x;
    const int d = blockIdx.x * 256 + tid;
    const int c = blockIdx.y;
    const int b = blockIdx.z;
    const int mbase = b * SEQ + c * CL;

    {
        const int s = tid & 15, t0 = tid >> 4;
        #pragma unroll
        for (int q = 0; q < CL / 16; ++q)
            Bsh[t0 + 16 * q][s] = dbc[(size_t)(mbase + t0 + 16 * q) * 96 + DT_RANK + s];
    }
    float A[16];
    #pragma unroll
    for (int q = 0; q < 4; ++q) {
        float4 v = *reinterpret_cast<const float4*>(&A_log[d * 16 + q * 4]);
        A[q*4+0] = -__expf(v.x); A[q*4+1] = -__expf(v.y);
        A[q*4+2] = -__expf(v.z); A[q*4+3] = -__expf(v.w);
    }
    __syncthreads();

    float h[16] = {};
    float Pp[16];
    #pragma unroll
    for (int s = 0; s < 16; ++s) Pp[s] = 1.f;

    for (int t = 0; t < CL; ++t) {
        const int m = mbase + t;
        const float dtv = dt[(size_t)m * D_INNER + d];
        const float u   = x_act[(size_t)m * D_INNER + d];
        const float du  = dtv * u;
        float Bv[16];
        #pragma unroll
        for (int q = 0; q < 4; ++q) {
            float4 v = *reinterpret_cast<const float4*>(&Bsh[t][q * 4]);
            Bv[q*4+0] = v.x; Bv[q*4+1] = v.y; Bv[q*4+2] = v.z; Bv[q*4+3] = v.w;
        }
        #pragma unroll
        for (int s = 0; s < 16; ++s) {
            const float dA = __expf(dtv * A[s]);
            Pp[s] *= dA;
            h[s] = fmaf(dA, h[s], du * Bv[s]);
        }
    }
    const size_t base = ((size_t)(b * NC + c) * 16) * D_INNER + d;
    #pragma unroll
    for (int s = 0; s < 16; ++s) {
        P[base + (size_t)s * D_INNER] = Pp[s];
        F[base + (size_t)s * D_INNER] = h[s];
    }
}

template<int NC>
__launch_bounds__(256, 2)
__global__ void scan_combine(const float* __restrict__ P, float* F) {
    const int idx = blockIdx.x * 256 + threadIdx.x;
    const int d  = idx % D_INNER;
    const int bs = idx / D_INNER;
    const int b  = bs >> 4, s = bs & 15;
    const size_t base0 = ((size_t)b * NC * 16 + s) * D_INNER + d;
    const size_t cstep = (size_t)16 * D_INNER;

    float Pv[NC], Fv[NC];
    #pragma unroll
    for (int c = 0; c < NC; ++c) {
        Pv[c] = P[base0 + c * cstep];
        Fv[c] = F[base0 + c * cstep];
    }
    float G = 0.f;
    #pragma unroll
    for (int c = 0; c < NC; ++c) {
        const float f = Fv[c];
        Fv[c] = G;
        G = fmaf(Pv[c], G, f);
    }
    #pragma unroll
    for (int c = 0; c < NC; ++c)
        F[base0 + c * cstep] = Fv[c];
}

// ZBF16: z input stored as bf16. BF16OUT: emit yf as bf16 for out_proj.
// Fallback: <NC,0,0> with fp32 z aliasing yf (z preloaded per half-chunk).
template<int NC, int ZBF16, int BF16OUT>
__launch_bounds__(256)
__global__ void scan_part2(const float* __restrict__ dt,
                           const float* __restrict__ x_act,
                           const float* __restrict__ dbc,
                           const float* __restrict__ A_log,
                           const float* __restrict__ Dp,
                           const float* __restrict__ Ginit,
                           const void* zp, int zld,
                           float* yf, u16* yh) {
    constexpr int CL = SEQ / NC;
    __shared__ float BCs[CL][32];
    const int tid = threadIdx.x;
    const int d = blockIdx.x * 256 + tid;
    const int c = blockIdx.y;
    const int b = blockIdx.z;
    const int mbase = b * SEQ + c * CL;

    {
        const int t0 = tid >> 3;
        const int j  = (tid & 7) * 4;
        if (t0 < CL) {
            float4 v = *reinterpret_cast<const float4*>(
                &dbc[(size_t)(mbase + t0) * 96 + DT_RANK + j]);
            *reinterpret_cast<float4*>(&BCs[t0][j]) = v;
        }
    }
    float A[16];
    #pragma unroll
    for (int q = 0; q < 4; ++q) {
        float4 v = *reinterpret_cast<const float4*>(&A_log[d * 16 + q * 4]);
        A[q*4+0] = -__expf(v.x); A[q*4+1] = -__expf(v.y);
        A[q*4+2] = -__expf(v.z); A[q*4+3] = -__expf(v.w);
    }
    float h[16];
    const size_t gbase = ((size_t)(b * NC + c) * 16) * D_INNER + d;
    #pragma unroll
    for (int s = 0; s < 16; ++s) h[s] = Ginit[gbase + (size_t)s * D_INNER];
    const float Dv = Dp[d];
    __syncthreads();

    for (int half = 0; half < 2; ++half) {
        const int tb = half * (CL / 2);
        float zreg[CL / 2];
        #pragma unroll
        for (int t = 0; t < CL / 2; ++t) {
            if (ZBF16)
                zreg[t] = bf2f(((const u16*)zp)[(size_t)(mbase + tb + t) * zld + d]);
            else
                zreg[t] = ((const float*)zp)[(size_t)(mbase + tb + t) * zld + d];
        }

        for (int t = 0; t < CL / 2; ++t) {
            const int m = mbase + tb + t;
            const float dtv = dt[(size_t)m * D_INNER + d];
            const float u   = x_act[(size_t)m * D_INNER + d];
            const float du  = dtv * u;
            float Bv[16], Cv[16];
            #pragma unroll
            for (int q = 0; q < 4; ++q) {
                float4 vb = *reinterpret_cast<const float4*>(&BCs[tb + t][q * 4]);
                float4 vc = *reinterpret_cast<const float4*>(&BCs[tb + t][16 + q * 4]);
                Bv[q*4+0] = vb.x; Bv[q*4+1] = vb.y; Bv[q*4+2] = vb.z; Bv[q*4+3] = vb.w;
                Cv[q*4+0] = vc.x; Cv[q*4+1] = vc.y; Cv[q*4+2] = vc.z; Cv[q*4+3] = vc.w;
            }
            float y0 = 0.f, y1 = 0.f;
            #pragma unroll
            for (int s = 0; s < 16; s += 2) {
                const float dA0 = __expf(dtv * A[s]);
                const float dA1 = __expf(dtv * A[s + 1]);
                h[s]     = fmaf(dA0, h[s],     du * Bv[s]);
                h[s + 1] = fmaf(dA1, h[s + 1], du * Bv[s + 1]);
                y0 = fmaf(h[s],     Cv[s],     y0);
                y1 = fmaf(h[s + 1], Cv[s + 1], y1);
            }
            float y = y0 + y1;
            y = fmaf(u, Dv, y);
            const float zv = zreg[t];
            const float g  = zv / (1.f + __expf(-zv));
            const float val = y * g;
            if (BF16OUT) {
                yh[(size_t)m * D_INNER + d] = rne_bf16(val);
            } else {
                yf[(size_t)m * D_INNER + d] = val;
            }
        }
    }
}

// ===========================================================================
extern "C" void kernel_launch(void* const* d_in, const int* in_sizes, int n_in,
                              void* d_out, int out_size, void* d_ws, size_t ws_size,
                              hipStream_t stream) {
    const float* x      = (const float*)d_in[0];
    const float* W_in   = (const float*)d_in[1];
    const float* conv_w = (const float*)d_in[2];
    const float* conv_b = (const float*)d_in[3];
    const float* W_x    = (const float*)d_in[4];
    const float* W_dt   = (const float*)d_in[5];
    const float* b_dt   = (const float*)d_in[6];
    const float* A_log  = (const float*)d_in[7];
    const float* Dp     = (const float*)d_in[8];
    const float* W_out  = (const float*)d_in[9];
    float* out = (float*)d_out;

    const size_t M1 = 1024u * 1024u;
    const size_t fXACT = 4 * M1, fDBC = (size_t)BT * 96, fDT = 4 * M1;
    const size_t fPF32 = 2 * M1;   // P or F at NC=32
    const size_t fPF64 = 4 * M1;   // P or F at NC=64
    const size_t shorts = 12 * M1; // xz 8M | yh 4M
    const size_t need32 = (fXACT + fDBC + fDT + 2 * fPF32) * 4 + shorts * 2;
    const size_t need64 = (fXACT + fDBC + fDT + 2 * fPF64) * 4 + shorts * 2;

    if (ws_size >= need32) {
        const bool big = (ws_size >= need64);
        const size_t fPF = big ? fPF64 : fPF32;

        float* ws    = (float*)d_ws;
        float* x_act = ws;
        float* dbc   = x_act + fXACT;
        float* dtbuf = dbc   + fDBC;
        float* Pbuf  = dtbuf + fDT;
        float* Fbuf  = Pbuf  + fPF;
        u16* xz = (u16*)(Fbuf + fPF);  // [2048][4096] bf16
        u16* yh = xz + 8 * M1;         // 4M shorts
        float* dbc_part = Pbuf;        // 12.6 MB <= P+F

        // 1) in_proj: xz = bf16( x @ W_in^T ), fp32 sources converted in-kernel
        gemm_mx<128, 128, 64, 64, 1, 1, 1><<<dim3(4096 / 128, BT / 128), 256, 0, stream>>>(
            x, D_MODEL, W_in, D_MODEL, xz, 4096, D_MODEL);

        // 2) conv + SiLU (bf16 in, fp32 out)
        conv_silu_kernel<1><<<dim3((BT * D_INNER) / 1024), 256, 0, stream>>>(
            xz, 4096, conv_w, conv_b, x_act);

        // 3) dbc = x_act @ W_x^T (fp32 split-K)
        gemm_nt_splitk<64,32,16,4,4><<<dim3(96 / 32, BT / 64, KSPLIT), 128, 0, stream>>>(
            x_act, D_INNER, W_x, D_INNER, dbc_part, 96, D_INNER / KSPLIT);
        reduce_splitk<<<dim3((BT * 96 + 255) / 256), 256, 0, stream>>>(
            dbc_part, dbc, BT * 96);

        // 4) dt = softplus(dbc[:, :64] @ W_dt^T + b_dt) (fp32)
        gemm_nt<64,64,16,4,4,1><<<dim3(D_INNER / 64, BT / 64), 256, 0, stream>>>(
            dbc, 96, W_dt, DT_RANK, dtbuf, D_INNER, DT_RANK, b_dt);

        // 5) chunked scan + skip + gate; z read as bf16; emit yh bf16
        if (big) {
            scan_part1<64><<<dim3(D_INNER / 256, 64, BATCH), 256, 0, stream>>>(
                dtbuf, x_act, dbc, A_log, Pbuf, Fbuf);
            scan_combine<64><<<dim3((BATCH * 16 * D_INNER) / 256), 256, 0, stream>>>(
                Pbuf, Fbuf);
            scan_part2<64, 1, 1><<<dim3(D_INNER / 256, 64, BATCH), 256, 0, stream>>>(
                dtbuf, x_act, dbc, A_log, Dp, Fbuf, xz + D_INNER, 4096,
                nullptr, yh);
        } else {
            scan_part1<32><<<dim3(D_INNER / 256, 32, BATCH), 256, 0, stream>>>(
                dtbuf, x_act, dbc, A_log, Pbuf, Fbuf);
            scan_combine<32><<<dim3((BATCH * 16 * D_INNER) / 256), 256, 0, stream>>>(
                Pbuf, Fbuf);
            scan_part2<32, 1, 1><<<dim3(D_INNER / 256, 32, BATCH), 256, 0, stream>>>(
                dtbuf, x_act, dbc, A_log, Dp, Fbuf, xz + D_INNER, 4096,
                nullptr, yh);
        }

        // 6) out_proj: out = yh @ bf16(W_out)^T (W_out converted in-kernel)
        gemm_mx<64, 128, 32, 64, 0, 1, 0><<<dim3(D_MODEL / 128, BT / 64), 256, 0, stream>>>(
            yh, D_INNER, W_out, D_INNER, out, D_MODEL, D_INNER);
    } else {
        // ------------------- fallback: all-fp32 path (NC=32) ---------------
        float* ws    = (float*)d_ws;
        float* x_in  = ws;
        float* z     = x_in  + (size_t)BT * D_INNER;
        float* x_act = z     + (size_t)BT * D_INNER;
        float* dbc   = x_act + (size_t)BT * D_INNER;
        float* Pbuf  = dbc   + (size_t)BT * 96;
        float* Fbuf  = Pbuf  + (size_t)BATCH * 32 * 16 * D_INNER;
        float* dtbuf = x_in;
        float* yf    = z;

        gemm_nt<64,64,16,4,4,0><<<dim3(D_INNER/64, BT/64), 256, 0, stream>>>(
            x, D_MODEL, W_in, D_MODEL, x_in, D_INNER, D_MODEL, nullptr);
        gemm_nt<64,64,16,4,4,0><<<dim3(D_INNER/64, BT/64), 256, 0, stream>>>(
            x, D_MODEL, W_in + (size_t)D_INNER * D_MODEL, D_MODEL, z, D_INNER, D_MODEL, nullptr);
        conv_silu_kernel<0><<<dim3((BT * D_INNER) / 1024), 256, 0, stream>>>(
            x_in, D_INNER, conv_w, conv_b, x_act);
        gemm_nt<64,32,16,4,4,0><<<dim3(96/32, BT/64), 128, 0, stream>>>(
            x_act, D_INNER, W_x, D_INNER, dbc, 96, D_INNER, nullptr);
        gemm_nt<64,64,16,4,4,1><<<dim3(D_INNER/64, BT/64), 256, 0, stream>>>(
            dbc, 96, W_dt, DT_RANK, dtbuf, D_INNER, DT_RANK, b_dt);
        scan_part1<32><<<dim3(D_INNER/256, 32, BATCH), 256, 0, stream>>>(
            dtbuf, x_act, dbc, A_log, Pbuf, Fbuf);
        scan_combine<32><<<dim3((BATCH * 16 * D_INNER) / 256), 256, 0, stream>>>(
            Pbuf, Fbuf);
        scan_part2<32, 0, 0><<<dim3(D_INNER/256, 32, BATCH), 256, 0, stream>>>(
            dtbuf, x_act, dbc, A_log, Dp, Fbuf, z, D_INNER, yf, nullptr);
        gemm_nt<64,64,16,4,4,0><<<dim3(D_MODEL/64, BT/64), 256, 0, stream>>>(
            yf, D_INNER, W_out, D_INNER, out, D_MODEL, D_INNER, nullptr);
    }
}